// Round 1
// baseline (3614.552 us; speedup 1.0000x reference)
//
#include <hip/hip_runtime.h>
#include <hip/hip_bf16.h>

// Problem constants (fixed instance)
#define N_NODES 4096
#define CF      256        // nopen == nhid == nNclose
#define CIN     64
#define E0_EDGES 65536
#define E_TOT   (E0_EDGES + N_NODES)   // with self loops appended
#define NLAYER  8
#define NOUT    1024
#define CN      (CF * N_NODES)         // 1048576 elements

// ---------------- block reduction helpers (blockDim.x == 256) ----------------
__device__ __forceinline__ float waveSumF(float v){
  #pragma unroll
  for (int o = 32; o; o >>= 1) v += __shfl_xor(v, o);
  return v;
}
__device__ __forceinline__ double waveSumD(double v){
  #pragma unroll
  for (int o = 32; o; o >>= 1) v += __shfl_xor(v, o);
  return v;
}
__device__ __forceinline__ float waveMaxF(float v){
  #pragma unroll
  for (int o = 32; o; o >>= 1) v = fmaxf(v, __shfl_xor(v, o));
  return v;
}
__device__ float blockSumF(float v){
  __shared__ float sm[4];
  v = waveSumF(v);
  int l = threadIdx.x & 63, w = threadIdx.x >> 6;
  __syncthreads();
  if (l == 0) sm[w] = v;
  __syncthreads();
  return sm[0] + sm[1] + sm[2] + sm[3];
}
__device__ double blockSumD(double v){
  __shared__ double sm[4];
  v = waveSumD(v);
  int l = threadIdx.x & 63, w = threadIdx.x >> 6;
  __syncthreads();
  if (l == 0) sm[w] = v;
  __syncthreads();
  return sm[0] + sm[1] + sm[2] + sm[3];
}
__device__ float blockMaxF(float v){
  __shared__ float sm[4];
  v = waveMaxF(v);
  int l = threadIdx.x & 63, w = threadIdx.x >> 6;
  __syncthreads();
  if (l == 0) sm[w] = v;
  __syncthreads();
  return fmaxf(fmaxf(sm[0], sm[1]), fmaxf(sm[2], sm[3]));
}

// ---------------- f32 tiled GEMM: C[M,N] = alpha*A·op(B) + beta*C (+bias, act) ----
// A row-major [M,K] (lda). op(B)=B row-major [K,N] (ldb) or, if TRANSB, B^T with
// B stored row-major [N,K] (ldb). 64x64 tile, BK=16, 256 threads, 4x4 micro-tile.
// gridDim.z>1 => split-K with atomic accumulation (requires beta==0, C pre-zeroed).
template<bool TRANSB, int ACT>  // ACT: 0 none, 1 elu
__global__ __launch_bounds__(256)
void gemm64(const float* __restrict__ A, int lda,
            const float* __restrict__ B, int ldb,
            float* __restrict__ C, int ldc,
            int K, int kChunk, float alpha, float beta,
            const float* __restrict__ bias)
{
  __shared__ float As[16][65];
  __shared__ float Bs[16][65];
  const int tid = threadIdx.x;
  const int tx = tid & 15, ty = tid >> 4;
  const int row0 = blockIdx.y * 64, col0 = blockIdx.x * 64;
  const int kStart = blockIdx.z * kChunk;

  const int am = tid >> 2;          // 0..63
  const int ak = (tid & 3) * 4;     // 0,4,8,12
  const int bk = tid >> 4;          // 0..15
  const int bn = (tid & 15) * 4;    // 0..60

  float acc[4][4] = {};

  for (int k0 = kStart; k0 < kStart + kChunk; k0 += 16) {
    float4 av = *(const float4*)(A + (size_t)(row0 + am) * lda + k0 + ak);
    As[ak+0][am] = av.x; As[ak+1][am] = av.y; As[ak+2][am] = av.z; As[ak+3][am] = av.w;
    if (TRANSB) {
      float4 bv = *(const float4*)(B + (size_t)(col0 + am) * ldb + k0 + ak);
      Bs[ak+0][am] = bv.x; Bs[ak+1][am] = bv.y; Bs[ak+2][am] = bv.z; Bs[ak+3][am] = bv.w;
    } else {
      float4 bv = *(const float4*)(B + (size_t)(k0 + bk) * ldb + col0 + bn);
      Bs[bk][bn+0] = bv.x; Bs[bk][bn+1] = bv.y; Bs[bk][bn+2] = bv.z; Bs[bk][bn+3] = bv.w;
    }
    __syncthreads();
    #pragma unroll
    for (int k = 0; k < 16; k++) {
      float a[4], b[4];
      #pragma unroll
      for (int i = 0; i < 4; i++) a[i] = As[k][ty*4 + i];
      #pragma unroll
      for (int j = 0; j < 4; j++) b[j] = Bs[k][tx*4 + j];
      #pragma unroll
      for (int i = 0; i < 4; i++)
        #pragma unroll
        for (int j = 0; j < 4; j++) acc[i][j] += a[i] * b[j];
    }
    __syncthreads();
  }

  if (gridDim.z > 1) {
    #pragma unroll
    for (int i = 0; i < 4; i++)
      #pragma unroll
      for (int j = 0; j < 4; j++)
        unsafeAtomicAdd(&C[(size_t)(row0 + ty*4 + i) * ldc + col0 + tx*4 + j], alpha * acc[i][j]);
  } else {
    #pragma unroll
    for (int i = 0; i < 4; i++) {
      float* cp = C + (size_t)(row0 + ty*4 + i) * ldc + col0 + tx*4;
      #pragma unroll
      for (int j = 0; j < 4; j++) {
        float v = alpha * acc[i][j];
        if (beta != 0.0f) v += beta * cp[j];
        if (bias) v += bias[col0 + tx*4 + j];
        if (ACT == 1) v = (v > 0.0f) ? v : expm1f(v);
        cp[j] = v;
      }
    }
  }
}

// ---------------- transpose: in[R][Cc] -> out[Cc][R] ----------------
__global__ __launch_bounds__(256)
void transposeK(const float* __restrict__ in, float* __restrict__ out, int R, int Cc)
{
  __shared__ float t[32][33];
  int x  = blockIdx.x * 32 + threadIdx.x;   // column in 'in'
  int y0 = blockIdx.y * 32;                 // row base in 'in'
  for (int dy = threadIdx.y; dy < 32; dy += 8)
    t[dy][threadIdx.x] = in[(size_t)(y0 + dy) * Cc + x];
  __syncthreads();
  int ox  = y0 + threadIdx.x;               // column in 'out' (R-dim)
  int oy0 = blockIdx.x * 32;                // row base in 'out'
  for (int dy = threadIdx.y; dy < 32; dy += 8)
    out[(size_t)(oy0 + dy) * R + ox] = t[threadIdx.x][dy];
}

// ---------------- whole-tensor mean/var reduce (double atomics) ----------------
__global__ __launch_bounds__(256)
void reduceMV(const float* __restrict__ x, int n4, double* acc)
{
  double s = 0, s2 = 0;
  for (int i = blockIdx.x * blockDim.x + threadIdx.x; i < n4; i += gridDim.x * blockDim.x) {
    float4 v = ((const float4*)x)[i];
    s  += (double)v.x + v.y + v.z + v.w;
    s2 += (double)v.x*v.x + (double)v.y*v.y + (double)v.z*v.z + (double)v.w*v.w;
  }
  s  = blockSumD(s);
  s2 = blockSumD(s2);
  if (threadIdx.x == 0) { unsafeAtomicAdd(acc, s); unsafeAtomicAdd(acc + 1, s2); }
}

__global__ __launch_bounds__(256)
void tanhNormK(float* __restrict__ x, int n4, const double* __restrict__ acc, double invCount)
{
  double m   = acc[0] * invCount;
  double var = acc[1] * invCount - m * m;
  float rs = (float)(1.0 / sqrt(var + 1e-5));
  float mf = (float)m;
  for (int i = blockIdx.x * blockDim.x + threadIdx.x; i < n4; i += gridDim.x * blockDim.x) {
    float4 v = ((const float4*)x)[i];
    v.x = tanhf((v.x - mf) * rs);
    v.y = tanhf((v.y - mf) * rs);
    v.z = tanhf((v.z - mf) * rs);
    v.w = tanhf((v.w - mf) * rs);
    ((float4*)x)[i] = v;
  }
}

// ---------------- per-node squared norms (from ft[N][CF]) + S1,S2 ----------------
__global__ __launch_bounds__(256)
void rowSqK(const float* __restrict__ ft, float* __restrict__ sq, double* __restrict__ dS)
{
  int n = blockIdx.x;
  float v = ft[(size_t)n * CF + threadIdx.x];
  float t = blockSumF(v * v);
  if (threadIdx.x == 0) {
    sq[n] = t;
    unsafeAtomicAdd(dS,     (double)t);
    unsafeAtomicAdd(dS + 1, (double)t * t);
  }
}

// ---------------- per-channel sums: s[c]=Σ_n f[c,n], h[c]=Σ_n sq[n]*f[c,n] ----------
__global__ __launch_bounds__(256)
void colSHK(const float* __restrict__ f, const float* __restrict__ sq,
            float* __restrict__ s, float* __restrict__ h)
{
  int c = blockIdx.x;
  double ps = 0, ph = 0;
  for (int n = threadIdx.x; n < N_NODES; n += 256) {
    float v = f[(size_t)c * N_NODES + n];
    ps += v;
    ph += (double)v * sq[n];
  }
  ps = blockSumD(ps);
  ph = blockSumD(ph);
  if (threadIdx.x == 0) { s[c] = (float)ps; h[c] = (float)ph; }
}

// ---------------- closed-form std of the NxN distance matrix ----------------
__global__ __launch_bounds__(256)
void finalizeStdK(const float* __restrict__ s, const float* __restrict__ h,
                  const float* __restrict__ G, const double* __restrict__ dS,
                  float* __restrict__ c0)
{
  int c = threadIdx.x;
  double sd = (double)s[c] * s[c];
  double hd = (double)h[c] * s[c];
  double gf = 0;
  for (int i = c; i < CF * CF; i += 256) { double g = G[i]; gf += g * g; }
  sd = blockSumD(sd);
  hd = blockSumD(hd);
  gf = blockSumD(gf);
  if (c == 0) {
    double S1 = dS[0], S2 = dS[1];
    double NN = (double)N_NODES;
    double sum1 = 2.0 * NN * S1 - 2.0 * sd;
    double sum2 = 2.0 * NN * S2 + 2.0 * S1 * S1 + 4.0 * gf - 8.0 * hd;
    double n2 = NN * NN;
    double var = (sum2 - sum1 * sum1 / n2) / (n2 - 1.0);
    double sdev = sqrt(var > 0 ? var : 0);
    c0[0] = (float)(-2.0 / sdev);
  }
}

// ---------------- edge affinities (wave per edge) + deg ----------------
__global__ __launch_bounds__(256)
void edgeWK(const int* __restrict__ ei, const int* __restrict__ ej,
            const float* __restrict__ ft, const float* __restrict__ sq,
            const float* __restrict__ c0,
            float* __restrict__ wE, float* __restrict__ deg)
{
  int wid  = (blockIdx.x * 256 + threadIdx.x) >> 6;
  int lane = threadIdx.x & 63;
  if (wid >= E_TOT) return;
  int i, j;
  if (wid < E0_EDGES) { i = ei[wid]; j = ej[wid]; } else { i = j = wid - E0_EDGES; }
  float4 a = ((const float4*)(ft + (size_t)i * CF))[lane];
  float4 b = ((const float4*)(ft + (size_t)j * CF))[lane];
  float d = a.x*b.x + a.y*b.y + a.z*b.z + a.w*b.w;
  d = waveSumF(d);
  if (lane == 0) {
    float dist = fmaxf(sq[i] + sq[j] - 2.0f * d, 0.0f);
    float w = expf(c0[0] * dist);
    wE[wid] = w;
    unsafeAtomicAdd(deg + j, w);
  }
}

__global__ void disKK(float* deg)
{
  int n = blockIdx.x * blockDim.x + threadIdx.x;
  if (n < N_NODES) { float d = deg[n]; deg[n] = d > 0.0f ? rsqrtf(d) : 0.0f; }
}

// ---------------- graph Laplacian scatter into lapT[N][CF] ----------------
__global__ __launch_bounds__(256)
void scatterLapK(const int* __restrict__ ei, const int* __restrict__ ej,
                 const float* __restrict__ ft, const float* __restrict__ wE,
                 const float* __restrict__ dis, float* __restrict__ lapT)
{
  int e = blockIdx.x;
  int i = ei[e], j = ej[e];
  if (i == j) return;
  float W = dis[i] * wE[e] * dis[j];
  float W2 = W * W;
  int c = threadIdx.x;
  float v = W2 * (ft[(size_t)i * CF + c] - ft[(size_t)j * CF + c]);
  unsafeAtomicAdd(lapT + (size_t)i * CF + c,  v);
  unsafeAtomicAdd(lapT + (size_t)j * CF + c, -v);
}

// ---------------- row log-softmax, f32 out ----------------
__global__ __launch_bounds__(256)
void logSoftmaxK(const float* __restrict__ logits, float* __restrict__ out)
{
  int n = blockIdx.x;
  const float* row = logits + (size_t)n * NOUT;
  float mx = -1e30f;
  for (int o = threadIdx.x; o < NOUT; o += 256) mx = fmaxf(mx, row[o]);
  mx = blockMaxF(mx);
  float se = 0;
  for (int o = threadIdx.x; o < NOUT; o += 256) se += expf(row[o] - mx);
  se = blockSumF(se);
  float lse = mx + logf(se);
  for (int o = threadIdx.x; o < NOUT; o += 256) out[(size_t)n * NOUT + o] = row[o] - lse;
}

// ---------------- host-side GEMM dispatch ----------------
static void gemmLaunch(hipStream_t st, const float* A, int lda, const float* B, int ldb,
                       float* C, int ldc, int M, int Nn, int K, float alpha, float beta,
                       const float* bias, bool transb, int act, int splitk)
{
  dim3 grid(Nn / 64, M / 64, splitk), block(256);
  int kChunk = K / splitk;
  if (!transb && act == 0)
    gemm64<false,0><<<grid, block, 0, st>>>(A, lda, B, ldb, C, ldc, K, kChunk, alpha, beta, bias);
  else if (!transb)
    gemm64<false,1><<<grid, block, 0, st>>>(A, lda, B, ldb, C, ldc, K, kChunk, alpha, beta, bias);
  else if (act == 0)
    gemm64<true,0><<<grid, block, 0, st>>>(A, lda, B, ldb, C, ldc, K, kChunk, alpha, beta, bias);
  else
    gemm64<true,1><<<grid, block, 0, st>>>(A, lda, B, ldb, C, ldc, K, kChunk, alpha, beta, bias);
}

extern "C" void kernel_launch(void* const* d_in, const int* in_sizes, int n_in,
                              void* d_out, int out_size, void* d_ws, size_t ws_size,
                              hipStream_t stream)
{
  (void)in_sizes; (void)n_in; (void)out_size; (void)ws_size;
  const float* x0      = (const float*)d_in[0];
  const float* K1      = (const float*)d_in[1];
  const float* K2      = (const float*)d_in[2];
  const float* KNclose = (const float*)d_in[3];
  const float* KN1     = (const float*)d_in[4];
  const float* KN2     = (const float*)d_in[5];
  const float* lin1w   = (const float*)d_in[6];
  const float* lin1b   = (const float*)d_in[7];
  const float* lin2w   = (const float*)d_in[8];
  const float* lin2b   = (const float*)d_in[9];
  const int*   ei      = (const int*)d_in[10];
  const int*   ej      = (const int*)d_in[11];
  float* out = (float*)d_out;

  float* base   = (float*)d_ws;
  float* f      = base;                 // [CF][N]  current node features
  float* u      = base + 1 * (size_t)CN; // [CF][N] double_layer intermediate / y
  float* lapT   = base + 2 * (size_t)CN; // [N][CF] laplacian (node-major); reused as x1
  float* ft     = base + 3 * (size_t)CN; // [N][CF] transposed features; reused as yT
  float* logits = base + 4 * (size_t)CN; // [N][NOUT] = 4*CN floats
  float* wE     = base + 8 * (size_t)CN; // [E_TOT]
  float* sq     = wE + E_TOT;            // [N]
  float* deg    = sq + N_NODES;          // [N] (deg, then dis in-place)
  float* sArr   = deg + N_NODES;         // [CF]
  float* hArr   = sArr + CF;             // [CF]
  float* G      = hArr + CF;             // [CF][CF]
  float* c0     = G + CF * CF;           // [1]
  double* dScal = (double*)(base + 9 * (size_t)CN); // [0,1]=mean/var acc, [2,3]=S1,S2
  double* mvAcc = dScal;
  double* dS    = dScal + 2;

  // ---- opening double_layer: f = K2·tanh(LN(K1·x0)) ----
  hipMemsetAsync(mvAcc, 0, 2 * sizeof(double), stream);
  gemmLaunch(stream, K1, CIN, x0, N_NODES, u, N_NODES, CF, N_NODES, CIN, 1.f, 0.f, nullptr, false, 0, 1);
  reduceMV<<<512, 256, 0, stream>>>(u, CN / 4, mvAcc);
  tanhNormK<<<512, 256, 0, stream>>>(u, CN / 4, mvAcc, 1.0 / (double)CN);
  gemmLaunch(stream, K2, CF, u, N_NODES, f, N_NODES, CF, N_NODES, CF, 1.f, 0.f, nullptr, false, 0, 1);

  for (int L = 0; L < NLAYER; L++) {
    const float* kn1 = KN1 + (size_t)L * CF * 2 * CF;   // [CF][2CF]
    const float* kn2 = KN2 + (size_t)L * CF * CF;       // [CF][CF]

    hipMemsetAsync(dScal, 0, 4 * sizeof(double), stream);
    hipMemsetAsync(deg,   0, N_NODES * sizeof(float), stream);
    hipMemsetAsync(lapT,  0, (size_t)CN * sizeof(float), stream);
    hipMemsetAsync(G,     0, CF * CF * sizeof(float), stream);

    transposeK<<<dim3(N_NODES/32, CF/32), dim3(32, 8), 0, stream>>>(f, ft, CF, N_NODES);
    rowSqK<<<N_NODES, 256, 0, stream>>>(ft, sq, dS);
    colSHK<<<CF, 256, 0, stream>>>(f, sq, sArr, hArr);
    // G = f·f^T  (256x256, K=4096, split-K=16 with atomic accumulate)
    gemmLaunch(stream, f, N_NODES, f, N_NODES, G, CF, CF, CF, N_NODES, 1.f, 0.f, nullptr, true, 0, 16);
    finalizeStdK<<<1, 256, 0, stream>>>(sArr, hArr, G, dS, c0);
    edgeWK<<<E_TOT/4, 256, 0, stream>>>(ei, ej, ft, sq, c0, wE, deg);
    disKK<<<N_NODES/256, 256, 0, stream>>>(deg);
    scatterLapK<<<E0_EDGES, 256, 0, stream>>>(ei, ej, ft, wE, deg, lapT);

    // u = KN1[:, :CF]·f + KN1[:, CF:]·lapT^T
    gemmLaunch(stream, kn1,      2*CF, f,    N_NODES, u, N_NODES, CF, N_NODES, CF, 1.f, 0.f, nullptr, false, 0, 1);
    gemmLaunch(stream, kn1 + CF, 2*CF, lapT, CF,      u, N_NODES, CF, N_NODES, CF, 1.f, 1.f, nullptr, true,  0, 1);
    reduceMV<<<512, 256, 0, stream>>>(u, CN / 4, mvAcc);
    tanhNormK<<<512, 256, 0, stream>>>(u, CN / 4, mvAcc, 1.0 / (double)CN);
    // f += 0.1 * KN2·u
    gemmLaunch(stream, kn2, CF, u, N_NODES, f, N_NODES, CF, N_NODES, CF, 0.1f, 1.f, nullptr, false, 0, 1);
  }

  // ---- close: y = KNclose·f ; yT ; x1 = elu(yT·lin1^T + b1) ; logits ; log_softmax ----
  gemmLaunch(stream, KNclose, CF, f, N_NODES, u, N_NODES, CF, N_NODES, CF, 1.f, 0.f, nullptr, false, 0, 1);
  transposeK<<<dim3(N_NODES/32, CF/32), dim3(32, 8), 0, stream>>>(u, ft, CF, N_NODES);
  gemmLaunch(stream, ft,   CF, lin1w, CF, lapT,   CF,   N_NODES, CF,   CF, 1.f, 0.f, lin1b, true, 1, 1);
  gemmLaunch(stream, lapT, CF, lin2w, CF, logits, NOUT, N_NODES, NOUT, CF, 1.f, 0.f, lin2b, true, 0, 1);
  logSoftmaxK<<<N_NODES, 256, 0, stream>>>(logits, out);
}

// Round 2
// 3032.100 us; speedup vs baseline: 1.1921x; 1.1921x over previous
//
#include <hip/hip_runtime.h>
#include <hip/hip_bf16.h>

// Problem constants (fixed instance)
#define N_NODES 4096
#define CF      256        // nopen == nhid == nNclose
#define CIN     64
#define E0_EDGES 65536
#define E_TOT   (E0_EDGES + N_NODES)   // with self loops appended
#define NLAYER  8
#define NOUT    1024
#define CN      (CF * N_NODES)         // 1048576 elements

// ---------------- block reduction helpers (blockDim.x == 256) ----------------
__device__ __forceinline__ float waveSumF(float v){
  #pragma unroll
  for (int o = 32; o; o >>= 1) v += __shfl_xor(v, o);
  return v;
}
__device__ __forceinline__ double waveSumD(double v){
  #pragma unroll
  for (int o = 32; o; o >>= 1) v += __shfl_xor(v, o);
  return v;
}
__device__ __forceinline__ float waveMaxF(float v){
  #pragma unroll
  for (int o = 32; o; o >>= 1) v = fmaxf(v, __shfl_xor(v, o));
  return v;
}
__device__ float blockSumF(float v){
  __shared__ float sm[4];
  v = waveSumF(v);
  int l = threadIdx.x & 63, w = threadIdx.x >> 6;
  __syncthreads();
  if (l == 0) sm[w] = v;
  __syncthreads();
  return sm[0] + sm[1] + sm[2] + sm[3];
}
__device__ double blockSumD(double v){
  __shared__ double sm[4];
  v = waveSumD(v);
  int l = threadIdx.x & 63, w = threadIdx.x >> 6;
  __syncthreads();
  if (l == 0) sm[w] = v;
  __syncthreads();
  return sm[0] + sm[1] + sm[2] + sm[3];
}
__device__ float blockMaxF(float v){
  __shared__ float sm[4];
  v = waveMaxF(v);
  int l = threadIdx.x & 63, w = threadIdx.x >> 6;
  __syncthreads();
  if (l == 0) sm[w] = v;
  __syncthreads();
  return fmaxf(fmaxf(sm[0], sm[1]), fmaxf(sm[2], sm[3]));
}

// ---------------- f32 tiled GEMM: C[M,N] = alpha*A·op(B) + beta*C (+bias, act) ----
template<bool TRANSB, int ACT>  // ACT: 0 none, 1 elu
__global__ __launch_bounds__(256)
void gemm64(const float* __restrict__ A, int lda,
            const float* __restrict__ B, int ldb,
            float* __restrict__ C, int ldc,
            int K, int kChunk, float alpha, float beta,
            const float* __restrict__ bias)
{
  __shared__ float As[16][65];
  __shared__ float Bs[16][65];
  const int tid = threadIdx.x;
  const int tx = tid & 15, ty = tid >> 4;
  const int row0 = blockIdx.y * 64, col0 = blockIdx.x * 64;
  const int kStart = blockIdx.z * kChunk;

  const int am = tid >> 2;          // 0..63
  const int ak = (tid & 3) * 4;     // 0,4,8,12
  const int bk = tid >> 4;          // 0..15
  const int bn = (tid & 15) * 4;    // 0..60

  float acc[4][4] = {};

  for (int k0 = kStart; k0 < kStart + kChunk; k0 += 16) {
    float4 av = *(const float4*)(A + (size_t)(row0 + am) * lda + k0 + ak);
    As[ak+0][am] = av.x; As[ak+1][am] = av.y; As[ak+2][am] = av.z; As[ak+3][am] = av.w;
    if (TRANSB) {
      float4 bv = *(const float4*)(B + (size_t)(col0 + am) * ldb + k0 + ak);
      Bs[ak+0][am] = bv.x; Bs[ak+1][am] = bv.y; Bs[ak+2][am] = bv.z; Bs[ak+3][am] = bv.w;
    } else {
      float4 bv = *(const float4*)(B + (size_t)(k0 + bk) * ldb + col0 + bn);
      Bs[bk][bn+0] = bv.x; Bs[bk][bn+1] = bv.y; Bs[bk][bn+2] = bv.z; Bs[bk][bn+3] = bv.w;
    }
    __syncthreads();
    #pragma unroll
    for (int k = 0; k < 16; k++) {
      float a[4], b[4];
      #pragma unroll
      for (int i = 0; i < 4; i++) a[i] = As[k][ty*4 + i];
      #pragma unroll
      for (int j = 0; j < 4; j++) b[j] = Bs[k][tx*4 + j];
      #pragma unroll
      for (int i = 0; i < 4; i++)
        #pragma unroll
        for (int j = 0; j < 4; j++) acc[i][j] += a[i] * b[j];
    }
    __syncthreads();
  }

  if (gridDim.z > 1) {
    #pragma unroll
    for (int i = 0; i < 4; i++)
      #pragma unroll
      for (int j = 0; j < 4; j++)
        unsafeAtomicAdd(&C[(size_t)(row0 + ty*4 + i) * ldc + col0 + tx*4 + j], alpha * acc[i][j]);
  } else {
    #pragma unroll
    for (int i = 0; i < 4; i++) {
      float* cp = C + (size_t)(row0 + ty*4 + i) * ldc + col0 + tx*4;
      #pragma unroll
      for (int j = 0; j < 4; j++) {
        float v = alpha * acc[i][j];
        if (beta != 0.0f) v += beta * cp[j];
        if (bias) v += bias[col0 + tx*4 + j];
        if (ACT == 1) v = (v > 0.0f) ? v : expm1f(v);
        cp[j] = v;
      }
    }
  }
}

// ---------------- transpose: in[R][Cc] -> out[Cc][R] ----------------
__global__ __launch_bounds__(256)
void transposeK(const float* __restrict__ in, float* __restrict__ out, int R, int Cc)
{
  __shared__ float t[32][33];
  int x  = blockIdx.x * 32 + threadIdx.x;
  int y0 = blockIdx.y * 32;
  for (int dy = threadIdx.y; dy < 32; dy += 8)
    t[dy][threadIdx.x] = in[(size_t)(y0 + dy) * Cc + x];
  __syncthreads();
  int ox  = y0 + threadIdx.x;
  int oy0 = blockIdx.x * 32;
  for (int dy = threadIdx.y; dy < 32; dy += 8)
    out[(size_t)(oy0 + dy) * R + ox] = t[threadIdx.x][dy];
}

// ---------------- whole-tensor mean/var reduce (double atomics) ----------------
__global__ __launch_bounds__(256)
void reduceMV(const float* __restrict__ x, int n4, double* acc)
{
  double s = 0, s2 = 0;
  for (int i = blockIdx.x * blockDim.x + threadIdx.x; i < n4; i += gridDim.x * blockDim.x) {
    float4 v = ((const float4*)x)[i];
    s  += (double)v.x + v.y + v.z + v.w;
    s2 += (double)v.x*v.x + (double)v.y*v.y + (double)v.z*v.z + (double)v.w*v.w;
  }
  s  = blockSumD(s);
  s2 = blockSumD(s2);
  if (threadIdx.x == 0) { unsafeAtomicAdd(acc, s); unsafeAtomicAdd(acc + 1, s2); }
}

__global__ __launch_bounds__(256)
void tanhNormK(float* __restrict__ x, int n4, const double* __restrict__ acc, double invCount)
{
  double m   = acc[0] * invCount;
  double var = acc[1] * invCount - m * m;
  float rs = (float)(1.0 / sqrt(var + 1e-5));
  float mf = (float)m;
  for (int i = blockIdx.x * blockDim.x + threadIdx.x; i < n4; i += gridDim.x * blockDim.x) {
    float4 v = ((const float4*)x)[i];
    v.x = tanhf((v.x - mf) * rs);
    v.y = tanhf((v.y - mf) * rs);
    v.z = tanhf((v.z - mf) * rs);
    v.w = tanhf((v.w - mf) * rs);
    ((float4*)x)[i] = v;
  }
}

// ---------------- per-node squared norms (from ft[N][CF]) + S1,S2 ----------------
__global__ __launch_bounds__(256)
void rowSqK(const float* __restrict__ ft, float* __restrict__ sq, double* __restrict__ dS)
{
  int n = blockIdx.x;
  float v = ft[(size_t)n * CF + threadIdx.x];
  float t = blockSumF(v * v);
  if (threadIdx.x == 0) {
    sq[n] = t;
    unsafeAtomicAdd(dS,     (double)t);
    unsafeAtomicAdd(dS + 1, (double)t * t);
  }
}

// ---------------- per-channel sums ----------------
__global__ __launch_bounds__(256)
void colSHK(const float* __restrict__ f, const float* __restrict__ sq,
            float* __restrict__ s, float* __restrict__ h)
{
  int c = blockIdx.x;
  double ps = 0, ph = 0;
  for (int n = threadIdx.x; n < N_NODES; n += 256) {
    float v = f[(size_t)c * N_NODES + n];
    ps += v;
    ph += (double)v * sq[n];
  }
  ps = blockSumD(ps);
  ph = blockSumD(ph);
  if (threadIdx.x == 0) { s[c] = (float)ps; h[c] = (float)ph; }
}

// ---------------- closed-form std of the NxN distance matrix ----------------
__global__ __launch_bounds__(256)
void finalizeStdK(const float* __restrict__ s, const float* __restrict__ h,
                  const float* __restrict__ G, const double* __restrict__ dS,
                  float* __restrict__ c0)
{
  int c = threadIdx.x;
  double sd = (double)s[c] * s[c];
  double hd = (double)h[c] * s[c];
  double gf = 0;
  for (int i = c; i < CF * CF; i += 256) { double g = G[i]; gf += g * g; }
  sd = blockSumD(sd);
  hd = blockSumD(hd);
  gf = blockSumD(gf);
  if (c == 0) {
    double S1 = dS[0], S2 = dS[1];
    double NN = (double)N_NODES;
    double sum1 = 2.0 * NN * S1 - 2.0 * sd;
    double sum2 = 2.0 * NN * S2 + 2.0 * S1 * S1 + 4.0 * gf - 8.0 * hd;
    double n2 = NN * NN;
    double var = (sum2 - sum1 * sum1 / n2) / (n2 - 1.0);
    double sdev = sqrt(var > 0 ? var : 0);
    c0[0] = (float)(-2.0 / sdev);
  }
}

// ---------------- edge affinities (wave per edge) + deg ----------------
__global__ __launch_bounds__(256)
void edgeWK(const int* __restrict__ ei, const int* __restrict__ ej,
            const float* __restrict__ ft, const float* __restrict__ sq,
            const float* __restrict__ c0,
            float* __restrict__ wE, float* __restrict__ deg)
{
  int wid  = (blockIdx.x * 256 + threadIdx.x) >> 6;
  int lane = threadIdx.x & 63;
  if (wid >= E_TOT) return;
  int i, j;
  if (wid < E0_EDGES) { i = ei[wid]; j = ej[wid]; } else { i = j = wid - E0_EDGES; }
  float4 a = ((const float4*)(ft + (size_t)i * CF))[lane];
  float4 b = ((const float4*)(ft + (size_t)j * CF))[lane];
  float d = a.x*b.x + a.y*b.y + a.z*b.z + a.w*b.w;
  d = waveSumF(d);
  if (lane == 0) {
    float dist = fmaxf(sq[i] + sq[j] - 2.0f * d, 0.0f);
    float w = expf(c0[0] * dist);
    wE[wid] = w;
    unsafeAtomicAdd(deg + j, w);
  }
}

__global__ void disKK(float* deg)
{
  int n = blockIdx.x * blockDim.x + threadIdx.x;
  if (n < N_NODES) { float d = deg[n]; deg[n] = d > 0.0f ? rsqrtf(d) : 0.0f; }
}

// ---------------- CSR build (once per launch; edge list is a fixed input) -----
__global__ __launch_bounds__(256)
void csrCountK(const int* __restrict__ ei, const int* __restrict__ ej,
               int* __restrict__ cntO, int* __restrict__ cntI)
{
  int e = blockIdx.x * 256 + threadIdx.x;
  if (e < E0_EDGES) {
    atomicAdd(&cntO[ei[e]], 1);
    atomicAdd(&cntI[ej[e]], 1);
  }
}

// exclusive scan of both count arrays (4096 each); one block of 256 threads
__global__ __launch_bounds__(256)
void csrScanK(const int* __restrict__ cntO, const int* __restrict__ cntI,
              int* __restrict__ ofsO, int* __restrict__ ofsI)
{
  __shared__ int smO[256], smI[256];
  int t = threadIdx.x;
  int lo[16], li[16];
  int sO = 0, sI = 0;
  #pragma unroll
  for (int k = 0; k < 16; k++) {
    lo[k] = cntO[t * 16 + k]; li[k] = cntI[t * 16 + k];
    sO += lo[k]; sI += li[k];
  }
  smO[t] = sO; smI[t] = sI;
  __syncthreads();
  for (int off = 1; off < 256; off <<= 1) {
    int aO = (t >= off) ? smO[t - off] : 0;
    int aI = (t >= off) ? smI[t - off] : 0;
    __syncthreads();
    smO[t] += aO; smI[t] += aI;
    __syncthreads();
  }
  int bO = smO[t] - sO;   // exclusive base
  int bI = smI[t] - sI;
  #pragma unroll
  for (int k = 0; k < 16; k++) {
    ofsO[t * 16 + k] = bO; bO += lo[k];
    ofsI[t * 16 + k] = bI; bI += li[k];
  }
}

__global__ __launch_bounds__(256)
void csrFillK(const int* __restrict__ ei, const int* __restrict__ ej,
              const int* __restrict__ ofsO, const int* __restrict__ ofsI,
              int* __restrict__ curO, int* __restrict__ curI,
              int2* __restrict__ lstO, int2* __restrict__ lstI)
{
  int e = blockIdx.x * 256 + threadIdx.x;
  if (e >= E0_EDGES) return;
  int i = ei[e], j = ej[e];
  int p = atomicAdd(&curO[i], 1); lstO[ofsO[i] + p] = make_int2(j, e);
  int q = atomicAdd(&curI[j], 1); lstI[ofsI[j] + q] = make_int2(i, e);
}

// ---------------- per-edge normalized weight squared ----------------
__global__ __launch_bounds__(256)
void wsqK(const int* __restrict__ ei, const int* __restrict__ ej,
          const float* __restrict__ wE, const float* __restrict__ dis,
          float* __restrict__ Wsq)
{
  int e = blockIdx.x * 256 + threadIdx.x;
  if (e < E0_EDGES) {
    float W = dis[ei[e]] * wE[e] * dis[ej[e]];
    Wsq[e] = W * W;
  }
}

// ---------------- graph Laplacian gather into lapT[N][CF] (no atomics) --------
__global__ __launch_bounds__(256)
void gatherLapK(const int2* __restrict__ lstO, const int2* __restrict__ lstI,
                const int* __restrict__ ofsO, const int* __restrict__ ofsI,
                const int* __restrict__ cntO, const int* __restrict__ cntI,
                const float* __restrict__ Wsq, const float* __restrict__ ft,
                float* __restrict__ lapT)
{
  int n = blockIdx.x, c = threadIdx.x;
  float own = ft[(size_t)n * CF + c];
  float acc = 0.0f;
  int o0 = ofsO[n], oc = cntO[n];
  for (int k = 0; k < oc; k++) {
    int2 oe = lstO[o0 + k];
    acc += Wsq[oe.y] * (own - ft[(size_t)oe.x * CF + c]);
  }
  int i0 = ofsI[n], ic = cntI[n];
  for (int k = 0; k < ic; k++) {
    int2 oe = lstI[i0 + k];
    acc -= Wsq[oe.y] * (ft[(size_t)oe.x * CF + c] - own);
  }
  lapT[(size_t)n * CF + c] = acc;
}

// ---------------- row log-softmax, f32 out ----------------
__global__ __launch_bounds__(256)
void logSoftmaxK(const float* __restrict__ logits, float* __restrict__ out)
{
  int n = blockIdx.x;
  const float* row = logits + (size_t)n * NOUT;
  float mx = -1e30f;
  for (int o = threadIdx.x; o < NOUT; o += 256) mx = fmaxf(mx, row[o]);
  mx = blockMaxF(mx);
  float se = 0;
  for (int o = threadIdx.x; o < NOUT; o += 256) se += expf(row[o] - mx);
  se = blockSumF(se);
  float lse = mx + logf(se);
  for (int o = threadIdx.x; o < NOUT; o += 256) out[(size_t)n * NOUT + o] = row[o] - lse;
}

// ---------------- host-side GEMM dispatch ----------------
static void gemmLaunch(hipStream_t st, const float* A, int lda, const float* B, int ldb,
                       float* C, int ldc, int M, int Nn, int K, float alpha, float beta,
                       const float* bias, bool transb, int act, int splitk)
{
  dim3 grid(Nn / 64, M / 64, splitk), block(256);
  int kChunk = K / splitk;
  if (!transb && act == 0)
    gemm64<false,0><<<grid, block, 0, st>>>(A, lda, B, ldb, C, ldc, K, kChunk, alpha, beta, bias);
  else if (!transb)
    gemm64<false,1><<<grid, block, 0, st>>>(A, lda, B, ldb, C, ldc, K, kChunk, alpha, beta, bias);
  else if (act == 0)
    gemm64<true,0><<<grid, block, 0, st>>>(A, lda, B, ldb, C, ldc, K, kChunk, alpha, beta, bias);
  else
    gemm64<true,1><<<grid, block, 0, st>>>(A, lda, B, ldb, C, ldc, K, kChunk, alpha, beta, bias);
}

extern "C" void kernel_launch(void* const* d_in, const int* in_sizes, int n_in,
                              void* d_out, int out_size, void* d_ws, size_t ws_size,
                              hipStream_t stream)
{
  (void)in_sizes; (void)n_in; (void)out_size; (void)ws_size;
  const float* x0      = (const float*)d_in[0];
  const float* K1      = (const float*)d_in[1];
  const float* K2      = (const float*)d_in[2];
  const float* KNclose = (const float*)d_in[3];
  const float* KN1     = (const float*)d_in[4];
  const float* KN2     = (const float*)d_in[5];
  const float* lin1w   = (const float*)d_in[6];
  const float* lin1b   = (const float*)d_in[7];
  const float* lin2w   = (const float*)d_in[8];
  const float* lin2b   = (const float*)d_in[9];
  const int*   ei      = (const int*)d_in[10];
  const int*   ej      = (const int*)d_in[11];
  float* out = (float*)d_out;

  float* base   = (float*)d_ws;
  float* f      = base;                  // [CF][N]
  float* u      = base + 1 * (size_t)CN; // [CF][N]
  float* lapT   = base + 2 * (size_t)CN; // [N][CF]; reused as x1 at close
  float* ft     = base + 3 * (size_t)CN; // [N][CF]
  float* logits = base + 4 * (size_t)CN; // [N][NOUT] = 4*CN floats
  float* wE     = base + 8 * (size_t)CN; // [E_TOT]
  float* sq     = wE + E_TOT;            // [N]
  float* deg    = sq + N_NODES;          // [N] (deg -> dis in place)
  float* sArr   = deg + N_NODES;         // [CF]
  float* hArr   = sArr + CF;             // [CF]
  float* G      = hArr + CF;             // [CF][CF]
  float* c0     = G + CF * CF;           // [1]
  double* dScal = (double*)(base + 9 * (size_t)CN); // 4 doubles
  double* mvAcc = dScal;
  double* dS    = dScal + 2;

  // CSR region (ints) after the doubles
  int* ibase = (int*)(base + 9 * (size_t)CN + 16);
  int*  cntO = ibase;                    // [N]
  int*  cntI = cntO + N_NODES;           // [N]
  int*  ofsO = cntI + N_NODES;           // [N]
  int*  ofsI = ofsO + N_NODES;           // [N]
  int*  curO = ofsI + N_NODES;           // [N]
  int*  curI = curO + N_NODES;           // [N]
  int2* lstO = (int2*)(curI + N_NODES);  // [E0]
  int2* lstI = lstO + E0_EDGES;          // [E0]
  float* Wsq = (float*)(lstI + E0_EDGES);// [E0]

  // ---- CSR build (edge structure is layer-invariant) ----
  hipMemsetAsync(cntO, 0, 6 * N_NODES * sizeof(int), stream); // cntO..curI
  csrCountK<<<E0_EDGES/256, 256, 0, stream>>>(ei, ej, cntO, cntI);
  csrScanK<<<1, 256, 0, stream>>>(cntO, cntI, ofsO, ofsI);
  csrFillK<<<E0_EDGES/256, 256, 0, stream>>>(ei, ej, ofsO, ofsI, curO, curI, lstO, lstI);

  // ---- opening double_layer: f = K2·tanh(LN(K1·x0)) ----
  hipMemsetAsync(mvAcc, 0, 2 * sizeof(double), stream);
  gemmLaunch(stream, K1, CIN, x0, N_NODES, u, N_NODES, CF, N_NODES, CIN, 1.f, 0.f, nullptr, false, 0, 1);
  reduceMV<<<512, 256, 0, stream>>>(u, CN / 4, mvAcc);
  tanhNormK<<<512, 256, 0, stream>>>(u, CN / 4, mvAcc, 1.0 / (double)CN);
  gemmLaunch(stream, K2, CF, u, N_NODES, f, N_NODES, CF, N_NODES, CF, 1.f, 0.f, nullptr, false, 0, 1);

  for (int L = 0; L < NLAYER; L++) {
    const float* kn1 = KN1 + (size_t)L * CF * 2 * CF;   // [CF][2CF]
    const float* kn2 = KN2 + (size_t)L * CF * CF;       // [CF][CF]

    hipMemsetAsync(dScal, 0, 4 * sizeof(double), stream);
    hipMemsetAsync(deg,   0, N_NODES * sizeof(float), stream);
    hipMemsetAsync(G,     0, CF * CF * sizeof(float), stream);

    transposeK<<<dim3(N_NODES/32, CF/32), dim3(32, 8), 0, stream>>>(f, ft, CF, N_NODES);
    rowSqK<<<N_NODES, 256, 0, stream>>>(ft, sq, dS);
    colSHK<<<CF, 256, 0, stream>>>(f, sq, sArr, hArr);
    gemmLaunch(stream, f, N_NODES, f, N_NODES, G, CF, CF, CF, N_NODES, 1.f, 0.f, nullptr, true, 0, 16);
    finalizeStdK<<<1, 256, 0, stream>>>(sArr, hArr, G, dS, c0);
    edgeWK<<<E_TOT/4, 256, 0, stream>>>(ei, ej, ft, sq, c0, wE, deg);
    disKK<<<N_NODES/256, 256, 0, stream>>>(deg);
    wsqK<<<E0_EDGES/256, 256, 0, stream>>>(ei, ej, wE, deg, Wsq);
    gatherLapK<<<N_NODES, 256, 0, stream>>>(lstO, lstI, ofsO, ofsI, cntO, cntI, Wsq, ft, lapT);

    // u = KN1[:, :CF]·f + KN1[:, CF:]·lapT^T
    gemmLaunch(stream, kn1,      2*CF, f,    N_NODES, u, N_NODES, CF, N_NODES, CF, 1.f, 0.f, nullptr, false, 0, 1);
    gemmLaunch(stream, kn1 + CF, 2*CF, lapT, CF,      u, N_NODES, CF, N_NODES, CF, 1.f, 1.f, nullptr, true,  0, 1);
    reduceMV<<<512, 256, 0, stream>>>(u, CN / 4, mvAcc);
    tanhNormK<<<512, 256, 0, stream>>>(u, CN / 4, mvAcc, 1.0 / (double)CN);
    // f += 0.1 * KN2·u
    gemmLaunch(stream, kn2, CF, u, N_NODES, f, N_NODES, CF, N_NODES, CF, 0.1f, 1.f, nullptr, false, 0, 1);
  }

  // ---- close ----
  gemmLaunch(stream, KNclose, CF, f, N_NODES, u, N_NODES, CF, N_NODES, CF, 1.f, 0.f, nullptr, false, 0, 1);
  transposeK<<<dim3(N_NODES/32, CF/32), dim3(32, 8), 0, stream>>>(u, ft, CF, N_NODES);
  gemmLaunch(stream, ft,   CF, lin1w, CF, lapT,   CF,   N_NODES, CF,   CF, 1.f, 0.f, lin1b, true, 1, 1);
  gemmLaunch(stream, lapT, CF, lin2w, CF, logits, NOUT, N_NODES, NOUT, CF, 1.f, 0.f, lin2b, true, 0, 1);
  logSoftmaxK<<<N_NODES, 256, 0, stream>>>(logits, out);
}

// Round 3
// 1626.035 us; speedup vs baseline: 2.2229x; 1.8647x over previous
//
#include <hip/hip_runtime.h>
#include <hip/hip_bf16.h>

// Problem constants (fixed instance)
#define N_NODES 4096
#define CF      256        // nopen == nhid == nNclose
#define CIN     64
#define E0_EDGES 65536
#define E_TOT   (E0_EDGES + N_NODES)
#define NLAYER  8
#define NOUT    1024
#define CN      (CF * N_NODES)

typedef __attribute__((ext_vector_type(8))) short s8v;   // 8 bf16 (4 VGPRs)
typedef __attribute__((ext_vector_type(4))) float f4v;   // MFMA acc

__device__ __forceinline__ unsigned short f2bf(float x){
  unsigned int u = __builtin_bit_cast(unsigned int, x);
  return (unsigned short)((u + 0x7FFFu + ((u >> 16) & 1u)) >> 16);
}
__device__ __forceinline__ float bf2f(unsigned short h){
  unsigned int u = ((unsigned int)h) << 16;
  return __builtin_bit_cast(float, u);
}

// ---------------- block reduction helpers (256 threads) ----------------
__device__ __forceinline__ float waveSumF(float v){
  #pragma unroll
  for (int o = 32; o; o >>= 1) v += __shfl_xor(v, o);
  return v;
}
__device__ __forceinline__ double waveSumD(double v){
  #pragma unroll
  for (int o = 32; o; o >>= 1) v += __shfl_xor(v, o);
  return v;
}
__device__ __forceinline__ float waveMaxF(float v){
  #pragma unroll
  for (int o = 32; o; o >>= 1) v = fmaxf(v, __shfl_xor(v, o));
  return v;
}
__device__ float blockSumF(float v){
  __shared__ float sm[4];
  v = waveSumF(v);
  int l = threadIdx.x & 63, w = threadIdx.x >> 6;
  __syncthreads();
  if (l == 0) sm[w] = v;
  __syncthreads();
  return sm[0] + sm[1] + sm[2] + sm[3];
}
__device__ double blockSumD(double v){
  __shared__ double sm[4];
  v = waveSumD(v);
  int l = threadIdx.x & 63, w = threadIdx.x >> 6;
  __syncthreads();
  if (l == 0) sm[w] = v;
  __syncthreads();
  return sm[0] + sm[1] + sm[2] + sm[3];
}
__device__ float blockMaxF(float v){
  __shared__ float sm[4];
  v = waveMaxF(v);
  int l = threadIdx.x & 63, w = threadIdx.x >> 6;
  __syncthreads();
  if (l == 0) sm[w] = v;
  __syncthreads();
  return fmaxf(fmaxf(sm[0], sm[1]), fmaxf(sm[2], sm[3]));
}

// ---------------- MFMA GEMM: C[M,N] = alpha*A·B^T (+beta*C, +bias, act) -------
// A: [M][lda] row-major, B: [N][ldb] row-major (both K-contiguous).
// 64x64 tile, BK=64, 4 waves as 2x2 of 32x32, mfma_f32_16x16x32_bf16.
// f32 inputs split hi+lo bf16; 3 MFMA terms per product -> ~f32 accuracy.
// gridDim.z>1 => split-K atomic accumulation (beta must be 0, C pre-zeroed).
__device__ __forceinline__ void cvt8(const float* vs, s8v* ph, s8v* pl){
  s8v h, l;
  #pragma unroll
  for (int i = 0; i < 8; i++){
    unsigned short hb = f2bf(vs[i]);
    h[i] = (short)hb;
    l[i] = (short)f2bf(vs[i] - bf2f(hb));
  }
  *ph = h; *pl = l;
}

#define MF(a,b,c) c = __builtin_amdgcn_mfma_f32_16x16x32_bf16(a, b, c, 0, 0, 0)

template<int ACT>  // 0 none, 1 elu
__global__ __launch_bounds__(256)
void gemmMF(const float* __restrict__ A, int lda,
            const float* __restrict__ B, int ldb,
            float* __restrict__ C, int ldc,
            int kChunk, float alpha, float beta,
            const float* __restrict__ bias)
{
  __shared__ unsigned short Ah[64][72], Al[64][72], Bh[64][72], Bl[64][72];
  const int tid = threadIdx.x;
  const int r  = tid >> 2;           // 0..63 staging row
  const int kq = (tid & 3) * 16;     // 0,16,32,48
  const int row0 = blockIdx.y * 64, col0 = blockIdx.x * 64;
  const int kStart = blockIdx.z * kChunk;

  const int wid = tid >> 6, lane = tid & 63;
  const int wr = (wid >> 1) * 32, wc = (wid & 1) * 32;
  const int fr = lane & 15, fk = (lane >> 4) * 8;

  f4v acc[2][2] = {};

  for (int k0 = kStart; k0 < kStart + kChunk; k0 += 64) {
    const float* ap = A + (size_t)(row0 + r) * lda + k0 + kq;
    const float* bp = B + (size_t)(col0 + r) * ldb + k0 + kq;
    float av[16], bv[16];
    *(float4*)&av[0]  = *(const float4*)(ap + 0);
    *(float4*)&av[4]  = *(const float4*)(ap + 4);
    *(float4*)&av[8]  = *(const float4*)(ap + 8);
    *(float4*)&av[12] = *(const float4*)(ap + 12);
    *(float4*)&bv[0]  = *(const float4*)(bp + 0);
    *(float4*)&bv[4]  = *(const float4*)(bp + 4);
    *(float4*)&bv[8]  = *(const float4*)(bp + 8);
    *(float4*)&bv[12] = *(const float4*)(bp + 12);
    __syncthreads();   // previous iteration's LDS reads done
    cvt8(&av[0], (s8v*)&Ah[r][kq],     (s8v*)&Al[r][kq]);
    cvt8(&av[8], (s8v*)&Ah[r][kq + 8], (s8v*)&Al[r][kq + 8]);
    cvt8(&bv[0], (s8v*)&Bh[r][kq],     (s8v*)&Bl[r][kq]);
    cvt8(&bv[8], (s8v*)&Bh[r][kq + 8], (s8v*)&Bl[r][kq + 8]);
    __syncthreads();

    #pragma unroll
    for (int ks = 0; ks < 64; ks += 32) {
      s8v ah0 = *(const s8v*)&Ah[wr + fr][ks + fk];
      s8v ah1 = *(const s8v*)&Ah[wr + 16 + fr][ks + fk];
      s8v al0 = *(const s8v*)&Al[wr + fr][ks + fk];
      s8v al1 = *(const s8v*)&Al[wr + 16 + fr][ks + fk];
      s8v bh0 = *(const s8v*)&Bh[wc + fr][ks + fk];
      s8v bh1 = *(const s8v*)&Bh[wc + 16 + fr][ks + fk];
      s8v bl0 = *(const s8v*)&Bl[wc + fr][ks + fk];
      s8v bl1 = *(const s8v*)&Bl[wc + 16 + fr][ks + fk];
      MF(ah0, bh0, acc[0][0]); MF(ah0, bl0, acc[0][0]); MF(al0, bh0, acc[0][0]);
      MF(ah0, bh1, acc[0][1]); MF(ah0, bl1, acc[0][1]); MF(al0, bh1, acc[0][1]);
      MF(ah1, bh0, acc[1][0]); MF(ah1, bl0, acc[1][0]); MF(al1, bh0, acc[1][0]);
      MF(ah1, bh1, acc[1][1]); MF(ah1, bl1, acc[1][1]); MF(al1, bh1, acc[1][1]);
    }
  }

  // epilogue: D row = wr + m*16 + (lane>>4)*4 + q ; col = wc + n*16 + (lane&15)
  if (gridDim.z > 1) {
    #pragma unroll
    for (int m = 0; m < 2; m++)
      #pragma unroll
      for (int n = 0; n < 2; n++)
        #pragma unroll
        for (int q = 0; q < 4; q++) {
          int row = row0 + wr + m * 16 + (lane >> 4) * 4 + q;
          int col = col0 + wc + n * 16 + fr;
          unsafeAtomicAdd(&C[(size_t)row * ldc + col], alpha * acc[m][n][q]);
        }
  } else {
    #pragma unroll
    for (int m = 0; m < 2; m++)
      #pragma unroll
      for (int n = 0; n < 2; n++)
        #pragma unroll
        for (int q = 0; q < 4; q++) {
          int row = row0 + wr + m * 16 + (lane >> 4) * 4 + q;
          int col = col0 + wc + n * 16 + fr;
          float v = alpha * acc[m][n][q];
          if (beta != 0.0f) v += beta * C[(size_t)row * ldc + col];
          if (bias) v += bias[col];
          if (ACT == 1) v = (v > 0.0f) ? v : expm1f(v);
          C[(size_t)row * ldc + col] = v;
        }
  }
}

static void gemmT(hipStream_t st, const float* A, int lda, const float* B, int ldb,
                  float* C, int ldc, int M, int Nn, int K, float alpha, float beta,
                  const float* bias, int act, int splitk)
{
  dim3 grid(Nn / 64, M / 64, splitk), block(256);
  int kChunk = K / splitk;
  if (act)
    gemmMF<1><<<grid, block, 0, st>>>(A, lda, B, ldb, C, ldc, kChunk, alpha, beta, bias);
  else
    gemmMF<0><<<grid, block, 0, st>>>(A, lda, B, ldb, C, ldc, kChunk, alpha, beta, bias);
}

// ---------------- transpose: in[R][Cc] -> out[Cc][R] ----------------
__global__ __launch_bounds__(256)
void transposeK(const float* __restrict__ in, float* __restrict__ out, int R, int Cc)
{
  __shared__ float t[32][33];
  int x  = blockIdx.x * 32 + threadIdx.x;
  int y0 = blockIdx.y * 32;
  for (int dy = threadIdx.y; dy < 32; dy += 8)
    t[dy][threadIdx.x] = in[(size_t)(y0 + dy) * Cc + x];
  __syncthreads();
  int ox  = y0 + threadIdx.x;
  int oy0 = blockIdx.x * 32;
  for (int dy = threadIdx.y; dy < 32; dy += 8)
    out[(size_t)(oy0 + dy) * R + ox] = t[threadIdx.x][dy];
}

// ---------------- whole-tensor mean/var: per-block partials (no atomics) -------
__global__ __launch_bounds__(256)
void reduceMV(const float* __restrict__ x, double* __restrict__ pS, double* __restrict__ pS2)
{
  double s = 0, s2 = 0;
  for (int i = blockIdx.x * 256 + threadIdx.x; i < CN / 4; i += 256 * 256) {
    float4 v = ((const float4*)x)[i];
    s  += (double)v.x + v.y + v.z + v.w;
    s2 += (double)v.x*v.x + (double)v.y*v.y + (double)v.z*v.z + (double)v.w*v.w;
  }
  s  = blockSumD(s);
  s2 = blockSumD(s2);
  if (threadIdx.x == 0) { pS[blockIdx.x] = s; pS2[blockIdx.x] = s2; }
}

__global__ __launch_bounds__(256)
void tanhNormK(float* __restrict__ x, const double* __restrict__ pS, const double* __restrict__ pS2)
{
  __shared__ float bc[2];
  double a = pS[threadIdx.x], b = pS2[threadIdx.x];
  a = blockSumD(a);
  b = blockSumD(b);
  if (threadIdx.x == 0) {
    double m   = a / (double)CN;
    double var = b / (double)CN - m * m;
    bc[0] = (float)m;
    bc[1] = (float)(1.0 / sqrt(var + 1e-5));
  }
  __syncthreads();
  float mf = bc[0], rs = bc[1];
  for (int i = blockIdx.x * 256 + threadIdx.x; i < CN / 4; i += 256 * 256) {
    float4 v = ((const float4*)x)[i];
    v.x = tanhf((v.x - mf) * rs);
    v.y = tanhf((v.y - mf) * rs);
    v.z = tanhf((v.z - mf) * rs);
    v.w = tanhf((v.w - mf) * rs);
    ((float4*)x)[i] = v;
  }
}

// ---------------- per-node squared norms (wave per node, no atomics) ----------
__global__ __launch_bounds__(256)
void rowSqK(const float* __restrict__ ft, float* __restrict__ sq)
{
  int n = blockIdx.x * 4 + (threadIdx.x >> 6);
  int l = threadIdx.x & 63;
  float4 v = ((const float4*)(ft + (size_t)n * CF))[l];
  float t = waveSumF(v.x*v.x + v.y*v.y + v.z*v.z + v.w*v.w);
  if (l == 0) sq[n] = t;
}

// ---------------- per-channel sums ----------------
__global__ __launch_bounds__(256)
void colSHK(const float* __restrict__ f, const float* __restrict__ sq,
            float* __restrict__ s, float* __restrict__ h)
{
  int c = blockIdx.x;
  double ps = 0, ph = 0;
  for (int n = threadIdx.x; n < N_NODES; n += 256) {
    float v = f[(size_t)c * N_NODES + n];
    ps += v;
    ph += (double)v * sq[n];
  }
  ps = blockSumD(ps);
  ph = blockSumD(ph);
  if (threadIdx.x == 0) { s[c] = (float)ps; h[c] = (float)ph; }
}

// ---------------- closed-form std of the NxN distance matrix ----------------
__global__ __launch_bounds__(256)
void finalizeStdK(const float* __restrict__ s, const float* __restrict__ h,
                  const float* __restrict__ G, const float* __restrict__ sq,
                  float* __restrict__ c0)
{
  int c = threadIdx.x;
  double S1 = 0, S2 = 0;
  for (int i = c; i < N_NODES; i += 256) { double q = sq[i]; S1 += q; S2 += q * q; }
  double sd = (double)s[c] * s[c];
  double hd = (double)h[c] * s[c];
  double gf = 0;
  for (int i = c; i < CF * CF; i += 256) { double g = G[i]; gf += g * g; }
  S1 = blockSumD(S1);
  S2 = blockSumD(S2);
  sd = blockSumD(sd);
  hd = blockSumD(hd);
  gf = blockSumD(gf);
  if (c == 0) {
    double NN = (double)N_NODES;
    double sum1 = 2.0 * NN * S1 - 2.0 * sd;
    double sum2 = 2.0 * NN * S2 + 2.0 * S1 * S1 + 4.0 * gf - 8.0 * hd;
    double n2 = NN * NN;
    double var = (sum2 - sum1 * sum1 / n2) / (n2 - 1.0);
    double sdev = sqrt(var > 0 ? var : 0);
    c0[0] = (float)(-2.0 / sdev);
  }
}

// ---------------- edge affinities (wave per edge) + deg ----------------
__global__ __launch_bounds__(256)
void edgeWK(const int* __restrict__ ei, const int* __restrict__ ej,
            const float* __restrict__ ft, const float* __restrict__ sq,
            const float* __restrict__ c0,
            float* __restrict__ wE, float* __restrict__ deg)
{
  int wid  = (blockIdx.x * 256 + threadIdx.x) >> 6;
  int lane = threadIdx.x & 63;
  if (wid >= E_TOT) return;
  int i, j;
  if (wid < E0_EDGES) { i = ei[wid]; j = ej[wid]; } else { i = j = wid - E0_EDGES; }
  float4 a = ((const float4*)(ft + (size_t)i * CF))[lane];
  float4 b = ((const float4*)(ft + (size_t)j * CF))[lane];
  float d = a.x*b.x + a.y*b.y + a.z*b.z + a.w*b.w;
  d = waveSumF(d);
  if (lane == 0) {
    float dist = fmaxf(sq[i] + sq[j] - 2.0f * d, 0.0f);
    float w = expf(c0[0] * dist);
    wE[wid] = w;
    unsafeAtomicAdd(deg + j, w);
  }
}

__global__ void disKK(float* deg)
{
  int n = blockIdx.x * blockDim.x + threadIdx.x;
  if (n < N_NODES) { float d = deg[n]; deg[n] = d > 0.0f ? rsqrtf(d) : 0.0f; }
}

// ---------------- CSR build (edge list is a fixed input) ----------------
__global__ __launch_bounds__(256)
void csrCountK(const int* __restrict__ ei, const int* __restrict__ ej,
               int* __restrict__ cntO, int* __restrict__ cntI)
{
  int e = blockIdx.x * 256 + threadIdx.x;
  if (e < E0_EDGES) {
    atomicAdd(&cntO[ei[e]], 1);
    atomicAdd(&cntI[ej[e]], 1);
  }
}

__global__ __launch_bounds__(256)
void csrScanK(const int* __restrict__ cntO, const int* __restrict__ cntI,
              int* __restrict__ ofsO, int* __restrict__ ofsI)
{
  __shared__ int smO[256], smI[256];
  int t = threadIdx.x;
  int lo[16], li[16];
  int sO = 0, sI = 0;
  #pragma unroll
  for (int k = 0; k < 16; k++) {
    lo[k] = cntO[t * 16 + k]; li[k] = cntI[t * 16 + k];
    sO += lo[k]; sI += li[k];
  }
  smO[t] = sO; smI[t] = sI;
  __syncthreads();
  for (int off = 1; off < 256; off <<= 1) {
    int aO = (t >= off) ? smO[t - off] : 0;
    int aI = (t >= off) ? smI[t - off] : 0;
    __syncthreads();
    smO[t] += aO; smI[t] += aI;
    __syncthreads();
  }
  int bO = smO[t] - sO;
  int bI = smI[t] - sI;
  #pragma unroll
  for (int k = 0; k < 16; k++) {
    ofsO[t * 16 + k] = bO; bO += lo[k];
    ofsI[t * 16 + k] = bI; bI += li[k];
  }
}

__global__ __launch_bounds__(256)
void csrFillK(const int* __restrict__ ei, const int* __restrict__ ej,
              const int* __restrict__ ofsO, const int* __restrict__ ofsI,
              int* __restrict__ curO, int* __restrict__ curI,
              int2* __restrict__ lstO, int2* __restrict__ lstI)
{
  int e = blockIdx.x * 256 + threadIdx.x;
  if (e >= E0_EDGES) return;
  int i = ei[e], j = ej[e];
  int p = atomicAdd(&curO[i], 1); lstO[ofsO[i] + p] = make_int2(j, e);
  int q = atomicAdd(&curI[j], 1); lstI[ofsI[j] + q] = make_int2(i, e);
}

// ---------------- per-edge normalized weight squared ----------------
__global__ __launch_bounds__(256)
void wsqK(const int* __restrict__ ei, const int* __restrict__ ej,
          const float* __restrict__ wE, const float* __restrict__ dis,
          float* __restrict__ Wsq)
{
  int e = blockIdx.x * 256 + threadIdx.x;
  if (e < E0_EDGES) {
    float W = dis[ei[e]] * wE[e] * dis[ej[e]];
    Wsq[e] = W * W;
  }
}

// ---------------- graph Laplacian gather into lapT[N][CF] (no atomics) --------
__global__ __launch_bounds__(256)
void gatherLapK(const int2* __restrict__ lstO, const int2* __restrict__ lstI,
                const int* __restrict__ ofsO, const int* __restrict__ ofsI,
                const int* __restrict__ cntO, const int* __restrict__ cntI,
                const float* __restrict__ Wsq, const float* __restrict__ ft,
                float* __restrict__ lapT)
{
  int n = blockIdx.x, c = threadIdx.x;
  float own = ft[(size_t)n * CF + c];
  float acc = 0.0f;
  int o0 = ofsO[n], oc = cntO[n];
  for (int k = 0; k < oc; k++) {
    int2 oe = lstO[o0 + k];
    acc += Wsq[oe.y] * (own - ft[(size_t)oe.x * CF + c]);
  }
  int i0 = ofsI[n], ic = cntI[n];
  for (int k = 0; k < ic; k++) {
    int2 oe = lstI[i0 + k];
    acc -= Wsq[oe.y] * (ft[(size_t)oe.x * CF + c] - own);
  }
  lapT[(size_t)n * CF + c] = acc;
}

// ---------------- row log-softmax ----------------
__global__ __launch_bounds__(256)
void logSoftmaxK(const float* __restrict__ logits, float* __restrict__ out)
{
  int n = blockIdx.x;
  const float* row = logits + (size_t)n * NOUT;
  float mx = -1e30f;
  for (int o = threadIdx.x; o < NOUT; o += 256) mx = fmaxf(mx, row[o]);
  mx = blockMaxF(mx);
  float se = 0;
  for (int o = threadIdx.x; o < NOUT; o += 256) se += expf(row[o] - mx);
  se = blockSumF(se);
  float lse = mx + logf(se);
  for (int o = threadIdx.x; o < NOUT; o += 256) out[(size_t)n * NOUT + o] = row[o] - lse;
}

extern "C" void kernel_launch(void* const* d_in, const int* in_sizes, int n_in,
                              void* d_out, int out_size, void* d_ws, size_t ws_size,
                              hipStream_t stream)
{
  (void)in_sizes; (void)n_in; (void)out_size; (void)ws_size;
  const float* x0      = (const float*)d_in[0];
  const float* K1      = (const float*)d_in[1];
  const float* K2      = (const float*)d_in[2];
  const float* KNclose = (const float*)d_in[3];
  const float* KN1     = (const float*)d_in[4];
  const float* KN2     = (const float*)d_in[5];
  const float* lin1w   = (const float*)d_in[6];
  const float* lin1b   = (const float*)d_in[7];
  const float* lin2w   = (const float*)d_in[8];
  const float* lin2b   = (const float*)d_in[9];
  const int*   ei      = (const int*)d_in[10];
  const int*   ej      = (const int*)d_in[11];
  float* out = (float*)d_out;

  float* base   = (float*)d_ws;
  float* f      = base;                  // [CF][N] (per-layer transposed copy; x0T at open)
  float* uT     = base + 1 * (size_t)CN; // [N][CF]
  float* lapT   = base + 2 * (size_t)CN; // [N][CF]; x1 at close
  float* fT     = base + 3 * (size_t)CN; // [N][CF]  primary features
  float* logits = base + 4 * (size_t)CN; // [N][NOUT]
  float* wE     = base + 8 * (size_t)CN; // [E_TOT]
  float* sq     = wE + E_TOT;            // [N]
  float* deg    = sq + N_NODES;          // [N] (deg -> dis in place)
  float* sArr   = deg + N_NODES;         // [CF]
  float* hArr   = sArr + CF;             // [CF]
  float* G      = hArr + CF;             // [CF][CF]
  float* c0     = G + CF * CF;           // [1]
  double* pS    = (double*)(base + 9 * (size_t)CN); // [256]
  double* pS2   = pS + 256;                          // [256]

  int* ibase = (int*)(pS2 + 256);
  int*  cntO = ibase;
  int*  cntI = cntO + N_NODES;
  int*  ofsO = cntI + N_NODES;
  int*  ofsI = ofsO + N_NODES;
  int*  curO = ofsI + N_NODES;
  int*  curI = curO + N_NODES;
  int2* lstO = (int2*)(curI + N_NODES);
  int2* lstI = lstO + E0_EDGES;
  float* Wsq = (float*)(lstI + E0_EDGES);

  // ---- CSR build ----
  hipMemsetAsync(cntO, 0, 6 * N_NODES * sizeof(int), stream);
  csrCountK<<<E0_EDGES/256, 256, 0, stream>>>(ei, ej, cntO, cntI);
  csrScanK<<<1, 256, 0, stream>>>(cntO, cntI, ofsO, ofsI);
  csrFillK<<<E0_EDGES/256, 256, 0, stream>>>(ei, ej, ofsO, ofsI, curO, curI, lstO, lstI);

  // ---- opening: fT = tanh(LN(x0T·K1^T))·K2^T ----
  transposeK<<<dim3(N_NODES/32, CIN/32), dim3(32, 8), 0, stream>>>(x0, f, CIN, N_NODES); // f := x0T [N][64]
  gemmT(stream, f, CIN, K1, CIN, uT, CF, N_NODES, CF, CIN, 1.f, 0.f, nullptr, 0, 1);
  reduceMV<<<256, 256, 0, stream>>>(uT, pS, pS2);
  tanhNormK<<<256, 256, 0, stream>>>(uT, pS, pS2);
  gemmT(stream, uT, CF, K2, CF, fT, CF, N_NODES, CF, CF, 1.f, 0.f, nullptr, 0, 1);

  for (int L = 0; L < NLAYER; L++) {
    const float* kn1 = KN1 + (size_t)L * CF * 2 * CF;   // [CF][2CF]
    const float* kn2 = KN2 + (size_t)L * CF * CF;       // [CF][CF]

    hipMemsetAsync(deg, 0, N_NODES * sizeof(float), stream);
    hipMemsetAsync(G,   0, CF * CF * sizeof(float), stream);

    transposeK<<<dim3(CF/32, N_NODES/32), dim3(32, 8), 0, stream>>>(fT, f, N_NODES, CF); // f[CF][N]
    rowSqK<<<N_NODES/4, 256, 0, stream>>>(fT, sq);
    colSHK<<<CF, 256, 0, stream>>>(f, sq, sArr, hArr);
    gemmT(stream, f, N_NODES, f, N_NODES, G, CF, CF, CF, N_NODES, 1.f, 0.f, nullptr, 0, 16);
    finalizeStdK<<<1, 256, 0, stream>>>(sArr, hArr, G, sq, c0);
    edgeWK<<<E_TOT/4, 256, 0, stream>>>(ei, ej, fT, sq, c0, wE, deg);
    disKK<<<N_NODES/256, 256, 0, stream>>>(deg);
    wsqK<<<E0_EDGES/256, 256, 0, stream>>>(ei, ej, wE, deg, Wsq);
    gatherLapK<<<N_NODES, 256, 0, stream>>>(lstO, lstI, ofsO, ofsI, cntO, cntI, Wsq, fT, lapT);

    // uT = fT·kn1a^T + lapT·kn1b^T
    gemmT(stream, fT,   CF, kn1,      2*CF, uT, CF, N_NODES, CF, CF, 1.f, 0.f, nullptr, 0, 1);
    gemmT(stream, lapT, CF, kn1 + CF, 2*CF, uT, CF, N_NODES, CF, CF, 1.f, 1.f, nullptr, 0, 1);
    reduceMV<<<256, 256, 0, stream>>>(uT, pS, pS2);
    tanhNormK<<<256, 256, 0, stream>>>(uT, pS, pS2);
    // fT += 0.1 · uT·kn2^T
    gemmT(stream, uT, CF, kn2, CF, fT, CF, N_NODES, CF, CF, 0.1f, 1.f, nullptr, 0, 1);
  }

  // ---- close: yT = fT·KNclose^T ; x1 = elu(yT·lin1^T+b1) ; logits ; log_softmax ----
  gemmT(stream, fT, CF, KNclose, CF, uT, CF, N_NODES, CF, CF, 1.f, 0.f, nullptr, 0, 1);
  gemmT(stream, uT, CF, lin1w, CF, lapT, CF, N_NODES, CF, CF, 1.f, 0.f, lin1b, 1, 1);
  gemmT(stream, lapT, CF, lin2w, CF, logits, NOUT, N_NODES, NOUT, CF, 1.f, 0.f, lin2b, 0, 1);
  logSoftmaxK<<<N_NODES, 256, 0, stream>>>(logits, out);
}

// Round 4
// 1143.847 us; speedup vs baseline: 3.1600x; 1.4215x over previous
//
#include <hip/hip_runtime.h>
#include <hip/hip_bf16.h>

// Problem constants (fixed instance)
#define N_NODES 4096
#define CF      256        // nopen == nhid == nNclose
#define CIN     64
#define E0_EDGES 65536
#define E_TOT   (E0_EDGES + N_NODES)
#define NLAYER  8
#define NOUT    1024
#define CN      (CF * N_NODES)
#define STD_BLOCKS 64

typedef __attribute__((ext_vector_type(8))) short s8v;   // 8 bf16 (4 VGPRs)
typedef __attribute__((ext_vector_type(4))) float f4v;   // MFMA acc

__device__ __forceinline__ unsigned short f2bf(float x){
  unsigned int u = __builtin_bit_cast(unsigned int, x);
  return (unsigned short)((u + 0x7FFFu + ((u >> 16) & 1u)) >> 16);
}
__device__ __forceinline__ float bf2f(unsigned short h){
  unsigned int u = ((unsigned int)h) << 16;
  return __builtin_bit_cast(float, u);
}

// ---------------- block reduction helpers (256 threads) ----------------
__device__ __forceinline__ float waveSumF(float v){
  #pragma unroll
  for (int o = 32; o; o >>= 1) v += __shfl_xor(v, o);
  return v;
}
__device__ __forceinline__ double waveSumD(double v){
  #pragma unroll
  for (int o = 32; o; o >>= 1) v += __shfl_xor(v, o);
  return v;
}
__device__ __forceinline__ float waveMaxF(float v){
  #pragma unroll
  for (int o = 32; o; o >>= 1) v = fmaxf(v, __shfl_xor(v, o));
  return v;
}
__device__ float blockSumF(float v){
  __shared__ float sm[4];
  v = waveSumF(v);
  int l = threadIdx.x & 63, w = threadIdx.x >> 6;
  __syncthreads();
  if (l == 0) sm[w] = v;
  __syncthreads();
  return sm[0] + sm[1] + sm[2] + sm[3];
}
__device__ double blockSumD(double v){
  __shared__ double sm[4];
  v = waveSumD(v);
  int l = threadIdx.x & 63, w = threadIdx.x >> 6;
  __syncthreads();
  if (l == 0) sm[w] = v;
  __syncthreads();
  return sm[0] + sm[1] + sm[2] + sm[3];
}
__device__ float blockMaxF(float v){
  __shared__ float sm[4];
  v = waveMaxF(v);
  int l = threadIdx.x & 63, w = threadIdx.x >> 6;
  __syncthreads();
  if (l == 0) sm[w] = v;
  __syncthreads();
  return fmaxf(fmaxf(sm[0], sm[1]), fmaxf(sm[2], sm[3]));
}

// ---------------- MFMA GEMM: C[M,N] = alpha*A·B^T (+beta*C, +bias, act) -------
__device__ __forceinline__ void cvt8(const float* vs, s8v* ph, s8v* pl){
  s8v h, l;
  #pragma unroll
  for (int i = 0; i < 8; i++){
    unsigned short hb = f2bf(vs[i]);
    h[i] = (short)hb;
    l[i] = (short)f2bf(vs[i] - bf2f(hb));
  }
  *ph = h; *pl = l;
}

#define MF(a,b,c) c = __builtin_amdgcn_mfma_f32_16x16x32_bf16(a, b, c, 0, 0, 0)

template<int ACT>  // 0 none, 1 elu
__global__ __launch_bounds__(256)
void gemmMF(const float* __restrict__ A, int lda,
            const float* __restrict__ B, int ldb,
            float* __restrict__ C, int ldc,
            int kChunk, float alpha, float beta,
            const float* __restrict__ bias)
{
  __shared__ unsigned short Ah[64][72], Al[64][72], Bh[64][72], Bl[64][72];
  const int tid = threadIdx.x;
  const int r  = tid >> 2;           // 0..63 staging row
  const int kq = (tid & 3) * 16;     // 0,16,32,48
  const int row0 = blockIdx.y * 64, col0 = blockIdx.x * 64;
  const int kStart = blockIdx.z * kChunk;

  const int wid = tid >> 6, lane = tid & 63;
  const int wr = (wid >> 1) * 32, wc = (wid & 1) * 32;
  const int fr = lane & 15, fk = (lane >> 4) * 8;

  f4v acc[2][2] = {};

  for (int k0 = kStart; k0 < kStart + kChunk; k0 += 64) {
    const float* ap = A + (size_t)(row0 + r) * lda + k0 + kq;
    const float* bp = B + (size_t)(col0 + r) * ldb + k0 + kq;
    float av[16], bv[16];
    *(float4*)&av[0]  = *(const float4*)(ap + 0);
    *(float4*)&av[4]  = *(const float4*)(ap + 4);
    *(float4*)&av[8]  = *(const float4*)(ap + 8);
    *(float4*)&av[12] = *(const float4*)(ap + 12);
    *(float4*)&bv[0]  = *(const float4*)(bp + 0);
    *(float4*)&bv[4]  = *(const float4*)(bp + 4);
    *(float4*)&bv[8]  = *(const float4*)(bp + 8);
    *(float4*)&bv[12] = *(const float4*)(bp + 12);
    __syncthreads();   // previous iteration's LDS reads done
    cvt8(&av[0], (s8v*)&Ah[r][kq],     (s8v*)&Al[r][kq]);
    cvt8(&av[8], (s8v*)&Ah[r][kq + 8], (s8v*)&Al[r][kq + 8]);
    cvt8(&bv[0], (s8v*)&Bh[r][kq],     (s8v*)&Bl[r][kq]);
    cvt8(&bv[8], (s8v*)&Bh[r][kq + 8], (s8v*)&Bl[r][kq + 8]);
    __syncthreads();

    #pragma unroll
    for (int ks = 0; ks < 64; ks += 32) {
      s8v ah0 = *(const s8v*)&Ah[wr + fr][ks + fk];
      s8v ah1 = *(const s8v*)&Ah[wr + 16 + fr][ks + fk];
      s8v al0 = *(const s8v*)&Al[wr + fr][ks + fk];
      s8v al1 = *(const s8v*)&Al[wr + 16 + fr][ks + fk];
      s8v bh0 = *(const s8v*)&Bh[wc + fr][ks + fk];
      s8v bh1 = *(const s8v*)&Bh[wc + 16 + fr][ks + fk];
      s8v bl0 = *(const s8v*)&Bl[wc + fr][ks + fk];
      s8v bl1 = *(const s8v*)&Bl[wc + 16 + fr][ks + fk];
      MF(ah0, bh0, acc[0][0]); MF(ah0, bl0, acc[0][0]); MF(al0, bh0, acc[0][0]);
      MF(ah0, bh1, acc[0][1]); MF(ah0, bl1, acc[0][1]); MF(al0, bh1, acc[0][1]);
      MF(ah1, bh0, acc[1][0]); MF(ah1, bl0, acc[1][0]); MF(al1, bh0, acc[1][0]);
      MF(ah1, bh1, acc[1][1]); MF(ah1, bl1, acc[1][1]); MF(al1, bh1, acc[1][1]);
    }
  }

  if (gridDim.z > 1) {
    #pragma unroll
    for (int m = 0; m < 2; m++)
      #pragma unroll
      for (int n = 0; n < 2; n++)
        #pragma unroll
        for (int q = 0; q < 4; q++) {
          int row = row0 + wr + m * 16 + (lane >> 4) * 4 + q;
          int col = col0 + wc + n * 16 + fr;
          unsafeAtomicAdd(&C[(size_t)row * ldc + col], alpha * acc[m][n][q]);
        }
  } else {
    #pragma unroll
    for (int m = 0; m < 2; m++)
      #pragma unroll
      for (int n = 0; n < 2; n++)
        #pragma unroll
        for (int q = 0; q < 4; q++) {
          int row = row0 + wr + m * 16 + (lane >> 4) * 4 + q;
          int col = col0 + wc + n * 16 + fr;
          float v = alpha * acc[m][n][q];
          if (beta != 0.0f) v += beta * C[(size_t)row * ldc + col];
          if (bias) v += bias[col];
          if (ACT == 1) v = (v > 0.0f) ? v : expm1f(v);
          C[(size_t)row * ldc + col] = v;
        }
  }
}

static void gemmT(hipStream_t st, const float* A, int lda, const float* B, int ldb,
                  float* C, int ldc, int M, int Nn, int K, float alpha, float beta,
                  const float* bias, int act, int splitk)
{
  dim3 grid(Nn / 64, M / 64, splitk), block(256);
  int kChunk = K / splitk;
  if (act)
    gemmMF<1><<<grid, block, 0, st>>>(A, lda, B, ldb, C, ldc, kChunk, alpha, beta, bias);
  else
    gemmMF<0><<<grid, block, 0, st>>>(A, lda, B, ldb, C, ldc, kChunk, alpha, beta, bias);
}

// ---------------- transpose: in[R][Cc] -> out[Cc][R] ----------------
__global__ __launch_bounds__(256)
void transposeK(const float* __restrict__ in, float* __restrict__ out, int R, int Cc)
{
  __shared__ float t[32][33];
  int x  = blockIdx.x * 32 + threadIdx.x;
  int y0 = blockIdx.y * 32;
  for (int dy = threadIdx.y; dy < 32; dy += 8)
    t[dy][threadIdx.x] = in[(size_t)(y0 + dy) * Cc + x];
  __syncthreads();
  int ox  = y0 + threadIdx.x;
  int oy0 = blockIdx.x * 32;
  for (int dy = threadIdx.y; dy < 32; dy += 8)
    out[(size_t)(oy0 + dy) * R + ox] = t[threadIdx.x][dy];
}

// ---------------- whole-tensor mean/var: per-block partials (no atomics) -------
__global__ __launch_bounds__(256)
void reduceMV(const float* __restrict__ x, double* __restrict__ pS, double* __restrict__ pS2)
{
  double s = 0, s2 = 0;
  for (int i = blockIdx.x * 256 + threadIdx.x; i < CN / 4; i += 256 * 256) {
    float4 v = ((const float4*)x)[i];
    s  += (double)v.x + v.y + v.z + v.w;
    s2 += (double)v.x*v.x + (double)v.y*v.y + (double)v.z*v.z + (double)v.w*v.w;
  }
  s  = blockSumD(s);
  s2 = blockSumD(s2);
  if (threadIdx.x == 0) { pS[blockIdx.x] = s; pS2[blockIdx.x] = s2; }
}

__global__ __launch_bounds__(256)
void tanhNormK(float* __restrict__ x, const double* __restrict__ pS, const double* __restrict__ pS2)
{
  __shared__ float bc[2];
  double a = pS[threadIdx.x], b = pS2[threadIdx.x];
  a = blockSumD(a);
  b = blockSumD(b);
  if (threadIdx.x == 0) {
    double m   = a / (double)CN;
    double var = b / (double)CN - m * m;
    bc[0] = (float)m;
    bc[1] = (float)(1.0 / sqrt(var + 1e-5));
  }
  __syncthreads();
  float mf = bc[0], rs = bc[1];
  for (int i = blockIdx.x * 256 + threadIdx.x; i < CN / 4; i += 256 * 256) {
    float4 v = ((const float4*)x)[i];
    v.x = tanhf((v.x - mf) * rs);
    v.y = tanhf((v.y - mf) * rs);
    v.z = tanhf((v.z - mf) * rs);
    v.w = tanhf((v.w - mf) * rs);
    ((float4*)x)[i] = v;
  }
}

// ---------------- per-node squared norms (wave per node, no atomics) ----------
__global__ __launch_bounds__(256)
void rowSqK(const float* __restrict__ ft, float* __restrict__ sq)
{
  int n = blockIdx.x * 4 + (threadIdx.x >> 6);
  int l = threadIdx.x & 63;
  float4 v = ((const float4*)(ft + (size_t)n * CF))[l];
  float t = waveSumF(v.x*v.x + v.y*v.y + v.z*v.z + v.w*v.w);
  if (l == 0) sq[n] = t;
}

// ---------------- per-channel sums ----------------
__global__ __launch_bounds__(256)
void colSHK(const float* __restrict__ f, const float* __restrict__ sq,
            float* __restrict__ s, float* __restrict__ h)
{
  int c = blockIdx.x;
  double ps = 0, ph = 0;
  for (int n = threadIdx.x; n < N_NODES; n += 256) {
    float v = f[(size_t)c * N_NODES + n];
    ps += v;
    ph += (double)v * sq[n];
  }
  ps = blockSumD(ps);
  ph = blockSumD(ph);
  if (threadIdx.x == 0) { s[c] = (float)ps; h[c] = (float)ph; }
}

// ---------------- std(D) closed form: stage 1, 64-block partials ----------------
// parts layout: parts[c * STD_BLOCKS + b], c in {S1,S2,sd,hd,gf}
__global__ __launch_bounds__(256)
void stdPartsK(const float* __restrict__ s, const float* __restrict__ h,
               const float* __restrict__ G, const float* __restrict__ sq,
               double* __restrict__ parts)
{
  int b = blockIdx.x, t = threadIdx.x;
  double S1 = 0, S2 = 0, sd = 0, hd = 0, gf = 0;
  for (int i = b * 256 + t; i < N_NODES; i += STD_BLOCKS * 256) {
    double q = sq[i]; S1 += q; S2 += q * q;
  }
  if (b == 0) {
    double sv = s[t], hv = h[t];
    sd = sv * sv; hd = hv * sv;
  }
  for (int i = b * 256 + t; i < CF * CF; i += STD_BLOCKS * 256) {
    double g = G[i]; gf += g * g;
  }
  S1 = blockSumD(S1);
  S2 = blockSumD(S2);
  sd = blockSumD(sd);
  hd = blockSumD(hd);
  gf = blockSumD(gf);
  if (t == 0) {
    parts[0 * STD_BLOCKS + b] = S1;
    parts[1 * STD_BLOCKS + b] = S2;
    parts[2 * STD_BLOCKS + b] = sd;
    parts[3 * STD_BLOCKS + b] = hd;
    parts[4 * STD_BLOCKS + b] = gf;
  }
}

// ---------------- std(D) closed form: stage 2, tiny finalize ----------------
__global__ __launch_bounds__(64)
void finalizeStd2K(const double* __restrict__ parts, float* __restrict__ c0)
{
  int l = threadIdx.x;   // 64 == STD_BLOCKS
  double v[5];
  #pragma unroll
  for (int c = 0; c < 5; c++) v[c] = waveSumD(parts[c * STD_BLOCKS + l]);
  if (l == 0) {
    double S1 = v[0], S2 = v[1], sd = v[2], hd = v[3], gf = v[4];
    double NN = (double)N_NODES;
    double sum1 = 2.0 * NN * S1 - 2.0 * sd;
    double sum2 = 2.0 * NN * S2 + 2.0 * S1 * S1 + 4.0 * gf - 8.0 * hd;
    double n2 = NN * NN;
    double var = (sum2 - sum1 * sum1 / n2) / (n2 - 1.0);
    double sdev = sqrt(var > 0 ? var : 0);
    c0[0] = (float)(-2.0 / sdev);
  }
}

// ---------------- edge affinities (wave per edge) + deg ----------------
__global__ __launch_bounds__(256)
void edgeWK(const int* __restrict__ ei, const int* __restrict__ ej,
            const float* __restrict__ ft, const float* __restrict__ sq,
            const float* __restrict__ c0,
            float* __restrict__ wE, float* __restrict__ deg)
{
  int wid  = (blockIdx.x * 256 + threadIdx.x) >> 6;
  int lane = threadIdx.x & 63;
  if (wid >= E_TOT) return;
  int i, j;
  if (wid < E0_EDGES) { i = ei[wid]; j = ej[wid]; } else { i = j = wid - E0_EDGES; }
  float4 a = ((const float4*)(ft + (size_t)i * CF))[lane];
  float4 b = ((const float4*)(ft + (size_t)j * CF))[lane];
  float d = a.x*b.x + a.y*b.y + a.z*b.z + a.w*b.w;
  d = waveSumF(d);
  if (lane == 0) {
    float dist = fmaxf(sq[i] + sq[j] - 2.0f * d, 0.0f);
    float w = expf(c0[0] * dist);
    wE[wid] = w;
    unsafeAtomicAdd(deg + j, w);
  }
}

__global__ void disKK(float* deg)
{
  int n = blockIdx.x * blockDim.x + threadIdx.x;
  if (n < N_NODES) { float d = deg[n]; deg[n] = d > 0.0f ? rsqrtf(d) : 0.0f; }
}

// ---------------- CSR build (edge list is a fixed input) ----------------
__global__ __launch_bounds__(256)
void csrCountK(const int* __restrict__ ei, const int* __restrict__ ej,
               int* __restrict__ cntO, int* __restrict__ cntI)
{
  int e = blockIdx.x * 256 + threadIdx.x;
  if (e < E0_EDGES) {
    atomicAdd(&cntO[ei[e]], 1);
    atomicAdd(&cntI[ej[e]], 1);
  }
}

__global__ __launch_bounds__(256)
void csrScanK(const int* __restrict__ cntO, const int* __restrict__ cntI,
              int* __restrict__ ofsO, int* __restrict__ ofsI)
{
  __shared__ int smO[256], smI[256];
  int t = threadIdx.x;
  int lo[16], li[16];
  int sO = 0, sI = 0;
  #pragma unroll
  for (int k = 0; k < 16; k++) {
    lo[k] = cntO[t * 16 + k]; li[k] = cntI[t * 16 + k];
    sO += lo[k]; sI += li[k];
  }
  smO[t] = sO; smI[t] = sI;
  __syncthreads();
  for (int off = 1; off < 256; off <<= 1) {
    int aO = (t >= off) ? smO[t - off] : 0;
    int aI = (t >= off) ? smI[t - off] : 0;
    __syncthreads();
    smO[t] += aO; smI[t] += aI;
    __syncthreads();
  }
  int bO = smO[t] - sO;
  int bI = smI[t] - sI;
  #pragma unroll
  for (int k = 0; k < 16; k++) {
    ofsO[t * 16 + k] = bO; bO += lo[k];
    ofsI[t * 16 + k] = bI; bI += li[k];
  }
}

__global__ __launch_bounds__(256)
void csrFillK(const int* __restrict__ ei, const int* __restrict__ ej,
              const int* __restrict__ ofsO, const int* __restrict__ ofsI,
              int* __restrict__ curO, int* __restrict__ curI,
              int2* __restrict__ lstO, int2* __restrict__ lstI)
{
  int e = blockIdx.x * 256 + threadIdx.x;
  if (e >= E0_EDGES) return;
  int i = ei[e], j = ej[e];
  int p = atomicAdd(&curO[i], 1); lstO[ofsO[i] + p] = make_int2(j, e);
  int q = atomicAdd(&curI[j], 1); lstI[ofsI[j] + q] = make_int2(i, e);
}

// ---------------- per-edge normalized weight squared ----------------
__global__ __launch_bounds__(256)
void wsqK(const int* __restrict__ ei, const int* __restrict__ ej,
          const float* __restrict__ wE, const float* __restrict__ dis,
          float* __restrict__ Wsq)
{
  int e = blockIdx.x * 256 + threadIdx.x;
  if (e < E0_EDGES) {
    float W = dis[ei[e]] * wE[e] * dis[ej[e]];
    Wsq[e] = W * W;
  }
}

// ---------------- graph Laplacian gather into lapT[N][CF] (no atomics) --------
__global__ __launch_bounds__(256)
void gatherLapK(const int2* __restrict__ lstO, const int2* __restrict__ lstI,
                const int* __restrict__ ofsO, const int* __restrict__ ofsI,
                const int* __restrict__ cntO, const int* __restrict__ cntI,
                const float* __restrict__ Wsq, const float* __restrict__ ft,
                float* __restrict__ lapT)
{
  int n = blockIdx.x, c = threadIdx.x;
  float own = ft[(size_t)n * CF + c];
  float acc = 0.0f;
  int o0 = ofsO[n], oc = cntO[n];
  for (int k = 0; k < oc; k++) {
    int2 oe = lstO[o0 + k];
    acc += Wsq[oe.y] * (own - ft[(size_t)oe.x * CF + c]);
  }
  int i0 = ofsI[n], ic = cntI[n];
  for (int k = 0; k < ic; k++) {
    int2 oe = lstI[i0 + k];
    acc -= Wsq[oe.y] * (ft[(size_t)oe.x * CF + c] - own);
  }
  lapT[(size_t)n * CF + c] = acc;
}

// ---------------- row log-softmax ----------------
__global__ __launch_bounds__(256)
void logSoftmaxK(const float* __restrict__ logits, float* __restrict__ out)
{
  int n = blockIdx.x;
  const float* row = logits + (size_t)n * NOUT;
  float mx = -1e30f;
  for (int o = threadIdx.x; o < NOUT; o += 256) mx = fmaxf(mx, row[o]);
  mx = blockMaxF(mx);
  float se = 0;
  for (int o = threadIdx.x; o < NOUT; o += 256) se += expf(row[o] - mx);
  se = blockSumF(se);
  float lse = mx + logf(se);
  for (int o = threadIdx.x; o < NOUT; o += 256) out[(size_t)n * NOUT + o] = row[o] - lse;
}

extern "C" void kernel_launch(void* const* d_in, const int* in_sizes, int n_in,
                              void* d_out, int out_size, void* d_ws, size_t ws_size,
                              hipStream_t stream)
{
  (void)in_sizes; (void)n_in; (void)out_size; (void)ws_size;
  const float* x0      = (const float*)d_in[0];
  const float* K1      = (const float*)d_in[1];
  const float* K2      = (const float*)d_in[2];
  const float* KNclose = (const float*)d_in[3];
  const float* KN1     = (const float*)d_in[4];
  const float* KN2     = (const float*)d_in[5];
  const float* lin1w   = (const float*)d_in[6];
  const float* lin1b   = (const float*)d_in[7];
  const float* lin2w   = (const float*)d_in[8];
  const float* lin2b   = (const float*)d_in[9];
  const int*   ei      = (const int*)d_in[10];
  const int*   ej      = (const int*)d_in[11];
  float* out = (float*)d_out;

  float* base   = (float*)d_ws;
  float* f      = base;                  // [CF][N] (per-layer transposed copy; x0T at open)
  float* uT     = base + 1 * (size_t)CN; // [N][CF]
  float* lapT   = base + 2 * (size_t)CN; // [N][CF]; x1 at close
  float* fT     = base + 3 * (size_t)CN; // [N][CF]  primary features
  float* logits = base + 4 * (size_t)CN; // [N][NOUT]
  float* wE     = base + 8 * (size_t)CN; // [E_TOT]
  float* sq     = wE + E_TOT;            // [N]
  float* deg    = sq + N_NODES;          // [N] (deg -> dis in place)
  float* sArr   = deg + N_NODES;         // [CF]
  float* hArr   = sArr + CF;             // [CF]
  float* G      = hArr + CF;             // [CF][CF]
  float* c0     = G + CF * CF;           // [1]
  double* pS    = (double*)(base + 9 * (size_t)CN); // [256]
  double* pS2   = pS + 256;                          // [256]
  double* parts = pS2 + 256;                         // [5*STD_BLOCKS]

  int* ibase = (int*)(parts + 5 * STD_BLOCKS);
  int*  cntO = ibase;
  int*  cntI = cntO + N_NODES;
  int*  ofsO = cntI + N_NODES;
  int*  ofsI = ofsO + N_NODES;
  int*  curO = ofsI + N_NODES;
  int*  curI = curO + N_NODES;
  int2* lstO = (int2*)(curI + N_NODES);
  int2* lstI = lstO + E0_EDGES;
  float* Wsq = (float*)(lstI + E0_EDGES);

  // ---- CSR build ----
  hipMemsetAsync(cntO, 0, 6 * N_NODES * sizeof(int), stream);
  csrCountK<<<E0_EDGES/256, 256, 0, stream>>>(ei, ej, cntO, cntI);
  csrScanK<<<1, 256, 0, stream>>>(cntO, cntI, ofsO, ofsI);
  csrFillK<<<E0_EDGES/256, 256, 0, stream>>>(ei, ej, ofsO, ofsI, curO, curI, lstO, lstI);

  // ---- opening: fT = tanh(LN(x0T·K1^T))·K2^T ----
  transposeK<<<dim3(N_NODES/32, CIN/32), dim3(32, 8), 0, stream>>>(x0, f, CIN, N_NODES); // f := x0T [N][64]
  gemmT(stream, f, CIN, K1, CIN, uT, CF, N_NODES, CF, CIN, 1.f, 0.f, nullptr, 0, 1);
  reduceMV<<<256, 256, 0, stream>>>(uT, pS, pS2);
  tanhNormK<<<256, 256, 0, stream>>>(uT, pS, pS2);
  gemmT(stream, uT, CF, K2, CF, fT, CF, N_NODES, CF, CF, 1.f, 0.f, nullptr, 0, 1);

  for (int L = 0; L < NLAYER; L++) {
    const float* kn1 = KN1 + (size_t)L * CF * 2 * CF;   // [CF][2CF]
    const float* kn2 = KN2 + (size_t)L * CF * CF;       // [CF][CF]

    hipMemsetAsync(deg, 0, N_NODES * sizeof(float), stream);
    hipMemsetAsync(G,   0, CF * CF * sizeof(float), stream);

    transposeK<<<dim3(CF/32, N_NODES/32), dim3(32, 8), 0, stream>>>(fT, f, N_NODES, CF); // f[CF][N]
    rowSqK<<<N_NODES/4, 256, 0, stream>>>(fT, sq);
    colSHK<<<CF, 256, 0, stream>>>(f, sq, sArr, hArr);
    gemmT(stream, f, N_NODES, f, N_NODES, G, CF, CF, CF, N_NODES, 1.f, 0.f, nullptr, 0, 16);
    stdPartsK<<<STD_BLOCKS, 256, 0, stream>>>(sArr, hArr, G, sq, parts);
    finalizeStd2K<<<1, 64, 0, stream>>>(parts, c0);
    edgeWK<<<E_TOT/4, 256, 0, stream>>>(ei, ej, fT, sq, c0, wE, deg);
    disKK<<<N_NODES/256, 256, 0, stream>>>(deg);
    wsqK<<<E0_EDGES/256, 256, 0, stream>>>(ei, ej, wE, deg, Wsq);
    gatherLapK<<<N_NODES, 256, 0, stream>>>(lstO, lstI, ofsO, ofsI, cntO, cntI, Wsq, fT, lapT);

    // uT = fT·kn1a^T + lapT·kn1b^T
    gemmT(stream, fT,   CF, kn1,      2*CF, uT, CF, N_NODES, CF, CF, 1.f, 0.f, nullptr, 0, 1);
    gemmT(stream, lapT, CF, kn1 + CF, 2*CF, uT, CF, N_NODES, CF, CF, 1.f, 1.f, nullptr, 0, 1);
    reduceMV<<<256, 256, 0, stream>>>(uT, pS, pS2);
    tanhNormK<<<256, 256, 0, stream>>>(uT, pS, pS2);
    // fT += 0.1 · uT·kn2^T
    gemmT(stream, uT, CF, kn2, CF, fT, CF, N_NODES, CF, CF, 0.1f, 1.f, nullptr, 0, 1);
  }

  // ---- close: yT = fT·KNclose^T ; x1 = elu(yT·lin1^T+b1) ; logits ; log_softmax ----
  gemmT(stream, fT, CF, KNclose, CF, uT, CF, N_NODES, CF, CF, 1.f, 0.f, nullptr, 0, 1);
  gemmT(stream, uT, CF, lin1w, CF, lapT, CF, N_NODES, CF, CF, 1.f, 0.f, lin1b, 1, 1);
  gemmT(stream, lapT, CF, lin2w, CF, logits, NOUT, N_NODES, NOUT, CF, 1.f, 0.f, lin2b, 0, 1);
  logSoftmaxK<<<N_NODES, 256, 0, stream>>>(logits, out);
}

// Round 5
// 1139.592 us; speedup vs baseline: 3.1718x; 1.0037x over previous
//
#include <hip/hip_runtime.h>
#include <hip/hip_bf16.h>

// Problem constants (fixed instance)
#define N_NODES 4096
#define CF      256
#define CIN     64
#define E0_EDGES 65536
#define NLAYER  8
#define NOUT    1024
#define CN      (CF * N_NODES)

typedef unsigned short ushort;
typedef __attribute__((ext_vector_type(8))) short s8v;   // 8 bf16 (4 VGPRs)
typedef __attribute__((ext_vector_type(4))) float f4v;   // MFMA acc

__device__ __forceinline__ ushort f2bf(float x){
  unsigned int u = __builtin_bit_cast(unsigned int, x);
  return (ushort)((u + 0x7FFFu + ((u >> 16) & 1u)) >> 16);
}
__device__ __forceinline__ float bf2f(ushort h){
  unsigned int u = ((unsigned int)h) << 16;
  return __builtin_bit_cast(float, u);
}

// ---------------- reduction helpers ----------------
__device__ __forceinline__ float waveSumF(float v){
  #pragma unroll
  for (int o = 32; o; o >>= 1) v += __shfl_xor(v, o);
  return v;
}
__device__ __forceinline__ double waveSumD(double v){
  #pragma unroll
  for (int o = 32; o; o >>= 1) v += __shfl_xor(v, o);
  return v;
}
__device__ __forceinline__ float waveMaxF(float v){
  #pragma unroll
  for (int o = 32; o; o >>= 1) v = fmaxf(v, __shfl_xor(v, o));
  return v;
}
__device__ float blockSumF(float v){
  __shared__ float sm[4];
  v = waveSumF(v);
  int l = threadIdx.x & 63, w = threadIdx.x >> 6;
  __syncthreads();
  if (l == 0) sm[w] = v;
  __syncthreads();
  return sm[0] + sm[1] + sm[2] + sm[3];
}
__device__ double blockSumD(double v){
  __shared__ double sm[4];
  v = waveSumD(v);
  int l = threadIdx.x & 63, w = threadIdx.x >> 6;
  __syncthreads();
  if (l == 0) sm[w] = v;
  __syncthreads();
  return sm[0] + sm[1] + sm[2] + sm[3];
}
__device__ float blockMaxF(float v){
  __shared__ float sm[4];
  v = waveMaxF(v);
  int l = threadIdx.x & 63, w = threadIdx.x >> 6;
  __syncthreads();
  if (l == 0) sm[w] = v;
  __syncthreads();
  return fmaxf(fmaxf(sm[0], sm[1]), fmaxf(sm[2], sm[3]));
}

// ---------------- MFMA GEMM on precomputed bf16 hi/lo pairs ----------------
// C[M,N] = alpha*A·B^T (+beta*Cf, +bias, act). A rows may be split across two
// buffers at K=splitAt (dual-A). 64x64 tile, BK=64, 4 waves (2x2 of 32x32),
// 3-term hi/lo MFMA (~f32 operand accuracy).
// cStrideZ!=0: write per-z split-K partials Cf[z*cStrideZ + idx] (plain store).
#define MF(a,b,c) c = __builtin_amdgcn_mfma_f32_16x16x32_bf16(a, b, c, 0, 0, 0)

template<int ACT, bool WF32, bool WBF, bool MV>   // ACT: 0 none, 1 elu
__global__ __launch_bounds__(256)
void gemmBF(const ushort* __restrict__ A1h, const ushort* __restrict__ A1l,
            const ushort* __restrict__ A2h, const ushort* __restrict__ A2l,
            int lda, int splitAt,
            const ushort* __restrict__ Bh, const ushort* __restrict__ Bl, int ldb,
            float* __restrict__ Cf, ushort* __restrict__ Ch, ushort* __restrict__ Cl,
            int ldc, size_t cStrideZ, int kChunk,
            float alpha, float beta, const float* __restrict__ bias,
            double* __restrict__ pS, double* __restrict__ pS2)
{
  __shared__ ushort Ahs[64][72], Als[64][72], Bhs[64][72], Bls[64][72];
  const int tid = threadIdx.x;
  const int r  = tid >> 2;           // staging row 0..63
  const int kq = (tid & 3) * 16;     // 0,16,32,48
  const int row0 = blockIdx.y * 64, col0 = blockIdx.x * 64;
  const int kStart = blockIdx.z * kChunk;

  const int wid = tid >> 6, lane = tid & 63;
  const int wr = (wid >> 1) * 32, wc = (wid & 1) * 32;
  const int fr = lane & 15, fk = (lane >> 4) * 8;

  f4v acc[2][2] = {};

  for (int k0 = kStart; k0 < kStart + kChunk; k0 += 64) {
    bool firstA = (k0 < splitAt);
    const ushort* Ah_g = firstA ? A1h : A2h;
    const ushort* Al_g = firstA ? A1l : A2l;
    int kk = firstA ? k0 : (k0 - splitAt);
    size_t aoff = (size_t)(row0 + r) * lda + kk + kq;
    size_t boff = (size_t)(col0 + r) * ldb + k0 + kq;
    s8v a0 = *(const s8v*)(Ah_g + aoff), a1 = *(const s8v*)(Ah_g + aoff + 8);
    s8v a2 = *(const s8v*)(Al_g + aoff), a3 = *(const s8v*)(Al_g + aoff + 8);
    s8v b0 = *(const s8v*)(Bh + boff),   b1 = *(const s8v*)(Bh + boff + 8);
    s8v b2 = *(const s8v*)(Bl + boff),   b3 = *(const s8v*)(Bl + boff + 8);
    __syncthreads();   // previous iteration's LDS reads done
    *(s8v*)&Ahs[r][kq] = a0; *(s8v*)&Ahs[r][kq + 8] = a1;
    *(s8v*)&Als[r][kq] = a2; *(s8v*)&Als[r][kq + 8] = a3;
    *(s8v*)&Bhs[r][kq] = b0; *(s8v*)&Bhs[r][kq + 8] = b1;
    *(s8v*)&Bls[r][kq] = b2; *(s8v*)&Bls[r][kq + 8] = b3;
    __syncthreads();

    #pragma unroll
    for (int ks = 0; ks < 64; ks += 32) {
      s8v ah0 = *(const s8v*)&Ahs[wr + fr][ks + fk];
      s8v ah1 = *(const s8v*)&Ahs[wr + 16 + fr][ks + fk];
      s8v al0 = *(const s8v*)&Als[wr + fr][ks + fk];
      s8v al1 = *(const s8v*)&Als[wr + 16 + fr][ks + fk];
      s8v bh0 = *(const s8v*)&Bhs[wc + fr][ks + fk];
      s8v bh1 = *(const s8v*)&Bhs[wc + 16 + fr][ks + fk];
      s8v bl0 = *(const s8v*)&Bls[wc + fr][ks + fk];
      s8v bl1 = *(const s8v*)&Bls[wc + 16 + fr][ks + fk];
      MF(ah0, bh0, acc[0][0]); MF(ah0, bl0, acc[0][0]); MF(al0, bh0, acc[0][0]);
      MF(ah0, bh1, acc[0][1]); MF(ah0, bl1, acc[0][1]); MF(al0, bh1, acc[0][1]);
      MF(ah1, bh0, acc[1][0]); MF(ah1, bl0, acc[1][0]); MF(al1, bh0, acc[1][0]);
      MF(ah1, bh1, acc[1][1]); MF(ah1, bl1, acc[1][1]); MF(al1, bh1, acc[1][1]);
    }
  }

  double s = 0, s2 = 0;
  #pragma unroll
  for (int m = 0; m < 2; m++)
    #pragma unroll
    for (int n = 0; n < 2; n++)
      #pragma unroll
      for (int q = 0; q < 4; q++) {
        int row = row0 + wr + m * 16 + (lane >> 4) * 4 + q;
        int col = col0 + wc + n * 16 + fr;
        size_t cidx = (size_t)row * ldc + col;
        float v = alpha * acc[m][n][q];
        if (cStrideZ) {
          Cf[blockIdx.z * cStrideZ + cidx] = v;
        } else {
          if (beta != 0.0f) v += beta * Cf[cidx];
          if (bias) v += bias[col];
          if (ACT == 1) v = (v > 0.0f) ? v : expm1f(v);
          if (WF32) Cf[cidx] = v;
          if (WBF) { ushort h = f2bf(v); Ch[cidx] = h; Cl[cidx] = f2bf(v - bf2f(h)); }
          if (MV)  { s += v; s2 += (double)v * v; }
        }
      }
  if (MV) {
    s  = blockSumD(s);
    s2 = blockSumD(s2);
    if (tid == 0) {
      int bid = blockIdx.y * gridDim.x + blockIdx.x;   // grids are (4,64) = 256 blocks
      pS[bid] = s; pS2[bid] = s2;
    }
  }
}

// ---------------- weight f32 -> bf16 hi/lo pairs (once per launch) ----------
#define OFF_K1   0
#define OFF_K2   16384
#define OFF_KNC  81920
#define OFF_KN1  147456
#define OFF_KN2  1196032
#define OFF_L1   1720320
#define OFF_L2   1785856
#define NW_TOT   2048000

__global__ __launch_bounds__(256)
void prepWK(const float* s0, const float* s1, const float* s2, const float* s3,
            const float* s4, const float* s5, const float* s6,
            ushort* __restrict__ h, ushort* __restrict__ l)
{
  const int sizes[7] = {16384, 65536, 65536, 1048576, 524288, 65536, 262144};
  const int offs[7]  = {OFF_K1, OFF_K2, OFF_KNC, OFF_KN1, OFF_KN2, OFF_L1, OFF_L2};
  int seg = blockIdx.y;
  const float* src = seg==0?s0: seg==1?s1: seg==2?s2: seg==3?s3: seg==4?s4: seg==5?s5: s6;
  int n = sizes[seg], off = offs[seg];
  for (int i = blockIdx.x * 256 + threadIdx.x; i < n; i += gridDim.x * 256) {
    float v = src[i];
    ushort hh = f2bf(v);
    h[off + i] = hh;
    l[off + i] = f2bf(v - bf2f(hh));
  }
}

// ---------------- transpose f32 [R][Cc] -> bf16 hi/lo pair [Cc][R] ----------
__global__ __launch_bounds__(256)
void transposeBF(const float* __restrict__ in, ushort* __restrict__ outh,
                 ushort* __restrict__ outl, int R, int Cc)
{
  __shared__ float t[32][33];
  int x  = blockIdx.x * 32 + threadIdx.x;
  int y0 = blockIdx.y * 32;
  for (int dy = threadIdx.y; dy < 32; dy += 8)
    t[dy][threadIdx.x] = in[(size_t)(y0 + dy) * Cc + x];
  __syncthreads();
  int ox  = y0 + threadIdx.x;
  int oy0 = blockIdx.x * 32;
  for (int dy = threadIdx.y; dy < 32; dy += 8) {
    float v = t[threadIdx.x][dy];
    ushort h = f2bf(v);
    outh[(size_t)(oy0 + dy) * R + ox] = h;
    outl[(size_t)(oy0 + dy) * R + ox] = f2bf(v - bf2f(h));
  }
}

// ---------------- whole-tensor tanh-LN on hi/lo pairs (in place) ------------
__global__ __launch_bounds__(256)
void tanhNormPairK(ushort* __restrict__ h, ushort* __restrict__ l,
                   const double* __restrict__ pS, const double* __restrict__ pS2)
{
  __shared__ float bc[2];
  double a = pS[threadIdx.x], b = pS2[threadIdx.x];
  a = blockSumD(a);
  b = blockSumD(b);
  if (threadIdx.x == 0) {
    double m   = a / (double)CN;
    double var = b / (double)CN - m * m;
    bc[0] = (float)m;
    bc[1] = (float)(1.0 / sqrt(var + 1e-5));
  }
  __syncthreads();
  float mf = bc[0], rs = bc[1];
  for (size_t i = ((size_t)blockIdx.x * 256 + threadIdx.x) * 8; i < CN; i += (size_t)256 * 256 * 8) {
    s8v hv = *(s8v*)(h + i), lv = *(s8v*)(l + i);
    #pragma unroll
    for (int k = 0; k < 8; k++) {
      float x = bf2f((ushort)hv[k]) + bf2f((ushort)lv[k]);
      x = tanhf((x - mf) * rs);
      ushort hh = f2bf(x);
      hv[k] = (short)hh;
      lv[k] = (short)f2bf(x - bf2f(hh));
    }
    *(s8v*)(h + i) = hv;
    *(s8v*)(l + i) = lv;
  }
}

// ---------------- fused per-node sq + per-channel s/h partials --------------
// 64 blocks; wave w of block b handles rows b*64 + rr*4 + w. No cross-wave sync.
__global__ __launch_bounds__(256)
void sqSHK(const float* __restrict__ fT, float* __restrict__ sq,
           float* __restrict__ sP, float* __restrict__ hP)
{
  int b = blockIdx.x, w = threadIdx.x >> 6, lane = threadIdx.x & 63;
  float sA[4] = {0,0,0,0}, hA[4] = {0,0,0,0};
  for (int rr = 0; rr < 16; rr++) {
    int n = b * 64 + rr * 4 + w;
    float4 v = ((const float4*)(fT + (size_t)n * CF))[lane];
    float q = waveSumF(v.x*v.x + v.y*v.y + v.z*v.z + v.w*v.w);
    if (lane == 0) sq[n] = q;
    sA[0] += v.x; sA[1] += v.y; sA[2] += v.z; sA[3] += v.w;
    hA[0] += v.x*q; hA[1] += v.y*q; hA[2] += v.z*q; hA[3] += v.w*q;
  }
  int p = b * 4 + w;
  ((float4*)(sP + (size_t)p * CF))[lane] = make_float4(sA[0], sA[1], sA[2], sA[3]);
  ((float4*)(hP + (size_t)p * CF))[lane] = make_float4(hA[0], hA[1], hA[2], hA[3]);
}

// ---------------- std(D) closed form: 64-block partials ----------------
#define STD_BLOCKS 64
__global__ __launch_bounds__(256)
void stdPartsK(const float* __restrict__ sP, const float* __restrict__ hP,
               const float* __restrict__ Gp, const float* __restrict__ sq,
               double* __restrict__ parts)
{
  int b = blockIdx.x, t = threadIdx.x;
  double S1 = 0, S2 = 0, sd = 0, hd = 0, gf = 0;
  for (int i = b * 256 + t; i < N_NODES; i += STD_BLOCKS * 256) {
    double q = sq[i]; S1 += q; S2 += q * q;
  }
  if (b == 0) {
    double sv = 0, hv = 0;
    for (int p = 0; p < 256; p++) { sv += sP[p * 256 + t]; hv += hP[p * 256 + t]; }
    sd = sv * sv; hd = hv * sv;
  }
  for (int i = b * 256 + t; i < CF * CF; i += STD_BLOCKS * 256) {
    double g = 0;
    #pragma unroll 4
    for (int z = 0; z < 16; z++) g += Gp[(size_t)z * 65536 + i];
    gf += g * g;
  }
  S1 = blockSumD(S1);
  S2 = blockSumD(S2);
  sd = blockSumD(sd);
  hd = blockSumD(hd);
  gf = blockSumD(gf);
  if (t == 0) {
    parts[0 * STD_BLOCKS + b] = S1;
    parts[1 * STD_BLOCKS + b] = S2;
    parts[2 * STD_BLOCKS + b] = sd;
    parts[3 * STD_BLOCKS + b] = hd;
    parts[4 * STD_BLOCKS + b] = gf;
  }
}

__global__ __launch_bounds__(64)
void finalizeStd2K(const double* __restrict__ parts, float* __restrict__ c0)
{
  int l = threadIdx.x;
  double v[5];
  #pragma unroll
  for (int c = 0; c < 5; c++) v[c] = waveSumD(parts[c * STD_BLOCKS + l]);
  if (l == 0) {
    double S1 = v[0], S2 = v[1], sd = v[2], hd = v[3], gf = v[4];
    double NN = (double)N_NODES;
    double sum1 = 2.0 * NN * S1 - 2.0 * sd;
    double sum2 = 2.0 * NN * S2 + 2.0 * S1 * S1 + 4.0 * gf - 8.0 * hd;
    double n2 = NN * NN;
    double var = (sum2 - sum1 * sum1 / n2) / (n2 - 1.0);
    double sdev = sqrt(var > 0 ? var : 0);
    c0[0] = (float)(-2.0 / sdev);
  }
}

// ---------------- edge affinities (wave per edge, no atomics) ----------------
__global__ __launch_bounds__(256)
void edgeWK(const int* __restrict__ ei, const int* __restrict__ ej,
            const float* __restrict__ ft, const float* __restrict__ sq,
            const float* __restrict__ c0, float* __restrict__ wE)
{
  int wid  = (blockIdx.x * 256 + threadIdx.x) >> 6;
  int lane = threadIdx.x & 63;
  int i = ei[wid], j = ej[wid];
  float4 a = ((const float4*)(ft + (size_t)i * CF))[lane];
  float4 b = ((const float4*)(ft + (size_t)j * CF))[lane];
  float d = a.x*b.x + a.y*b.y + a.z*b.z + a.w*b.w;
  d = waveSumF(d);
  if (lane == 0) {
    float dist = fmaxf(sq[i] + sq[j] - 2.0f * d, 0.0f);
    wE[wid] = expf(c0[0] * dist);
  }
}

// ---------------- deg/dis via CSR-in gather (wave per node) ----------------
__global__ __launch_bounds__(256)
void degK(const int* __restrict__ ofsI, const int* __restrict__ cntI,
          const int2* __restrict__ lstI, const float* __restrict__ wE,
          float* __restrict__ dis)
{
  int n = blockIdx.x * 4 + (threadIdx.x >> 6);
  int lane = threadIdx.x & 63;
  int i0 = ofsI[n], ic = cntI[n];
  float s = 0;
  for (int k = lane; k < ic; k += 64) s += wE[lstI[i0 + k].y];
  s = waveSumF(s);
  if (lane == 0) dis[n] = rsqrtf(1.0f + s);   // +1 = self-loop weight
}

// ---------------- CSR build (edge list is a fixed input) ----------------
__global__ __launch_bounds__(256)
void csrCountK(const int* __restrict__ ei, const int* __restrict__ ej,
               int* __restrict__ cntO, int* __restrict__ cntI)
{
  int e = blockIdx.x * 256 + threadIdx.x;
  atomicAdd(&cntO[ei[e]], 1);
  atomicAdd(&cntI[ej[e]], 1);
}

__global__ __launch_bounds__(256)
void csrScanK(const int* __restrict__ cntO, const int* __restrict__ cntI,
              int* __restrict__ ofsO, int* __restrict__ ofsI)
{
  __shared__ int smO[256], smI[256];
  int t = threadIdx.x;
  int lo[16], li[16];
  int sO = 0, sI = 0;
  #pragma unroll
  for (int k = 0; k < 16; k++) {
    lo[k] = cntO[t * 16 + k]; li[k] = cntI[t * 16 + k];
    sO += lo[k]; sI += li[k];
  }
  smO[t] = sO; smI[t] = sI;
  __syncthreads();
  for (int off = 1; off < 256; off <<= 1) {
    int aO = (t >= off) ? smO[t - off] : 0;
    int aI = (t >= off) ? smI[t - off] : 0;
    __syncthreads();
    smO[t] += aO; smI[t] += aI;
    __syncthreads();
  }
  int bO = smO[t] - sO;
  int bI = smI[t] - sI;
  #pragma unroll
  for (int k = 0; k < 16; k++) {
    ofsO[t * 16 + k] = bO; bO += lo[k];
    ofsI[t * 16 + k] = bI; bI += li[k];
  }
}

__global__ __launch_bounds__(256)
void csrFillK(const int* __restrict__ ei, const int* __restrict__ ej,
              const int* __restrict__ ofsO, const int* __restrict__ ofsI,
              int* __restrict__ curO, int* __restrict__ curI,
              int2* __restrict__ lstO, int2* __restrict__ lstI)
{
  int e = blockIdx.x * 256 + threadIdx.x;
  int i = ei[e], j = ej[e];
  int p = atomicAdd(&curO[i], 1); lstO[ofsO[i] + p] = make_int2(j, e);
  int q = atomicAdd(&curI[j], 1); lstI[ofsI[j] + q] = make_int2(i, e);
}

// ---------------- graph Laplacian gather -> bf16 pair (no atomics) ----------
__global__ __launch_bounds__(256)
void gatherLapK(const int2* __restrict__ lstO, const int2* __restrict__ lstI,
                const int* __restrict__ ofsO, const int* __restrict__ ofsI,
                const int* __restrict__ cntO, const int* __restrict__ cntI,
                const float* __restrict__ wE, const float* __restrict__ dis,
                const float* __restrict__ fT,
                ushort* __restrict__ lapTh, ushort* __restrict__ lapTl)
{
  int n = blockIdx.x, c = threadIdx.x;
  float own = fT[(size_t)n * CF + c];
  float dn = dis[n];
  float acc = 0.0f;
  int o0 = ofsO[n], oc = cntO[n];
  for (int k = 0; k < oc; k++) {
    int2 oe = lstO[o0 + k];
    float W = dn * wE[oe.y] * dis[oe.x];
    acc += (W * W) * (own - fT[(size_t)oe.x * CF + c]);
  }
  int i0 = ofsI[n], ic = cntI[n];
  for (int k = 0; k < ic; k++) {
    int2 oe = lstI[i0 + k];
    float W = dis[oe.x] * wE[oe.y] * dn;
    acc -= (W * W) * (fT[(size_t)oe.x * CF + c] - own);
  }
  size_t idx = (size_t)n * CF + c;
  ushort h = f2bf(acc);
  lapTh[idx] = h;
  lapTl[idx] = f2bf(acc - bf2f(h));
}

// ---------------- row log-softmax ----------------
__global__ __launch_bounds__(256)
void logSoftmaxK(const float* __restrict__ logits, float* __restrict__ out)
{
  int n = blockIdx.x;
  const float* row = logits + (size_t)n * NOUT;
  float mx = -1e30f;
  for (int o = threadIdx.x; o < NOUT; o += 256) mx = fmaxf(mx, row[o]);
  mx = blockMaxF(mx);
  float se = 0;
  for (int o = threadIdx.x; o < NOUT; o += 256) se += expf(row[o] - mx);
  se = blockSumF(se);
  float lse = mx + logf(se);
  for (int o = threadIdx.x; o < NOUT; o += 256) out[(size_t)n * NOUT + o] = row[o] - lse;
}

extern "C" void kernel_launch(void* const* d_in, const int* in_sizes, int n_in,
                              void* d_out, int out_size, void* d_ws, size_t ws_size,
                              hipStream_t stream)
{
  (void)in_sizes; (void)n_in; (void)out_size; (void)ws_size;
  const float* x0      = (const float*)d_in[0];
  const float* K1      = (const float*)d_in[1];
  const float* K2      = (const float*)d_in[2];
  const float* KNclose = (const float*)d_in[3];
  const float* KN1     = (const float*)d_in[4];
  const float* KN2     = (const float*)d_in[5];
  const float* lin1w   = (const float*)d_in[6];
  const float* lin1b   = (const float*)d_in[7];
  const float* lin2w   = (const float*)d_in[8];
  const float* lin2b   = (const float*)d_in[9];
  const int*   ei      = (const int*)d_in[10];
  const int*   ej      = (const int*)d_in[11];
  float* out = (float*)d_out;

  // ---------------- workspace layout ----------------
  float* base   = (float*)d_ws;
  float* fT     = base;                     // [N][CF] f32 features
  float* logits = fT + (size_t)CN;          // [N][NOUT]
  float* Gp     = logits + 4 * (size_t)CN;  // [16][256*256] split-K partials
  float* sq     = Gp + (size_t)CN;          // [N]
  float* dis    = sq + N_NODES;             // [N]
  float* sP     = dis + N_NODES;            // [256][256]
  float* hP     = sP + 65536;               // [256][256]
  float* wE     = hP + 65536;               // [E0]
  float* c0     = wE + E0_EDGES;            // [1] (+3 pad)
  double* pS    = (double*)(c0 + 4);        // [256]
  double* pS2   = pS + 256;                 // [256]
  double* parts = pS2 + 256;                // [5*64]

  ushort* u0 = (ushort*)(((uintptr_t)(parts + 5 * STD_BLOCKS) + 15) & ~(uintptr_t)15);
  ushort* fTh   = u0;                       // [N][CF] pairs
  ushort* fTl   = fTh + (size_t)CN;
  ushort* fh    = fTl + (size_t)CN;         // [CF][N] transposed pairs (x0T at open)
  ushort* fl    = fh + (size_t)CN;
  ushort* lapTh = fl + (size_t)CN;          // lap pairs; x1 pairs at close
  ushort* lapTl = lapTh + (size_t)CN;
  ushort* uTh   = lapTl + (size_t)CN;       // intermediate pairs; y pairs at close
  ushort* uTl   = uTh + (size_t)CN;
  ushort* wH    = uTl + (size_t)CN;         // all weights hi
  ushort* wL    = wH + (size_t)NW_TOT;      // all weights lo

  int* ib = (int*)(((uintptr_t)(wL + NW_TOT) + 15) & ~(uintptr_t)15);
  int*  cntO = ib;
  int*  cntI = cntO + N_NODES;
  int*  ofsO = cntI + N_NODES;
  int*  ofsI = ofsO + N_NODES;
  int*  curO = ofsI + N_NODES;
  int*  curI = curO + N_NODES;
  int2* lstO = (int2*)(curI + N_NODES);
  int2* lstI = lstO + E0_EDGES;

  // ---- one-time: weight pairs + CSR ----
  prepWK<<<dim3(64, 7), 256, 0, stream>>>(K1, K2, KNclose, KN1, KN2, lin1w, lin2w, wH, wL);
  hipMemsetAsync(cntO, 0, 6 * N_NODES * sizeof(int), stream);
  csrCountK<<<E0_EDGES/256, 256, 0, stream>>>(ei, ej, cntO, cntI);
  csrScanK<<<1, 256, 0, stream>>>(cntO, cntI, ofsO, ofsI);
  csrFillK<<<E0_EDGES/256, 256, 0, stream>>>(ei, ej, ofsO, ofsI, curO, curI, lstO, lstI);

  // ---- opening: fT = tanh(LN(x0T·K1^T))·K2^T ----
  transposeBF<<<dim3(N_NODES/32, CIN/32), dim3(32, 8), 0, stream>>>(x0, fh, fl, CIN, N_NODES);
  gemmBF<0,0,1,1><<<dim3(4,64,1), 256, 0, stream>>>(
      fh, fl, fh, fl, CIN, 256, wH + OFF_K1, wL + OFF_K1, CIN,
      nullptr, uTh, uTl, CF, 0, CIN, 1.f, 0.f, nullptr, pS, pS2);
  tanhNormPairK<<<256, 256, 0, stream>>>(uTh, uTl, pS, pS2);
  gemmBF<0,1,1,0><<<dim3(4,64,1), 256, 0, stream>>>(
      uTh, uTl, uTh, uTl, CF, 512, wH + OFF_K2, wL + OFF_K2, CF,
      fT, fTh, fTl, CF, 0, CF, 1.f, 0.f, nullptr, nullptr, nullptr);

  for (int L = 0; L < NLAYER; L++) {
    const ushort* k1h = wH + OFF_KN1 + (size_t)L * CF * 2 * CF;
    const ushort* k1l = wL + OFF_KN1 + (size_t)L * CF * 2 * CF;
    const ushort* k2h = wH + OFF_KN2 + (size_t)L * CF * CF;
    const ushort* k2l = wL + OFF_KN2 + (size_t)L * CF * CF;

    transposeBF<<<dim3(CF/32, N_NODES/32), dim3(32, 8), 0, stream>>>(fT, fh, fl, N_NODES, CF);
    sqSHK<<<64, 256, 0, stream>>>(fT, sq, sP, hP);
    // Gram split-K=16 partials: Gp[z] = f[:, zchunk]·f[:, zchunk]^T
    gemmBF<0,1,0,0><<<dim3(4,4,16), 256, 0, stream>>>(
        fh, fl, fh, fl, N_NODES, 1 << 30, fh, fl, N_NODES,
        Gp, nullptr, nullptr, CF, 65536, 256, 1.f, 0.f, nullptr, nullptr, nullptr);
    stdPartsK<<<STD_BLOCKS, 256, 0, stream>>>(sP, hP, Gp, sq, parts);
    finalizeStd2K<<<1, 64, 0, stream>>>(parts, c0);
    edgeWK<<<E0_EDGES/4, 256, 0, stream>>>(ei, ej, fT, sq, c0, wE);
    degK<<<N_NODES/4, 256, 0, stream>>>(ofsI, cntI, lstI, wE, dis);
    gatherLapK<<<N_NODES, 256, 0, stream>>>(lstO, lstI, ofsO, ofsI, cntO, cntI,
                                            wE, dis, fT, lapTh, lapTl);
    // uT = [fT, lapT]·KN1^T  (fused K=512 dual-A), with LN-stat partials
    gemmBF<0,0,1,1><<<dim3(4,64,1), 256, 0, stream>>>(
        fTh, fTl, lapTh, lapTl, CF, 256, k1h, k1l, 2*CF,
        nullptr, uTh, uTl, CF, 0, 2*CF, 1.f, 0.f, nullptr, pS, pS2);
    tanhNormPairK<<<256, 256, 0, stream>>>(uTh, uTl, pS, pS2);
    // fT += 0.1 · uT·KN2^T
    gemmBF<0,1,1,0><<<dim3(4,64,1), 256, 0, stream>>>(
        uTh, uTl, uTh, uTl, CF, 512, k2h, k2l, CF,
        fT, fTh, fTl, CF, 0, CF, 0.1f, 1.f, nullptr, nullptr, nullptr);
  }

  // ---- close: y = fT·KNclose^T ; x1 = elu(y·lin1^T+b1) ; logits ; log_softmax ----
  gemmBF<0,0,1,0><<<dim3(4,64,1), 256, 0, stream>>>(
      fTh, fTl, fTh, fTl, CF, 512, wH + OFF_KNC, wL + OFF_KNC, CF,
      nullptr, uTh, uTl, CF, 0, CF, 1.f, 0.f, nullptr, nullptr, nullptr);
  gemmBF<1,0,1,0><<<dim3(4,64,1), 256, 0, stream>>>(
      uTh, uTl, uTh, uTl, CF, 512, wH + OFF_L1, wL + OFF_L1, CF,
      nullptr, lapTh, lapTl, CF, 0, CF, 1.f, 0.f, lin1b, nullptr, nullptr);
  gemmBF<0,1,0,0><<<dim3(16,64,1), 256, 0, stream>>>(
      lapTh, lapTl, lapTh, lapTl, CF, 512, wH + OFF_L2, wL + OFF_L2, CF,
      logits, nullptr, nullptr, NOUT, 0, CF, 1.f, 0.f, lin2b, nullptr, nullptr);
  logSoftmaxK<<<N_NODES, 256, 0, stream>>>(logits, out);
}

// Round 6
// 983.231 us; speedup vs baseline: 3.6762x; 1.1590x over previous
//
#include <hip/hip_runtime.h>
#include <hip/hip_bf16.h>

// Problem constants (fixed instance)
#define N_NODES 4096
#define CF      256
#define CIN     64
#define E0_EDGES 65536
#define NLAYER  8
#define NOUT    1024
#define CN      (CF * N_NODES)
#define STD_BLOCKS 64

typedef unsigned short ushort;
typedef __attribute__((ext_vector_type(8))) short s8v;   // 8 bf16
typedef __attribute__((ext_vector_type(4))) float f4v;   // MFMA acc

__device__ __forceinline__ ushort f2bf(float x){
  unsigned int u = __builtin_bit_cast(unsigned int, x);
  return (ushort)((u + 0x7FFFu + ((u >> 16) & 1u)) >> 16);
}
__device__ __forceinline__ float bf2f(ushort h){
  unsigned int u = ((unsigned int)h) << 16;
  return __builtin_bit_cast(float, u);
}

// ---------------- reduction helpers ----------------
__device__ __forceinline__ float waveSumF(float v){
  #pragma unroll
  for (int o = 32; o; o >>= 1) v += __shfl_xor(v, o);
  return v;
}
__device__ __forceinline__ double waveSumD(double v){
  #pragma unroll
  for (int o = 32; o; o >>= 1) v += __shfl_xor(v, o);
  return v;
}
__device__ __forceinline__ float waveMaxF(float v){
  #pragma unroll
  for (int o = 32; o; o >>= 1) v = fmaxf(v, __shfl_xor(v, o));
  return v;
}
__device__ float blockSumF(float v){
  __shared__ float sm[4];
  v = waveSumF(v);
  int l = threadIdx.x & 63, w = threadIdx.x >> 6;
  __syncthreads();
  if (l == 0) sm[w] = v;
  __syncthreads();
  return sm[0] + sm[1] + sm[2] + sm[3];
}
__device__ double blockSumD(double v){
  __shared__ double sm[4];
  v = waveSumD(v);
  int l = threadIdx.x & 63, w = threadIdx.x >> 6;
  __syncthreads();
  if (l == 0) sm[w] = v;
  __syncthreads();
  return sm[0] + sm[1] + sm[2] + sm[3];
}
__device__ float blockMaxF(float v){
  __shared__ float sm[4];
  v = waveMaxF(v);
  int l = threadIdx.x & 63, w = threadIdx.x >> 6;
  __syncthreads();
  if (l == 0) sm[w] = v;
  __syncthreads();
  return fmaxf(fmaxf(sm[0], sm[1]), fmaxf(sm[2], sm[3]));
}

// ---------------- bf16 MFMA GEMM, double-buffered pipeline -------------------
// C[M,N] = alpha*A·B^T (+beta*Cf, +bias, act). A,B bf16 row-major K-contiguous.
// A rows split across A1/A2 at K=splitAt (dual-A). 64x64 tile, BK=64, 4 waves
// (2x2 of 32x32), mfma_f32_16x16x32_bf16. One barrier per k-iter: global loads
// for tile t+1 issued before MFMA of tile t (latency hidden under compute).
// cStrideZ!=0: write per-z split-K partials (plain store).
#define MF(a,b,c) c = __builtin_amdgcn_mfma_f32_16x16x32_bf16(a, b, c, 0, 0, 0)

template<int ACT, bool WF32, bool WBF, bool MV>   // ACT: 0 none, 1 elu
__global__ __launch_bounds__(256)
void gemmB1(const ushort* __restrict__ A1, const ushort* __restrict__ A2,
            int lda, int splitAt,
            const ushort* __restrict__ B, int ldb,
            float* __restrict__ Cf, ushort* __restrict__ Cb,
            int ldc, size_t cStrideZ, int kChunk,
            float alpha, float beta, const float* __restrict__ bias,
            double* __restrict__ pS, double* __restrict__ pS2)
{
  __shared__ ushort As[2][64][72], Bs[2][64][72];
  const int tid = threadIdx.x;
  const int r  = tid >> 2;           // staging row 0..63
  const int kq = (tid & 3) * 16;     // 0,16,32,48
  const int row0 = blockIdx.y * 64, col0 = blockIdx.x * 64;
  const int kStart = blockIdx.z * kChunk;
  const int nT = kChunk >> 6;

  const int wid = tid >> 6, lane = tid & 63;
  const int wr = (wid >> 1) * 32, wc = (wid & 1) * 32;
  const int fr = lane & 15, fk = (lane >> 4) * 8;

  f4v acc[2][2] = {};
  s8v ra0, ra1, rb0, rb1;

#define LOADTILE(T) { \
    int k0 = kStart + (T) * 64; \
    const ushort* Ag; int kk; \
    if (k0 < splitAt) { Ag = A1; kk = k0; } else { Ag = A2; kk = k0 - splitAt; } \
    size_t aoff = (size_t)(row0 + r) * lda + kk + kq; \
    size_t boff = (size_t)(col0 + r) * ldb + k0 + kq; \
    ra0 = *(const s8v*)(Ag + aoff); ra1 = *(const s8v*)(Ag + aoff + 8); \
    rb0 = *(const s8v*)(B + boff);  rb1 = *(const s8v*)(B + boff + 8); }

  LOADTILE(0);
  *(s8v*)&As[0][r][kq] = ra0; *(s8v*)&As[0][r][kq + 8] = ra1;
  *(s8v*)&Bs[0][r][kq] = rb0; *(s8v*)&Bs[0][r][kq + 8] = rb1;

  for (int t = 0; t < nT; t++) {
    const int cur = t & 1;
    if (t + 1 < nT) LOADTILE(t + 1);          // in flight during MFMA below
    __syncthreads();                           // tile t writes visible; t-1 reads done
    #pragma unroll
    for (int ks = 0; ks < 64; ks += 32) {
      s8v a0 = *(const s8v*)&As[cur][wr + fr][ks + fk];
      s8v a1 = *(const s8v*)&As[cur][wr + 16 + fr][ks + fk];
      s8v b0 = *(const s8v*)&Bs[cur][wc + fr][ks + fk];
      s8v b1 = *(const s8v*)&Bs[cur][wc + 16 + fr][ks + fk];
      MF(a0, b0, acc[0][0]);
      MF(a0, b1, acc[0][1]);
      MF(a1, b0, acc[1][0]);
      MF(a1, b1, acc[1][1]);
    }
    if (t + 1 < nT) {
      const int nxt = cur ^ 1;                 // safe: buf nxt last read before barrier
      *(s8v*)&As[nxt][r][kq] = ra0; *(s8v*)&As[nxt][r][kq + 8] = ra1;
      *(s8v*)&Bs[nxt][r][kq] = rb0; *(s8v*)&Bs[nxt][r][kq + 8] = rb1;
    }
  }
#undef LOADTILE

  double s = 0, s2 = 0;
  #pragma unroll
  for (int m = 0; m < 2; m++)
    #pragma unroll
    for (int n = 0; n < 2; n++)
      #pragma unroll
      for (int q = 0; q < 4; q++) {
        int row = row0 + wr + m * 16 + (lane >> 4) * 4 + q;
        int col = col0 + wc + n * 16 + fr;
        size_t cidx = (size_t)row * ldc + col;
        float v = alpha * acc[m][n][q];
        if (cStrideZ) {
          Cf[blockIdx.z * cStrideZ + cidx] = v;
        } else {
          if (beta != 0.0f) v += beta * Cf[cidx];
          if (bias) v += bias[col];
          if (ACT == 1) v = (v > 0.0f) ? v : expm1f(v);
          if (WF32) Cf[cidx] = v;
          if (WBF)  Cb[cidx] = f2bf(v);
          if (MV)   { s += v; s2 += (double)v * v; }
        }
      }
  if (MV) {
    s  = blockSumD(s);
    s2 = blockSumD(s2);
    if (tid == 0) {
      int bid = blockIdx.y * gridDim.x + blockIdx.x;   // stats grids are 256 blocks
      pS[bid] = s; pS2[bid] = s2;
    }
  }
}

// ---------------- weight f32 -> bf16 (once per launch) ----------------------
#define OFF_K1   0
#define OFF_K2   16384
#define OFF_KNC  81920
#define OFF_KN1  147456
#define OFF_KN2  1196032
#define OFF_L1   1720320
#define OFF_L2   1785856
#define NW_TOT   2048000

__global__ __launch_bounds__(256)
void prepWK(const float* s0, const float* s1, const float* s2, const float* s3,
            const float* s4, const float* s5, const float* s6,
            ushort* __restrict__ h)
{
  const int sizes[7] = {16384, 65536, 65536, 1048576, 524288, 65536, 262144};
  const int offs[7]  = {OFF_K1, OFF_K2, OFF_KNC, OFF_KN1, OFF_KN2, OFF_L1, OFF_L2};
  int seg = blockIdx.y;
  const float* src = seg==0?s0: seg==1?s1: seg==2?s2: seg==3?s3: seg==4?s4: seg==5?s5: s6;
  int n = sizes[seg], off = offs[seg];
  for (int i = blockIdx.x * 256 + threadIdx.x; i < n; i += gridDim.x * 256)
    h[off + i] = f2bf(src[i]);
}

// ---------------- transpose f32 [R][Cc] -> bf16 [Cc][R] ----------------------
__global__ __launch_bounds__(256)
void transposeBF(const float* __restrict__ in, ushort* __restrict__ outh, int R, int Cc)
{
  __shared__ float t[32][33];
  int x  = blockIdx.x * 32 + threadIdx.x;
  int y0 = blockIdx.y * 32;
  for (int dy = threadIdx.y; dy < 32; dy += 8)
    t[dy][threadIdx.x] = in[(size_t)(y0 + dy) * Cc + x];
  __syncthreads();
  int ox  = y0 + threadIdx.x;
  int oy0 = blockIdx.x * 32;
  for (int dy = threadIdx.y; dy < 32; dy += 8)
    outh[(size_t)(oy0 + dy) * R + ox] = f2bf(t[threadIdx.x][dy]);
}

// ---------------- whole-tensor tanh-LN in place on bf16 ---------------------
__global__ __launch_bounds__(256)
void tanhNormBF(ushort* __restrict__ h, const double* __restrict__ pS,
                const double* __restrict__ pS2)
{
  __shared__ float bc[2];
  double a = pS[threadIdx.x], b = pS2[threadIdx.x];
  a = blockSumD(a);
  b = blockSumD(b);
  if (threadIdx.x == 0) {
    double m   = a / (double)CN;
    double var = b / (double)CN - m * m;
    bc[0] = (float)m;
    bc[1] = (float)(1.0 / sqrt(var + 1e-5));
  }
  __syncthreads();
  float mf = bc[0], rs = bc[1];
  for (size_t i = ((size_t)blockIdx.x * 256 + threadIdx.x) * 8; i < CN;
       i += (size_t)256 * 256 * 8) {
    s8v hv = *(s8v*)(h + i);
    #pragma unroll
    for (int k = 0; k < 8; k++) {
      float x = bf2f((ushort)hv[k]);
      x = tanhf((x - mf) * rs);
      hv[k] = (short)f2bf(x);
    }
    *(s8v*)(h + i) = hv;
  }
}

// ---------------- fused per-node sq + per-channel s/h partials ---------------
__global__ __launch_bounds__(256)
void sqSHK(const float* __restrict__ fT, float* __restrict__ sq,
           float* __restrict__ sP, float* __restrict__ hP)
{
  int b = blockIdx.x, w = threadIdx.x >> 6, lane = threadIdx.x & 63;
  float sA[4] = {0,0,0,0}, hA[4] = {0,0,0,0};
  for (int rr = 0; rr < 16; rr++) {
    int n = b * 64 + rr * 4 + w;
    float4 v = ((const float4*)(fT + (size_t)n * CF))[lane];
    float q = waveSumF(v.x*v.x + v.y*v.y + v.z*v.z + v.w*v.w);
    if (lane == 0) sq[n] = q;
    sA[0] += v.x; sA[1] += v.y; sA[2] += v.z; sA[3] += v.w;
    hA[0] += v.x*q; hA[1] += v.y*q; hA[2] += v.z*q; hA[3] += v.w*q;
  }
  int p = b * 4 + w;
  ((float4*)(sP + (size_t)p * CF))[lane] = make_float4(sA[0], sA[1], sA[2], sA[3]);
  ((float4*)(hP + (size_t)p * CF))[lane] = make_float4(hA[0], hA[1], hA[2], hA[3]);
}

// ---------------- std(D) closed form: 64-block partials ----------------------
__global__ __launch_bounds__(256)
void stdPartsK(const float* __restrict__ sP, const float* __restrict__ hP,
               const float* __restrict__ Gp, const float* __restrict__ sq,
               double* __restrict__ parts)
{
  int b = blockIdx.x, t = threadIdx.x;
  double S1 = 0, S2 = 0, sd = 0, hd = 0, gf = 0;
  for (int i = b * 256 + t; i < N_NODES; i += STD_BLOCKS * 256) {
    double q = sq[i]; S1 += q; S2 += q * q;
  }
  if (b == 0) {
    double sv = 0, hv = 0;
    for (int p = 0; p < 256; p++) { sv += sP[p * 256 + t]; hv += hP[p * 256 + t]; }
    sd = sv * sv; hd = hv * sv;
  }
  for (int i = b * 256 + t; i < CF * CF; i += STD_BLOCKS * 256) {
    double g = 0;
    #pragma unroll 4
    for (int z = 0; z < 16; z++) g += Gp[(size_t)z * 65536 + i];
    gf += g * g;
  }
  S1 = blockSumD(S1);
  S2 = blockSumD(S2);
  sd = blockSumD(sd);
  hd = blockSumD(hd);
  gf = blockSumD(gf);
  if (t == 0) {
    parts[0 * STD_BLOCKS + b] = S1;
    parts[1 * STD_BLOCKS + b] = S2;
    parts[2 * STD_BLOCKS + b] = sd;
    parts[3 * STD_BLOCKS + b] = hd;
    parts[4 * STD_BLOCKS + b] = gf;
  }
}

// ---------------- edge affinities + inline std finalize ----------------------
// 4 waves/block, 4 edges per wave. Each block redundantly reduces the 320
// partial doubles to c0 (cheap; kills the 1-block finalize dispatch).
__global__ __launch_bounds__(256)
void edgeWK(const int* __restrict__ ei, const int* __restrict__ ej,
            const float* __restrict__ ft, const float* __restrict__ sq,
            const double* __restrict__ parts, float* __restrict__ wE)
{
  __shared__ float c0s;
  if (threadIdx.x < 64) {
    int l = threadIdx.x;
    double v0 = waveSumD(parts[0 * STD_BLOCKS + l]);
    double v1 = waveSumD(parts[1 * STD_BLOCKS + l]);
    double v2 = waveSumD(parts[2 * STD_BLOCKS + l]);
    double v3 = waveSumD(parts[3 * STD_BLOCKS + l]);
    double v4 = waveSumD(parts[4 * STD_BLOCKS + l]);
    if (l == 0) {
      double NN = (double)N_NODES;
      double sum1 = 2.0 * NN * v0 - 2.0 * v2;
      double sum2 = 2.0 * NN * v1 + 2.0 * v0 * v0 + 4.0 * v4 - 8.0 * v3;
      double n2 = NN * NN;
      double var = (sum2 - sum1 * sum1 / n2) / (n2 - 1.0);
      double sdev = sqrt(var > 0 ? var : 0);
      c0s = (float)(-2.0 / sdev);
    }
  }
  __syncthreads();
  float c0 = c0s;
  int w = threadIdx.x >> 6, lane = threadIdx.x & 63;
  int e0 = (blockIdx.x * 4 + w) * 4;
  for (int q = 0; q < 4; q++) {
    int e = e0 + q;
    int i = ei[e], j = ej[e];
    float4 a = ((const float4*)(ft + (size_t)i * CF))[lane];
    float4 b = ((const float4*)(ft + (size_t)j * CF))[lane];
    float d = waveSumF(a.x*b.x + a.y*b.y + a.z*b.z + a.w*b.w);
    if (lane == 0) {
      float dist = fmaxf(sq[i] + sq[j] - 2.0f * d, 0.0f);
      wE[e] = expf(c0 * dist);
    }
  }
}

// ---------------- deg/dis via CSR-in gather (wave per node) ------------------
__global__ __launch_bounds__(256)
void degK(const int* __restrict__ ofsI, const int* __restrict__ cntI,
          const int2* __restrict__ lstI, const float* __restrict__ wE,
          float* __restrict__ dis)
{
  int n = blockIdx.x * 4 + (threadIdx.x >> 6);
  int lane = threadIdx.x & 63;
  int i0 = ofsI[n], ic = cntI[n];
  float s = 0;
  for (int k = lane; k < ic; k += 64) s += wE[lstI[i0 + k].y];
  s = waveSumF(s);
  if (lane == 0) dis[n] = rsqrtf(1.0f + s);   // +1 = self-loop weight
}

// ---------------- CSR build (edge list is a fixed input) ---------------------
__global__ __launch_bounds__(256)
void csrCountK(const int* __restrict__ ei, const int* __restrict__ ej,
               int* __restrict__ cntO, int* __restrict__ cntI)
{
  int e = blockIdx.x * 256 + threadIdx.x;
  atomicAdd(&cntO[ei[e]], 1);
  atomicAdd(&cntI[ej[e]], 1);
}

__global__ __launch_bounds__(256)
void csrScanK(const int* __restrict__ cntO, const int* __restrict__ cntI,
              int* __restrict__ ofsO, int* __restrict__ ofsI)
{
  __shared__ int smO[256], smI[256];
  int t = threadIdx.x;
  int lo[16], li[16];
  int sO = 0, sI = 0;
  #pragma unroll
  for (int k = 0; k < 16; k++) {
    lo[k] = cntO[t * 16 + k]; li[k] = cntI[t * 16 + k];
    sO += lo[k]; sI += li[k];
  }
  smO[t] = sO; smI[t] = sI;
  __syncthreads();
  for (int off = 1; off < 256; off <<= 1) {
    int aO = (t >= off) ? smO[t - off] : 0;
    int aI = (t >= off) ? smI[t - off] : 0;
    __syncthreads();
    smO[t] += aO; smI[t] += aI;
    __syncthreads();
  }
  int bO = smO[t] - sO;
  int bI = smI[t] - sI;
  #pragma unroll
  for (int k = 0; k < 16; k++) {
    ofsO[t * 16 + k] = bO; bO += lo[k];
    ofsI[t * 16 + k] = bI; bI += li[k];
  }
}

__global__ __launch_bounds__(256)
void csrFillK(const int* __restrict__ ei, const int* __restrict__ ej,
              const int* __restrict__ ofsO, const int* __restrict__ ofsI,
              int* __restrict__ curO, int* __restrict__ curI,
              int2* __restrict__ lstO, int2* __restrict__ lstI)
{
  int e = blockIdx.x * 256 + threadIdx.x;
  int i = ei[e], j = ej[e];
  int p = atomicAdd(&curO[i], 1); lstO[ofsO[i] + p] = make_int2(j, e);
  int q = atomicAdd(&curI[j], 1); lstI[ofsI[j] + q] = make_int2(i, e);
}

// ---------------- graph Laplacian gather -> bf16 (no atomics) ----------------
__global__ __launch_bounds__(256)
void gatherLapK(const int2* __restrict__ lstO, const int2* __restrict__ lstI,
                const int* __restrict__ ofsO, const int* __restrict__ ofsI,
                const int* __restrict__ cntO, const int* __restrict__ cntI,
                const float* __restrict__ wE, const float* __restrict__ dis,
                const float* __restrict__ fT, ushort* __restrict__ lapTh)
{
  int n = blockIdx.x, c = threadIdx.x;
  float own = fT[(size_t)n * CF + c];
  float dn = dis[n];
  float acc = 0.0f;
  int o0 = ofsO[n], oc = cntO[n];
  for (int k = 0; k < oc; k++) {
    int2 oe = lstO[o0 + k];
    float W = dn * wE[oe.y] * dis[oe.x];
    acc += (W * W) * (own - fT[(size_t)oe.x * CF + c]);
  }
  int i0 = ofsI[n], ic = cntI[n];
  for (int k = 0; k < ic; k++) {
    int2 oe = lstI[i0 + k];
    float W = dis[oe.x] * wE[oe.y] * dn;
    acc -= (W * W) * (fT[(size_t)oe.x * CF + c] - own);
  }
  lapTh[(size_t)n * CF + c] = f2bf(acc);
}

// ---------------- row log-softmax ----------------
__global__ __launch_bounds__(256)
void logSoftmaxK(const float* __restrict__ logits, float* __restrict__ out)
{
  int n = blockIdx.x;
  const float* row = logits + (size_t)n * NOUT;
  float mx = -1e30f;
  for (int o = threadIdx.x; o < NOUT; o += 256) mx = fmaxf(mx, row[o]);
  mx = blockMaxF(mx);
  float se = 0;
  for (int o = threadIdx.x; o < NOUT; o += 256) se += expf(row[o] - mx);
  se = blockSumF(se);
  float lse = mx + logf(se);
  for (int o = threadIdx.x; o < NOUT; o += 256) out[(size_t)n * NOUT + o] = row[o] - lse;
}

extern "C" void kernel_launch(void* const* d_in, const int* in_sizes, int n_in,
                              void* d_out, int out_size, void* d_ws, size_t ws_size,
                              hipStream_t stream)
{
  (void)in_sizes; (void)n_in; (void)out_size; (void)ws_size;
  const float* x0      = (const float*)d_in[0];
  const float* K1      = (const float*)d_in[1];
  const float* K2      = (const float*)d_in[2];
  const float* KNclose = (const float*)d_in[3];
  const float* KN1     = (const float*)d_in[4];
  const float* KN2     = (const float*)d_in[5];
  const float* lin1w   = (const float*)d_in[6];
  const float* lin1b   = (const float*)d_in[7];
  const float* lin2w   = (const float*)d_in[8];
  const float* lin2b   = (const float*)d_in[9];
  const int*   ei      = (const int*)d_in[10];
  const int*   ej      = (const int*)d_in[11];
  float* out = (float*)d_out;

  // ---------------- workspace layout ----------------
  float* base   = (float*)d_ws;
  float* fT     = base;                     // [N][CF] f32 residual features
  float* logits = fT + (size_t)CN;          // [N][NOUT]
  float* Gp     = logits + 4 * (size_t)CN;  // [16][256*256] Gram split-K partials
  float* sq     = Gp + (size_t)CN;          // [N]
  float* dis    = sq + N_NODES;             // [N]
  float* sP     = dis + N_NODES;            // [256][256]
  float* hP     = sP + 65536;               // [256][256]
  float* wE     = hP + 65536;               // [E0]
  double* pS    = (double*)(wE + E0_EDGES + 2);  // [256]
  double* pS2   = pS + 256;                 // [256]
  double* parts = pS2 + 256;                // [5*64]

  ushort* u0 = (ushort*)(((uintptr_t)(parts + 5 * STD_BLOCKS) + 15) & ~(uintptr_t)15);
  ushort* fTh   = u0;                       // [N][CF] bf16 features
  ushort* fh    = fTh + (size_t)CN;         // [CF][N] transposed bf16 (x0T at open)
  ushort* lapTh = fh + (size_t)CN;          // lap bf16; x1 at close
  ushort* uTh   = lapTh + (size_t)CN;       // intermediate bf16; y at close
  ushort* wH    = uTh + (size_t)CN;         // all weights bf16
  int* ib = (int*)(((uintptr_t)(wH + NW_TOT) + 15) & ~(uintptr_t)15);
  int*  cntO = ib;
  int*  cntI = cntO + N_NODES;
  int*  ofsO = cntI + N_NODES;
  int*  ofsI = ofsO + N_NODES;
  int*  curO = ofsI + N_NODES;
  int*  curI = curO + N_NODES;
  int2* lstO = (int2*)(curI + N_NODES);
  int2* lstI = lstO + E0_EDGES;

  // ---- one-time: weight bf16 + CSR ----
  prepWK<<<dim3(64, 7), 256, 0, stream>>>(K1, K2, KNclose, KN1, KN2, lin1w, lin2w, wH);
  hipMemsetAsync(cntO, 0, 6 * N_NODES * sizeof(int), stream);
  csrCountK<<<E0_EDGES/256, 256, 0, stream>>>(ei, ej, cntO, cntI);
  csrScanK<<<1, 256, 0, stream>>>(cntO, cntI, ofsO, ofsI);
  csrFillK<<<E0_EDGES/256, 256, 0, stream>>>(ei, ej, ofsO, ofsI, curO, curI, lstO, lstI);

  // ---- opening: fT = tanh(LN(x0T·K1^T))·K2^T ----
  transposeBF<<<dim3(N_NODES/32, CIN/32), dim3(32, 8), 0, stream>>>(x0, fh, CIN, N_NODES);
  gemmB1<0,0,1,1><<<dim3(4,64,1), 256, 0, stream>>>(
      fh, fh, CIN, 1 << 30, wH + OFF_K1, CIN,
      nullptr, uTh, CF, 0, CIN, 1.f, 0.f, nullptr, pS, pS2);
  tanhNormBF<<<256, 256, 0, stream>>>(uTh, pS, pS2);
  gemmB1<0,1,1,0><<<dim3(4,64,1), 256, 0, stream>>>(
      uTh, uTh, CF, 1 << 30, wH + OFF_K2, CF,
      fT, fTh, CF, 0, CF, 1.f, 0.f, nullptr, nullptr, nullptr);

  for (int L = 0; L < NLAYER; L++) {
    const ushort* k1h = wH + OFF_KN1 + (size_t)L * CF * 2 * CF;
    const ushort* k2h = wH + OFF_KN2 + (size_t)L * CF * CF;

    transposeBF<<<dim3(CF/32, N_NODES/32), dim3(32, 8), 0, stream>>>(fT, fh, N_NODES, CF);
    sqSHK<<<64, 256, 0, stream>>>(fT, sq, sP, hP);
    // Gram split-K=16 partials
    gemmB1<0,1,0,0><<<dim3(4,4,16), 256, 0, stream>>>(
        fh, fh, N_NODES, 1 << 30, fh, N_NODES,
        Gp, nullptr, CF, 65536, 256, 1.f, 0.f, nullptr, nullptr, nullptr);
    stdPartsK<<<STD_BLOCKS, 256, 0, stream>>>(sP, hP, Gp, sq, parts);
    edgeWK<<<E0_EDGES/16, 256, 0, stream>>>(ei, ej, fT, sq, parts, wE);
    degK<<<N_NODES/4, 256, 0, stream>>>(ofsI, cntI, lstI, wE, dis);
    gatherLapK<<<N_NODES, 256, 0, stream>>>(lstO, lstI, ofsO, ofsI, cntO, cntI,
                                            wE, dis, fT, lapTh);
    // uT = [fT, lapT]·KN1^T (fused K=512 dual-A) + LN-stat partials
    gemmB1<0,0,1,1><<<dim3(4,64,1), 256, 0, stream>>>(
        fTh, lapTh, CF, 256, k1h, 2*CF,
        nullptr, uTh, CF, 0, 2*CF, 1.f, 0.f, nullptr, pS, pS2);
    tanhNormBF<<<256, 256, 0, stream>>>(uTh, pS, pS2);
    // fT += 0.1 · uT·KN2^T
    gemmB1<0,1,1,0><<<dim3(4,64,1), 256, 0, stream>>>(
        uTh, uTh, CF, 1 << 30, k2h, CF,
        fT, fTh, CF, 0, CF, 0.1f, 1.f, nullptr, nullptr, nullptr);
  }

  // ---- close: y = fT·KNclose^T ; x1 = elu(y·lin1^T+b1) ; logits ; log_softmax ----
  gemmB1<0,0,1,0><<<dim3(4,64,1), 256, 0, stream>>>(
      fTh, fTh, CF, 1 << 30, wH + OFF_KNC, CF,
      nullptr, uTh, CF, 0, CF, 1.f, 0.f, nullptr, nullptr, nullptr);
  gemmB1<1,0,1,0><<<dim3(4,64,1), 256, 0, stream>>>(
      uTh, uTh, CF, 1 << 30, wH + OFF_L1, CF,
      nullptr, lapTh, CF, 0, CF, 1.f, 0.f, lin1b, nullptr, nullptr);
  gemmB1<0,1,0,0><<<dim3(16,64,1), 256, 0, stream>>>(
      lapTh, lapTh, CF, 1 << 30, wH + OFF_L2, CF,
      logits, nullptr, NOUT, 0, CF, 1.f, 0.f, lin2b, nullptr, nullptr);
  logSoftmaxK<<<N_NODES, 256, 0, stream>>>(logits, out);
}

// Round 7
// 885.141 us; speedup vs baseline: 4.0836x; 1.1108x over previous
//
#include <hip/hip_runtime.h>
#include <hip/hip_bf16.h>

// Problem constants (fixed instance)
#define N_NODES 4096
#define CF      256
#define CIN     64
#define E0_EDGES 65536
#define NLAYER  8
#define NOUT    1024
#define CN      (CF * N_NODES)
#define STD_BLOCKS 64

typedef unsigned short ushort;
typedef __attribute__((ext_vector_type(8))) short s8v;   // 8 bf16
typedef __attribute__((ext_vector_type(4))) float f4v;   // MFMA acc

__device__ __forceinline__ ushort f2bf(float x){
  unsigned int u = __builtin_bit_cast(unsigned int, x);
  return (ushort)((u + 0x7FFFu + ((u >> 16) & 1u)) >> 16);
}
__device__ __forceinline__ float bf2f(ushort h){
  unsigned int u = ((unsigned int)h) << 16;
  return __builtin_bit_cast(float, u);
}

// ---------------- reduction helpers ----------------
__device__ __forceinline__ float waveSumF(float v){
  #pragma unroll
  for (int o = 32; o; o >>= 1) v += __shfl_xor(v, o);
  return v;
}
__device__ __forceinline__ double waveSumD(double v){
  #pragma unroll
  for (int o = 32; o; o >>= 1) v += __shfl_xor(v, o);
  return v;
}
__device__ __forceinline__ float waveMaxF(float v){
  #pragma unroll
  for (int o = 32; o; o >>= 1) v = fmaxf(v, __shfl_xor(v, o));
  return v;
}
__device__ float blockSumF(float v){
  __shared__ float sm[4];
  v = waveSumF(v);
  int l = threadIdx.x & 63, w = threadIdx.x >> 6;
  __syncthreads();
  if (l == 0) sm[w] = v;
  __syncthreads();
  return sm[0] + sm[1] + sm[2] + sm[3];
}
__device__ double blockSumD(double v){
  __shared__ double sm[4];
  v = waveSumD(v);
  int l = threadIdx.x & 63, w = threadIdx.x >> 6;
  __syncthreads();
  if (l == 0) sm[w] = v;
  __syncthreads();
  return sm[0] + sm[1] + sm[2] + sm[3];
}
__device__ float blockMaxF(float v){
  __shared__ float sm[4];
  v = waveMaxF(v);
  int l = threadIdx.x & 63, w = threadIdx.x >> 6;
  __syncthreads();
  if (l == 0) sm[w] = v;
  __syncthreads();
  return fmaxf(fmaxf(sm[0], sm[1]), fmaxf(sm[2], sm[3]));
}

// ---------------- bf16 MFMA GEMM, double-buffered, templated BK --------------
// C[M,N] = alpha*A·B^T (+beta*Cf, +bias, act). A,B bf16 row-major K-contiguous.
// A rows split across A1/A2 at K=splitAt. 64x64 tile, 4 waves (2x2 of 32x32).
// WFH: additionally write transposed bf16 Cfh[col][row] (ldfh = N_NODES).
// cStrideZ!=0: write per-z split-K partials (plain store).
#define MF(a,b,c) c = __builtin_amdgcn_mfma_f32_16x16x32_bf16(a, b, c, 0, 0, 0)

template<int BK, int ACT, bool WF32, bool WBF, bool WFH, bool MV>
__global__ __launch_bounds__(256)
void gemmB1(const ushort* __restrict__ A1, const ushort* __restrict__ A2,
            int lda, int splitAt,
            const ushort* __restrict__ B, int ldb,
            float* __restrict__ Cf, ushort* __restrict__ Cb, ushort* __restrict__ Cfh,
            int ldc, size_t cStrideZ, int kChunk,
            float alpha, float beta, const float* __restrict__ bias,
            double* __restrict__ pS, double* __restrict__ pS2)
{
  constexpr int NC = BK / 32;                     // s8v chunks per thread per matrix
  __shared__ ushort As[2][64][BK + 8], Bs[2][64][BK + 8];
  const int tid = threadIdx.x;
  const int r  = tid >> 2;                        // staging row 0..63
  const int kq = (tid & 3) * (BK / 4);
  const int row0 = blockIdx.y * 64, col0 = blockIdx.x * 64;
  const int kStart = blockIdx.z * kChunk;
  const int nT = kChunk / BK;

  const int wid = tid >> 6, lane = tid & 63;
  const int wr = (wid >> 1) * 32, wc = (wid & 1) * 32;
  const int fr = lane & 15, fk = (lane >> 4) * 8;

  f4v acc[2][2] = {};
  s8v ra[NC], rb[NC];

#define LOADTILE(T) { \
    int k0 = kStart + (T) * BK; \
    const ushort* Ag; int kk; \
    if (k0 < splitAt) { Ag = A1; kk = k0; } else { Ag = A2; kk = k0 - splitAt; } \
    size_t aoff = (size_t)(row0 + r) * lda + kk + kq; \
    size_t boff = (size_t)(col0 + r) * ldb + k0 + kq; \
    _Pragma("unroll") \
    for (int c = 0; c < NC; c++) { \
      ra[c] = *(const s8v*)(A1 + 0, Ag + aoff + 8 * c); \
      rb[c] = *(const s8v*)(B + boff + 8 * c); } }

#define STORETILE(BUF) { \
    _Pragma("unroll") \
    for (int c = 0; c < NC; c++) { \
      *(s8v*)&As[BUF][r][kq + 8 * c] = ra[c]; \
      *(s8v*)&Bs[BUF][r][kq + 8 * c] = rb[c]; } }

  LOADTILE(0);
  STORETILE(0);

  for (int t = 0; t < nT; t++) {
    const int cur = t & 1;
    if (t + 1 < nT) LOADTILE(t + 1);          // in flight during MFMA below
    __syncthreads();                           // tile t visible; t-1 reads done
    #pragma unroll
    for (int ks = 0; ks < BK; ks += 32) {
      s8v a0 = *(const s8v*)&As[cur][wr + fr][ks + fk];
      s8v a1 = *(const s8v*)&As[cur][wr + 16 + fr][ks + fk];
      s8v b0 = *(const s8v*)&Bs[cur][wc + fr][ks + fk];
      s8v b1 = *(const s8v*)&Bs[cur][wc + 16 + fr][ks + fk];
      MF(a0, b0, acc[0][0]);
      MF(a0, b1, acc[0][1]);
      MF(a1, b0, acc[1][0]);
      MF(a1, b1, acc[1][1]);
    }
    if (t + 1 < nT) STORETILE(cur ^ 1);        // buf nxt last read before barrier
  }
#undef LOADTILE
#undef STORETILE

  double s = 0, s2 = 0;
  #pragma unroll
  for (int m = 0; m < 2; m++)
    #pragma unroll
    for (int n = 0; n < 2; n++) {
      const int rowb = row0 + wr + m * 16 + (lane >> 4) * 4;
      const int col  = col0 + wc + n * 16 + fr;
      ushort4 hv;
      #pragma unroll
      for (int q = 0; q < 4; q++) {
        size_t cidx = (size_t)(rowb + q) * ldc + col;
        float v = alpha * acc[m][n][q];
        if (cStrideZ) {
          Cf[blockIdx.z * cStrideZ + cidx] = v;
        } else {
          if (beta != 0.0f) v += beta * Cf[cidx];
          if (bias) v += bias[col];
          if (ACT == 1) v = (v > 0.0f) ? v : expm1f(v);
          if (WF32) Cf[cidx] = v;
          if (WBF)  Cb[cidx] = f2bf(v);
          if (WFH)  ((ushort*)&hv)[q] = f2bf(v);
          if (MV)   { s += v; s2 += (double)v * v; }
        }
      }
      if (WFH && !cStrideZ)
        *(ushort4*)(Cfh + (size_t)col * N_NODES + rowb) = hv;
    }
  if (MV) {
    s  = blockSumD(s);
    s2 = blockSumD(s2);
    if (tid == 0) {
      int bid = blockIdx.y * gridDim.x + blockIdx.x;   // stats grids are 256 blocks
      pS[bid] = s; pS2[bid] = s2;
    }
  }
}

// ---------------- weight f32 -> bf16 (once per launch) ----------------------
#define OFF_K1   0
#define OFF_K2   16384
#define OFF_KNC  81920
#define OFF_KN1  147456
#define OFF_KN2  1196032
#define OFF_L1   1720320
#define OFF_L2   1785856
#define NW_TOT   2048000

__global__ __launch_bounds__(256)
void prepWK(const float* s0, const float* s1, const float* s2, const float* s3,
            const float* s4, const float* s5, const float* s6,
            ushort* __restrict__ h)
{
  const int sizes[7] = {16384, 65536, 65536, 1048576, 524288, 65536, 262144};
  const int offs[7]  = {OFF_K1, OFF_K2, OFF_KNC, OFF_KN1, OFF_KN2, OFF_L1, OFF_L2};
  int seg = blockIdx.y;
  const float* src = seg==0?s0: seg==1?s1: seg==2?s2: seg==3?s3: seg==4?s4: seg==5?s5: s6;
  int n = sizes[seg], off = offs[seg];
  for (int i = blockIdx.x * 256 + threadIdx.x; i < n; i += gridDim.x * 256)
    h[off + i] = f2bf(src[i]);
}

// ---------------- transpose f32 [R][Cc] -> bf16 [Cc][R] (open only) ----------
__global__ __launch_bounds__(256)
void transposeBF(const float* __restrict__ in, ushort* __restrict__ outh, int R, int Cc)
{
  __shared__ float t[32][33];
  int x  = blockIdx.x * 32 + threadIdx.x;
  int y0 = blockIdx.y * 32;
  for (int dy = threadIdx.y; dy < 32; dy += 8)
    t[dy][threadIdx.x] = in[(size_t)(y0 + dy) * Cc + x];
  __syncthreads();
  int ox  = y0 + threadIdx.x;
  int oy0 = blockIdx.x * 32;
  for (int dy = threadIdx.y; dy < 32; dy += 8)
    outh[(size_t)(oy0 + dy) * R + ox] = f2bf(t[threadIdx.x][dy]);
}

// ---------------- whole-tensor tanh-LN in place on bf16 ---------------------
__global__ __launch_bounds__(256)
void tanhNormBF(ushort* __restrict__ h, const double* __restrict__ pS,
                const double* __restrict__ pS2)
{
  __shared__ float bc[2];
  double a = pS[threadIdx.x], b = pS2[threadIdx.x];
  a = blockSumD(a);
  b = blockSumD(b);
  if (threadIdx.x == 0) {
    double m   = a / (double)CN;
    double var = b / (double)CN - m * m;
    bc[0] = (float)m;
    bc[1] = (float)(1.0 / sqrt(var + 1e-5));
  }
  __syncthreads();
  float mf = bc[0], rs = bc[1];
  for (size_t i = ((size_t)blockIdx.x * 256 + threadIdx.x) * 8; i < CN;
       i += (size_t)256 * 256 * 8) {
    s8v hv = *(s8v*)(h + i);
    #pragma unroll
    for (int k = 0; k < 8; k++) {
      float x = bf2f((ushort)hv[k]);
      x = tanhf((x - mf) * rs);
      hv[k] = (short)f2bf(x);
    }
    *(s8v*)(h + i) = hv;
  }
}

// ---------------- fused sq + s/h block-partials + deg zero (bf16 in) ---------
__global__ __launch_bounds__(256)
void sqSHK(const ushort* __restrict__ fTh, float* __restrict__ sq,
           float* __restrict__ sP, float* __restrict__ hP, float* __restrict__ deg)
{
  __shared__ float smS[4][256], smH[4][256];
  int b = blockIdx.x, w = threadIdx.x >> 6, lane = threadIdx.x & 63;
  if (threadIdx.x < 64) deg[b * 64 + threadIdx.x] = 0.0f;
  float sA[4] = {0,0,0,0}, hA[4] = {0,0,0,0};
  for (int rr = 0; rr < 16; rr++) {
    int n = b * 64 + rr * 4 + w;
    ushort4 u = ((const ushort4*)(fTh + (size_t)n * CF))[lane];
    float x0 = bf2f(u.x), x1 = bf2f(u.y), x2 = bf2f(u.z), x3 = bf2f(u.w);
    float q = waveSumF(x0*x0 + x1*x1 + x2*x2 + x3*x3);
    if (lane == 0) sq[n] = q;
    sA[0] += x0; sA[1] += x1; sA[2] += x2; sA[3] += x3;
    hA[0] += x0*q; hA[1] += x1*q; hA[2] += x2*q; hA[3] += x3*q;
  }
  #pragma unroll
  for (int k = 0; k < 4; k++) { smS[w][lane*4+k] = sA[k]; smH[w][lane*4+k] = hA[k]; }
  __syncthreads();
  int t = threadIdx.x;
  sP[(size_t)b * 256 + t] = smS[0][t] + smS[1][t] + smS[2][t] + smS[3][t];
  hP[(size_t)b * 256 + t] = smH[0][t] + smH[1][t] + smH[2][t] + smH[3][t];
}

// ---------------- std(D) closed form: 64-block partials ----------------------
__global__ __launch_bounds__(256)
void stdPartsK(const float* __restrict__ sP, const float* __restrict__ hP,
               const float* __restrict__ Gp, const float* __restrict__ sq,
               double* __restrict__ parts)
{
  int b = blockIdx.x, t = threadIdx.x;
  double S1 = 0, S2 = 0, sd = 0, hd = 0, gf = 0;
  for (int i = b * 256 + t; i < N_NODES; i += STD_BLOCKS * 256) {
    double q = sq[i]; S1 += q; S2 += q * q;
  }
  if (b == 0) {
    float sv = 0, hv = 0;
    for (int p = 0; p < 64; p++) { sv += sP[p * 256 + t]; hv += hP[p * 256 + t]; }
    sd = (double)sv * sv; hd = (double)hv * sv;
  }
  for (int i = b * 256 + t; i < CF * CF; i += STD_BLOCKS * 256) {
    double g = 0;
    #pragma unroll 4
    for (int z = 0; z < 16; z++) g += Gp[(size_t)z * 65536 + i];
    gf += g * g;
  }
  S1 = blockSumD(S1);
  S2 = blockSumD(S2);
  sd = blockSumD(sd);
  hd = blockSumD(hd);
  gf = blockSumD(gf);
  if (t == 0) {
    parts[0 * STD_BLOCKS + b] = S1;
    parts[1 * STD_BLOCKS + b] = S2;
    parts[2 * STD_BLOCKS + b] = sd;
    parts[3 * STD_BLOCKS + b] = hd;
    parts[4 * STD_BLOCKS + b] = gf;
  }
}

// ---------------- edge affinities + inline std finalize + deg atomics --------
__global__ __launch_bounds__(256)
void edgeWK(const int* __restrict__ ei, const int* __restrict__ ej,
            const ushort* __restrict__ fTh, const float* __restrict__ sq,
            const double* __restrict__ parts, float* __restrict__ wE,
            float* __restrict__ deg)
{
  __shared__ float c0s;
  if (threadIdx.x < 64) {
    int l = threadIdx.x;
    double v0 = waveSumD(parts[0 * STD_BLOCKS + l]);
    double v1 = waveSumD(parts[1 * STD_BLOCKS + l]);
    double v2 = waveSumD(parts[2 * STD_BLOCKS + l]);
    double v3 = waveSumD(parts[3 * STD_BLOCKS + l]);
    double v4 = waveSumD(parts[4 * STD_BLOCKS + l]);
    if (l == 0) {
      double NN = (double)N_NODES;
      double sum1 = 2.0 * NN * v0 - 2.0 * v2;
      double sum2 = 2.0 * NN * v1 + 2.0 * v0 * v0 + 4.0 * v4 - 8.0 * v3;
      double n2 = NN * NN;
      double var = (sum2 - sum1 * sum1 / n2) / (n2 - 1.0);
      double sdev = sqrt(var > 0 ? var : 0);
      c0s = (float)(-2.0 / sdev);
    }
  }
  __syncthreads();
  float c0 = c0s;
  int w = threadIdx.x >> 6, lane = threadIdx.x & 63;
  int e0 = (blockIdx.x * 4 + w) * 4;
  for (int q = 0; q < 4; q++) {
    int e = e0 + q;
    int i = ei[e], j = ej[e];
    ushort4 ua = ((const ushort4*)(fTh + (size_t)i * CF))[lane];
    ushort4 ub = ((const ushort4*)(fTh + (size_t)j * CF))[lane];
    float d = waveSumF(bf2f(ua.x)*bf2f(ub.x) + bf2f(ua.y)*bf2f(ub.y) +
                       bf2f(ua.z)*bf2f(ub.z) + bf2f(ua.w)*bf2f(ub.w));
    if (lane == 0) {
      float dist = fmaxf(sq[i] + sq[j] - 2.0f * d, 0.0f);
      float ww = expf(c0 * dist);
      wE[e] = ww;
      unsafeAtomicAdd(&deg[j], ww);
    }
  }
}

// ---------------- CSR build (edge list is a fixed input) ---------------------
__global__ __launch_bounds__(256)
void csrCountK(const int* __restrict__ ei, const int* __restrict__ ej,
               int* __restrict__ cntO, int* __restrict__ cntI)
{
  int e = blockIdx.x * 256 + threadIdx.x;
  atomicAdd(&cntO[ei[e]], 1);
  atomicAdd(&cntI[ej[e]], 1);
}

__global__ __launch_bounds__(256)
void csrScanK(const int* __restrict__ cntO, const int* __restrict__ cntI,
              int* __restrict__ ofsO, int* __restrict__ ofsI)
{
  __shared__ int smO[256], smI[256];
  int t = threadIdx.x;
  int lo[16], li[16];
  int sO = 0, sI = 0;
  #pragma unroll
  for (int k = 0; k < 16; k++) {
    lo[k] = cntO[t * 16 + k]; li[k] = cntI[t * 16 + k];
    sO += lo[k]; sI += li[k];
  }
  smO[t] = sO; smI[t] = sI;
  __syncthreads();
  for (int off = 1; off < 256; off <<= 1) {
    int aO = (t >= off) ? smO[t - off] : 0;
    int aI = (t >= off) ? smI[t - off] : 0;
    __syncthreads();
    smO[t] += aO; smI[t] += aI;
    __syncthreads();
  }
  int bO = smO[t] - sO;
  int bI = smI[t] - sI;
  #pragma unroll
  for (int k = 0; k < 16; k++) {
    ofsO[t * 16 + k] = bO; bO += lo[k];
    ofsI[t * 16 + k] = bI; bI += li[k];
  }
}

__global__ __launch_bounds__(256)
void csrFillK(const int* __restrict__ ei, const int* __restrict__ ej,
              const int* __restrict__ ofsO, const int* __restrict__ ofsI,
              int* __restrict__ curO, int* __restrict__ curI,
              int2* __restrict__ lstO, int2* __restrict__ lstI)
{
  int e = blockIdx.x * 256 + threadIdx.x;
  int i = ei[e], j = ej[e];
  int p = atomicAdd(&curO[i], 1); lstO[ofsO[i] + p] = make_int2(j, e);
  int q = atomicAdd(&curI[j], 1); lstI[ofsI[j] + q] = make_int2(i, e);
}

// ---------------- graph Laplacian gather, bf16 in/out, dis on the fly --------
__global__ __launch_bounds__(256)
void gatherLapK(const int2* __restrict__ lstO, const int2* __restrict__ lstI,
                const int* __restrict__ ofsO, const int* __restrict__ ofsI,
                const int* __restrict__ cntO, const int* __restrict__ cntI,
                const float* __restrict__ wE, const float* __restrict__ deg,
                const ushort* __restrict__ fTh, ushort* __restrict__ lapTh)
{
  int n = blockIdx.x, c = threadIdx.x;
  float own = bf2f(fTh[(size_t)n * CF + c]);
  float dn = rsqrtf(1.0f + deg[n]);
  float acc = 0.0f;
  int o0 = ofsO[n], oc = cntO[n];
  for (int k = 0; k < oc; k++) {
    int2 oe = lstO[o0 + k];
    float W = dn * wE[oe.y] * rsqrtf(1.0f + deg[oe.x]);
    acc += (W * W) * (own - bf2f(fTh[(size_t)oe.x * CF + c]));
  }
  int i0 = ofsI[n], ic = cntI[n];
  for (int k = 0; k < ic; k++) {
    int2 oe = lstI[i0 + k];
    float W = rsqrtf(1.0f + deg[oe.x]) * wE[oe.y] * dn;
    acc -= (W * W) * (bf2f(fTh[(size_t)oe.x * CF + c]) - own);
  }
  lapTh[(size_t)n * CF + c] = f2bf(acc);
}

// ---------------- row log-softmax ----------------
__global__ __launch_bounds__(256)
void logSoftmaxK(const float* __restrict__ logits, float* __restrict__ out)
{
  int n = blockIdx.x;
  const float* row = logits + (size_t)n * NOUT;
  float mx = -1e30f;
  for (int o = threadIdx.x; o < NOUT; o += 256) mx = fmaxf(mx, row[o]);
  mx = blockMaxF(mx);
  float se = 0;
  for (int o = threadIdx.x; o < NOUT; o += 256) se += expf(row[o] - mx);
  se = blockSumF(se);
  float lse = mx + logf(se);
  for (int o = threadIdx.x; o < NOUT; o += 256) out[(size_t)n * NOUT + o] = row[o] - lse;
}

extern "C" void kernel_launch(void* const* d_in, const int* in_sizes, int n_in,
                              void* d_out, int out_size, void* d_ws, size_t ws_size,
                              hipStream_t stream)
{
  (void)in_sizes; (void)n_in; (void)out_size; (void)ws_size;
  const float* x0      = (const float*)d_in[0];
  const float* K1      = (const float*)d_in[1];
  const float* K2      = (const float*)d_in[2];
  const float* KNclose = (const float*)d_in[3];
  const float* KN1     = (const float*)d_in[4];
  const float* KN2     = (const float*)d_in[5];
  const float* lin1w   = (const float*)d_in[6];
  const float* lin1b   = (const float*)d_in[7];
  const float* lin2w   = (const float*)d_in[8];
  const float* lin2b   = (const float*)d_in[9];
  const int*   ei      = (const int*)d_in[10];
  const int*   ej      = (const int*)d_in[11];
  float* out = (float*)d_out;

  // ---------------- workspace layout ----------------
  float* base   = (float*)d_ws;
  float* fT     = base;                     // [N][CF] f32 residual features
  float* logits = fT + (size_t)CN;          // [N][NOUT]
  float* Gp     = logits + 4 * (size_t)CN;  // [16][256*256] Gram split-K partials
  float* sq     = Gp + (size_t)CN;          // [N]
  float* deg    = sq + N_NODES;             // [N]
  float* sP     = deg + N_NODES;            // [64][256]
  float* hP     = sP + 64 * 256;            // [64][256]
  float* wE     = hP + 64 * 256;            // [E0]
  double* pS    = (double*)(wE + E0_EDGES + 2);  // [256]
  double* pS2   = pS + 256;                 // [256]
  double* parts = pS2 + 256;                // [5*64]

  ushort* u0 = (ushort*)(((uintptr_t)(parts + 5 * STD_BLOCKS) + 15) & ~(uintptr_t)15);
  ushort* fTh   = u0;                       // [N][CF] bf16 features
  ushort* fh    = fTh + (size_t)CN;         // [CF][N] transposed bf16 (xt at open)
  ushort* lapTh = fh + (size_t)CN;          // lap bf16; x1 at close
  ushort* uTh   = lapTh + (size_t)CN;       // intermediate bf16; y at close
  ushort* wH    = uTh + (size_t)CN;         // all weights bf16
  int* ib = (int*)(((uintptr_t)(wH + NW_TOT) + 15) & ~(uintptr_t)15);
  int*  cntO = ib;
  int*  cntI = cntO + N_NODES;
  int*  ofsO = cntI + N_NODES;
  int*  ofsI = ofsO + N_NODES;
  int*  curO = ofsI + N_NODES;
  int*  curI = curO + N_NODES;
  int2* lstO = (int2*)(curI + N_NODES);
  int2* lstI = lstO + E0_EDGES;

  // ---- one-time: weight bf16 + CSR ----
  prepWK<<<dim3(64, 7), 256, 0, stream>>>(K1, K2, KNclose, KN1, KN2, lin1w, lin2w, wH);
  hipMemsetAsync(cntO, 0, 6 * N_NODES * sizeof(int), stream);
  csrCountK<<<E0_EDGES/256, 256, 0, stream>>>(ei, ej, cntO, cntI);
  csrScanK<<<1, 256, 0, stream>>>(cntO, cntI, ofsO, ofsI);
  csrFillK<<<E0_EDGES/256, 256, 0, stream>>>(ei, ej, ofsO, ofsI, curO, curI, lstO, lstI);

  // ---- opening: fT = tanh(LN(x0T·K1^T))·K2^T ----
  transposeBF<<<dim3(N_NODES/32, CIN/32), dim3(32, 8), 0, stream>>>(x0, fh, CIN, N_NODES);
  gemmB1<64,0,0,1,0,1><<<dim3(4,64,1), 256, 0, stream>>>(
      fh, fh, CIN, 1 << 30, wH + OFF_K1, CIN,
      nullptr, uTh, nullptr, CF, 0, CIN, 1.f, 0.f, nullptr, pS, pS2);
  tanhNormBF<<<256, 256, 0, stream>>>(uTh, pS, pS2);
  gemmB1<128,0,1,1,1,0><<<dim3(4,64,1), 256, 0, stream>>>(
      uTh, uTh, CF, 1 << 30, wH + OFF_K2, CF,
      fT, fTh, fh, CF, 0, CF, 1.f, 0.f, nullptr, nullptr, nullptr);

  for (int L = 0; L < NLAYER; L++) {
    const ushort* k1h = wH + OFF_KN1 + (size_t)L * CF * 2 * CF;
    const ushort* k2h = wH + OFF_KN2 + (size_t)L * CF * CF;

    sqSHK<<<64, 256, 0, stream>>>(fTh, sq, sP, hP, deg);
    // Gram split-K=16 partials (reads transposed fh)
    gemmB1<128,0,1,0,0,0><<<dim3(4,4,16), 256, 0, stream>>>(
        fh, fh, N_NODES, 1 << 30, fh, N_NODES,
        Gp, nullptr, nullptr, CF, 65536, 256, 1.f, 0.f, nullptr, nullptr, nullptr);
    stdPartsK<<<STD_BLOCKS, 256, 0, stream>>>(sP, hP, Gp, sq, parts);
    edgeWK<<<E0_EDGES/16, 256, 0, stream>>>(ei, ej, fTh, sq, parts, wE, deg);
    gatherLapK<<<N_NODES, 256, 0, stream>>>(lstO, lstI, ofsO, ofsI, cntO, cntI,
                                            wE, deg, fTh, lapTh);
    // uT = [fT, lapT]·KN1^T (fused K=512 dual-A) + LN-stat partials
    gemmB1<128,0,0,1,0,1><<<dim3(4,64,1), 256, 0, stream>>>(
        fTh, lapTh, CF, 256, k1h, 2*CF,
        nullptr, uTh, nullptr, CF, 0, 2*CF, 1.f, 0.f, nullptr, pS, pS2);
    tanhNormBF<<<256, 256, 0, stream>>>(uTh, pS, pS2);
    // fT += 0.1 · uT·KN2^T  (writes f32 fT, bf16 fTh, transposed bf16 fh)
    gemmB1<128,0,1,1,1,0><<<dim3(4,64,1), 256, 0, stream>>>(
        uTh, uTh, CF, 1 << 30, k2h, CF,
        fT, fTh, fh, CF, 0, CF, 0.1f, 1.f, nullptr, nullptr, nullptr);
  }

  // ---- close: y = fT·KNclose^T ; x1 = elu(y·lin1^T+b1) ; logits ; log_softmax ----
  gemmB1<128,0,0,1,0,0><<<dim3(4,64,1), 256, 0, stream>>>(
      fTh, fTh, CF, 1 << 30, wH + OFF_KNC, CF,
      nullptr, uTh, nullptr, CF, 0, CF, 1.f, 0.f, nullptr, nullptr, nullptr);
  gemmB1<128,1,0,1,0,0><<<dim3(4,64,1), 256, 0, stream>>>(
      uTh, uTh, CF, 1 << 30, wH + OFF_L1, CF,
      nullptr, lapTh, nullptr, CF, 0, CF, 1.f, 0.f, lin1b, nullptr, nullptr);
  gemmB1<128,0,1,0,0,0><<<dim3(16,64,1), 256, 0, stream>>>(
      lapTh, lapTh, CF, 1 << 30, wH + OFF_L2, CF,
      logits, nullptr, nullptr, NOUT, 0, CF, 1.f, 0.f, lin2b, nullptr, nullptr);
  logSoftmaxK<<<N_NODES, 256, 0, stream>>>(logits, out);
}

// Round 8
// 820.665 us; speedup vs baseline: 4.4044x; 1.0786x over previous
//
#include <hip/hip_runtime.h>
#include <hip/hip_bf16.h>

// Problem constants (fixed instance)
#define N_NODES 4096
#define CF      256
#define CIN     64
#define E0_EDGES 65536
#define NLAYER  8
#define NOUT    1024
#define CN      (CF * N_NODES)
#define STD_BLOCKS 64

typedef unsigned short ushort;
typedef __attribute__((ext_vector_type(8))) short s8v;   // 8 bf16
typedef __attribute__((ext_vector_type(4))) float f4v;   // MFMA acc

__device__ __forceinline__ ushort f2bf(float x){
  unsigned int u = __builtin_bit_cast(unsigned int, x);
  return (ushort)((u + 0x7FFFu + ((u >> 16) & 1u)) >> 16);
}
__device__ __forceinline__ float bf2f(ushort h){
  unsigned int u = ((unsigned int)h) << 16;
  return __builtin_bit_cast(float, u);
}

// ---------------- reduction helpers ----------------
__device__ __forceinline__ float waveSumF(float v){
  #pragma unroll
  for (int o = 32; o; o >>= 1) v += __shfl_xor(v, o);
  return v;
}
__device__ __forceinline__ double waveSumD(double v){
  #pragma unroll
  for (int o = 32; o; o >>= 1) v += __shfl_xor(v, o);
  return v;
}
__device__ __forceinline__ float waveMaxF(float v){
  #pragma unroll
  for (int o = 32; o; o >>= 1) v = fmaxf(v, __shfl_xor(v, o));
  return v;
}
__device__ float blockSumF(float v){
  __shared__ float sm[4];
  v = waveSumF(v);
  int l = threadIdx.x & 63, w = threadIdx.x >> 6;
  __syncthreads();
  if (l == 0) sm[w] = v;
  __syncthreads();
  return sm[0] + sm[1] + sm[2] + sm[3];
}
__device__ double blockSumD(double v){
  __shared__ double sm[4];
  v = waveSumD(v);
  int l = threadIdx.x & 63, w = threadIdx.x >> 6;
  __syncthreads();
  if (l == 0) sm[w] = v;
  __syncthreads();
  return sm[0] + sm[1] + sm[2] + sm[3];
}
__device__ float blockMaxF(float v){
  __shared__ float sm[4];
  v = waveMaxF(v);
  int l = threadIdx.x & 63, w = threadIdx.x >> 6;
  __syncthreads();
  if (l == 0) sm[w] = v;
  __syncthreads();
  return fmaxf(fmaxf(sm[0], sm[1]), fmaxf(sm[2], sm[3]));
}

// ---------------- bf16 MFMA GEMM, depth-2 prefetch pipeline ------------------
// C[M,N] = alpha*A·B^T (+beta*Cf, +bias, act). A,B bf16 row-major K-contiguous.
// A rows split across A1/A2 at K=splitAt. 64x64 tile, 4 waves (2x2 of 32x32).
// Global loads issued TWO tiles ahead (static ping-pong reg sets rA0/rB0,
// rA1/rB1); one barrier per tile. WFH: extra transposed bf16 write.
// TRI: grid.x indexes the 10 upper-triangle 64x64 tiles of a 256x256 output.
// cStrideZ!=0: per-z split-K partials (plain store).
#define MF(a,b,c) c = __builtin_amdgcn_mfma_f32_16x16x32_bf16(a, b, c, 0, 0, 0)

template<int BK, int ACT, bool WF32, bool WBF, bool WFH, bool MV, bool TRI>
__global__ __launch_bounds__(256)
void gemmB1(const ushort* __restrict__ A1, const ushort* __restrict__ A2,
            int lda, int splitAt,
            const ushort* __restrict__ B, int ldb,
            float* __restrict__ Cf, ushort* __restrict__ Cb, ushort* __restrict__ Cfh,
            int ldc, size_t cStrideZ, int kChunk,
            float alpha, float beta, const float* __restrict__ bias,
            double* __restrict__ pS, double* __restrict__ pS2)
{
  constexpr int NC = BK / 32;                     // s8v chunks per thread per matrix
  __shared__ ushort As[2][64][BK + 8], Bs[2][64][BK + 8];
  const int tid = threadIdx.x;
  const int r  = tid >> 2;                        // staging row 0..63
  const int kq = (tid & 3) * (BK / 4);
  int bx = blockIdx.x, by = blockIdx.y;
  if (TRI) {
    const int trT[10] = {0,0,0,0,1,1,1,2,2,3};
    const int tcT[10] = {0,1,2,3,1,2,3,2,3,3};
    by = trT[blockIdx.x]; bx = tcT[blockIdx.x];
  }
  const int row0 = by * 64, col0 = bx * 64;
  const int kStart = blockIdx.z * kChunk;
  const int nT = kChunk / BK;

  const int wid = tid >> 6, lane = tid & 63;
  const int wr = (wid >> 1) * 32, wc = (wid & 1) * 32;
  const int fr = lane & 15, fk = (lane >> 4) * 8;

  f4v acc[2][2] = {};
  s8v rA0[NC], rB0[NC], rA1[NC], rB1[NC];

#define LOADTILE(T, RA, RB) { \
    int k0 = kStart + (T) * BK; \
    const ushort* Ag; int kk; \
    if (k0 < splitAt) { Ag = A1; kk = k0; } else { Ag = A2; kk = k0 - splitAt; } \
    size_t aoff = (size_t)(row0 + r) * lda + kk + kq; \
    size_t boff = (size_t)(col0 + r) * ldb + k0 + kq; \
    _Pragma("unroll") \
    for (int c = 0; c < NC; c++) { \
      RA[c] = *(const s8v*)(Ag + aoff + 8 * c); \
      RB[c] = *(const s8v*)(B + boff + 8 * c); } }

#define STORETILE(BUF, RA, RB) { \
    _Pragma("unroll") \
    for (int c = 0; c < NC; c++) { \
      *(s8v*)&As[BUF][r][kq + 8 * c] = RA[c]; \
      *(s8v*)&Bs[BUF][r][kq + 8 * c] = RB[c]; } }

#define MFMAT(BUF) { \
    _Pragma("unroll") \
    for (int ks = 0; ks < BK; ks += 32) { \
      s8v a0 = *(const s8v*)&As[BUF][wr + fr][ks + fk]; \
      s8v a1 = *(const s8v*)&As[BUF][wr + 16 + fr][ks + fk]; \
      s8v b0 = *(const s8v*)&Bs[BUF][wc + fr][ks + fk]; \
      s8v b1 = *(const s8v*)&Bs[BUF][wc + 16 + fr][ks + fk]; \
      MF(a0, b0, acc[0][0]); \
      MF(a0, b1, acc[0][1]); \
      MF(a1, b0, acc[1][0]); \
      MF(a1, b1, acc[1][1]); } }

  LOADTILE(0, rA0, rB0);
  if (nT > 1) LOADTILE(1, rA1, rB1);
  STORETILE(0, rA0, rB0);

  for (int t = 0; t < nT; t += 2) {
    __syncthreads();                       // lds0(tile t) visible; old reads done
    if (t + 2 < nT) LOADTILE(t + 2, rA0, rB0);
    MFMAT(0);
    if (t + 1 < nT) {
      STORETILE(1, rA1, rB1);              // lds1 last read before top barrier
      __syncthreads();
      if (t + 3 < nT) LOADTILE(t + 3, rA1, rB1);
      MFMAT(1);
      if (t + 2 < nT) STORETILE(0, rA0, rB0);  // lds0 last read before mid barrier
    }
  }
#undef LOADTILE
#undef STORETILE
#undef MFMAT

  double s = 0, s2 = 0;
  #pragma unroll
  for (int m = 0; m < 2; m++)
    #pragma unroll
    for (int n = 0; n < 2; n++) {
      const int rowb = row0 + wr + m * 16 + (lane >> 4) * 4;
      const int col  = col0 + wc + n * 16 + fr;
      ushort4 hv;
      #pragma unroll
      for (int q = 0; q < 4; q++) {
        size_t cidx = (size_t)(rowb + q) * ldc + col;
        float v = alpha * acc[m][n][q];
        if (cStrideZ) {
          Cf[blockIdx.z * cStrideZ + cidx] = v;
        } else {
          if (beta != 0.0f) v += beta * Cf[cidx];
          if (bias) v += bias[col];
          if (ACT == 1) v = (v > 0.0f) ? v : expm1f(v);
          if (WF32) Cf[cidx] = v;
          if (WBF)  Cb[cidx] = f2bf(v);
          if (WFH)  ((ushort*)&hv)[q] = f2bf(v);
          if (MV)   { s += v; s2 += (double)v * v; }
        }
      }
      if (WFH && !cStrideZ)
        *(ushort4*)(Cfh + (size_t)col * N_NODES + rowb) = hv;
    }
  if (MV) {
    s  = blockSumD(s);
    s2 = blockSumD(s2);
    if (tid == 0) {
      int bid = blockIdx.y * gridDim.x + blockIdx.x;   // stats grids are 256 blocks
      pS[bid] = s; pS2[bid] = s2;
    }
  }
}

// ---------------- weight f32 -> bf16 (once per launch) ----------------------
#define OFF_K1   0
#define OFF_K2   16384
#define OFF_KNC  81920
#define OFF_KN1  147456
#define OFF_KN2  1196032
#define OFF_L1   1720320
#define OFF_L2   1785856
#define NW_TOT   2048000

__global__ __launch_bounds__(256)
void prepWK(const float* s0, const float* s1, const float* s2, const float* s3,
            const float* s4, const float* s5, const float* s6,
            ushort* __restrict__ h)
{
  const int sizes[7] = {16384, 65536, 65536, 1048576, 524288, 65536, 262144};
  const int offs[7]  = {OFF_K1, OFF_K2, OFF_KNC, OFF_KN1, OFF_KN2, OFF_L1, OFF_L2};
  int seg = blockIdx.y;
  const float* src = seg==0?s0: seg==1?s1: seg==2?s2: seg==3?s3: seg==4?s4: seg==5?s5: s6;
  int n = sizes[seg], off = offs[seg];
  for (int i = blockIdx.x * 256 + threadIdx.x; i < n; i += gridDim.x * 256)
    h[off + i] = f2bf(src[i]);
}

// ---------------- transpose f32 [R][Cc] -> bf16 [Cc][R] (open only) ----------
__global__ __launch_bounds__(256)
void transposeBF(const float* __restrict__ in, ushort* __restrict__ outh, int R, int Cc)
{
  __shared__ float t[32][33];
  int x  = blockIdx.x * 32 + threadIdx.x;
  int y0 = blockIdx.y * 32;
  for (int dy = threadIdx.y; dy < 32; dy += 8)
    t[dy][threadIdx.x] = in[(size_t)(y0 + dy) * Cc + x];
  __syncthreads();
  int ox  = y0 + threadIdx.x;
  int oy0 = blockIdx.x * 32;
  for (int dy = threadIdx.y; dy < 32; dy += 8)
    outh[(size_t)(oy0 + dy) * R + ox] = f2bf(t[threadIdx.x][dy]);
}

// ---------------- whole-tensor tanh-LN in place on bf16 ---------------------
__global__ __launch_bounds__(256)
void tanhNormBF(ushort* __restrict__ h, const double* __restrict__ pS,
                const double* __restrict__ pS2)
{
  __shared__ float bc[2];
  double a = pS[threadIdx.x], b = pS2[threadIdx.x];
  a = blockSumD(a);
  b = blockSumD(b);
  if (threadIdx.x == 0) {
    double m   = a / (double)CN;
    double var = b / (double)CN - m * m;
    bc[0] = (float)m;
    bc[1] = (float)(1.0 / sqrt(var + 1e-5));
  }
  __syncthreads();
  float mf = bc[0], rs = bc[1];
  for (size_t i = ((size_t)blockIdx.x * 256 + threadIdx.x) * 8; i < CN;
       i += (size_t)256 * 256 * 8) {
    s8v hv = *(s8v*)(h + i);
    #pragma unroll
    for (int k = 0; k < 8; k++) {
      float x = bf2f((ushort)hv[k]);
      x = tanhf((x - mf) * rs);
      hv[k] = (short)f2bf(x);
    }
    *(s8v*)(h + i) = hv;
  }
}

// ---------------- fused sq + s/h block-partials + deg zero (bf16 in) ---------
__global__ __launch_bounds__(256)
void sqSHK(const ushort* __restrict__ fTh, float* __restrict__ sq,
           float* __restrict__ sP, float* __restrict__ hP, float* __restrict__ deg)
{
  __shared__ float smS[4][256], smH[4][256];
  int b = blockIdx.x, w = threadIdx.x >> 6, lane = threadIdx.x & 63;
  if (threadIdx.x < 64) deg[b * 64 + threadIdx.x] = 0.0f;
  float sA[4] = {0,0,0,0}, hA[4] = {0,0,0,0};
  for (int rr = 0; rr < 16; rr++) {
    int n = b * 64 + rr * 4 + w;
    ushort4 u = ((const ushort4*)(fTh + (size_t)n * CF))[lane];
    float x0 = bf2f(u.x), x1 = bf2f(u.y), x2 = bf2f(u.z), x3 = bf2f(u.w);
    float q = waveSumF(x0*x0 + x1*x1 + x2*x2 + x3*x3);
    if (lane == 0) sq[n] = q;
    sA[0] += x0; sA[1] += x1; sA[2] += x2; sA[3] += x3;
    hA[0] += x0*q; hA[1] += x1*q; hA[2] += x2*q; hA[3] += x3*q;
  }
  #pragma unroll
  for (int k = 0; k < 4; k++) { smS[w][lane*4+k] = sA[k]; smH[w][lane*4+k] = hA[k]; }
  __syncthreads();
  int t = threadIdx.x;
  sP[(size_t)b * 256 + t] = smS[0][t] + smS[1][t] + smS[2][t] + smS[3][t];
  hP[(size_t)b * 256 + t] = smH[0][t] + smH[1][t] + smH[2][t] + smH[3][t];
}

// ---------------- std(D) closed form: 64-block partials (upper-tri G) --------
__global__ __launch_bounds__(256)
void stdPartsK(const float* __restrict__ sP, const float* __restrict__ hP,
               const float* __restrict__ Gp, const float* __restrict__ sq,
               double* __restrict__ parts)
{
  int b = blockIdx.x, t = threadIdx.x;
  double S1 = 0, S2 = 0, sd = 0, hd = 0, gf = 0;
  for (int i = b * 256 + t; i < N_NODES; i += STD_BLOCKS * 256) {
    double q = sq[i]; S1 += q; S2 += q * q;
  }
  if (b == 0) {
    float sv = 0, hv = 0;
    for (int p = 0; p < 64; p++) { sv += sP[p * 256 + t]; hv += hP[p * 256 + t]; }
    sd = (double)sv * sv; hd = (double)hv * sv;
  }
  for (int i = b * 256 + t; i < CF * CF; i += STD_BLOCKS * 256) {
    int r = i >> 8, c = i & 255;
    if (r > c) continue;               // only upper-triangle tiles were computed
    double g = 0;
    #pragma unroll 4
    for (int z = 0; z < 16; z++) g += Gp[(size_t)z * 65536 + i];
    gf += (r == c) ? g * g : 2.0 * g * g;
  }
  S1 = blockSumD(S1);
  S2 = blockSumD(S2);
  sd = blockSumD(sd);
  hd = blockSumD(hd);
  gf = blockSumD(gf);
  if (t == 0) {
    parts[0 * STD_BLOCKS + b] = S1;
    parts[1 * STD_BLOCKS + b] = S2;
    parts[2 * STD_BLOCKS + b] = sd;
    parts[3 * STD_BLOCKS + b] = hd;
    parts[4 * STD_BLOCKS + b] = gf;
  }
}

// ---------------- edge affinities + inline std finalize + deg atomics --------
__global__ __launch_bounds__(256)
void edgeWK(const int* __restrict__ ei, const int* __restrict__ ej,
            const ushort* __restrict__ fTh, const float* __restrict__ sq,
            const double* __restrict__ parts, float* __restrict__ wE,
            float* __restrict__ deg)
{
  __shared__ float c0s;
  if (threadIdx.x < 64) {
    int l = threadIdx.x;
    double v0 = waveSumD(parts[0 * STD_BLOCKS + l]);
    double v1 = waveSumD(parts[1 * STD_BLOCKS + l]);
    double v2 = waveSumD(parts[2 * STD_BLOCKS + l]);
    double v3 = waveSumD(parts[3 * STD_BLOCKS + l]);
    double v4 = waveSumD(parts[4 * STD_BLOCKS + l]);
    if (l == 0) {
      double NN = (double)N_NODES;
      double sum1 = 2.0 * NN * v0 - 2.0 * v2;
      double sum2 = 2.0 * NN * v1 + 2.0 * v0 * v0 + 4.0 * v4 - 8.0 * v3;
      double n2 = NN * NN;
      double var = (sum2 - sum1 * sum1 / n2) / (n2 - 1.0);
      double sdev = sqrt(var > 0 ? var : 0);
      c0s = (float)(-2.0 / sdev);
    }
  }
  __syncthreads();
  float c0 = c0s;
  int w = threadIdx.x >> 6, lane = threadIdx.x & 63;
  int e0 = (blockIdx.x * 4 + w) * 4;
  for (int q = 0; q < 4; q++) {
    int e = e0 + q;
    int i = ei[e], j = ej[e];
    ushort4 ua = ((const ushort4*)(fTh + (size_t)i * CF))[lane];
    ushort4 ub = ((const ushort4*)(fTh + (size_t)j * CF))[lane];
    float d = waveSumF(bf2f(ua.x)*bf2f(ub.x) + bf2f(ua.y)*bf2f(ub.y) +
                       bf2f(ua.z)*bf2f(ub.z) + bf2f(ua.w)*bf2f(ub.w));
    if (lane == 0) {
      float dist = fmaxf(sq[i] + sq[j] - 2.0f * d, 0.0f);
      float ww = expf(c0 * dist);
      wE[e] = ww;
      unsafeAtomicAdd(&deg[j], ww);
    }
  }
}

// ---------------- per-edge normalized weight squared -------------------------
__global__ __launch_bounds__(256)
void wsqK(const int* __restrict__ ei, const int* __restrict__ ej,
          const float* __restrict__ wE, const float* __restrict__ deg,
          float* __restrict__ Wsq)
{
  int e = blockIdx.x * 256 + threadIdx.x;
  float W = rsqrtf(1.0f + deg[ei[e]]) * wE[e] * rsqrtf(1.0f + deg[ej[e]]);
  Wsq[e] = W * W;
}

// ---------------- CSR build (edge list is a fixed input) ---------------------
__global__ __launch_bounds__(256)
void csrCountK(const int* __restrict__ ei, const int* __restrict__ ej,
               int* __restrict__ cntO, int* __restrict__ cntI)
{
  int e = blockIdx.x * 256 + threadIdx.x;
  atomicAdd(&cntO[ei[e]], 1);
  atomicAdd(&cntI[ej[e]], 1);
}

__global__ __launch_bounds__(256)
void csrScanK(const int* __restrict__ cntO, const int* __restrict__ cntI,
              int* __restrict__ ofsO, int* __restrict__ ofsI)
{
  __shared__ int smO[256], smI[256];
  int t = threadIdx.x;
  int lo[16], li[16];
  int sO = 0, sI = 0;
  #pragma unroll
  for (int k = 0; k < 16; k++) {
    lo[k] = cntO[t * 16 + k]; li[k] = cntI[t * 16 + k];
    sO += lo[k]; sI += li[k];
  }
  smO[t] = sO; smI[t] = sI;
  __syncthreads();
  for (int off = 1; off < 256; off <<= 1) {
    int aO = (t >= off) ? smO[t - off] : 0;
    int aI = (t >= off) ? smI[t - off] : 0;
    __syncthreads();
    smO[t] += aO; smI[t] += aI;
    __syncthreads();
  }
  int bO = smO[t] - sO;
  int bI = smI[t] - sI;
  #pragma unroll
  for (int k = 0; k < 16; k++) {
    ofsO[t * 16 + k] = bO; bO += lo[k];
    ofsI[t * 16 + k] = bI; bI += li[k];
  }
}

__global__ __launch_bounds__(256)
void csrFillK(const int* __restrict__ ei, const int* __restrict__ ej,
              const int* __restrict__ ofsO, const int* __restrict__ ofsI,
              int* __restrict__ curO, int* __restrict__ curI,
              int2* __restrict__ lstO, int2* __restrict__ lstI)
{
  int e = blockIdx.x * 256 + threadIdx.x;
  int i = ei[e], j = ej[e];
  int p = atomicAdd(&curO[i], 1); lstO[ofsO[i] + p] = make_int2(j, e);
  int q = atomicAdd(&curI[j], 1); lstI[ofsI[j] + q] = make_int2(i, e);
}

// ---------------- graph Laplacian gather: wave per node, ushort4 -------------
__global__ __launch_bounds__(256)
void gatherLapK(const int2* __restrict__ lstO, const int2* __restrict__ lstI,
                const int* __restrict__ ofsO, const int* __restrict__ ofsI,
                const int* __restrict__ cntO, const int* __restrict__ cntI,
                const float* __restrict__ Wsq,
                const ushort* __restrict__ fTh, ushort* __restrict__ lapTh)
{
  int w = threadIdx.x >> 6, lane = threadIdx.x & 63;
  int n = blockIdx.x * 4 + w;
  ushort4 u = ((const ushort4*)(fTh + (size_t)n * CF))[lane];
  float o0 = bf2f(u.x), o1 = bf2f(u.y), o2 = bf2f(u.z), o3 = bf2f(u.w);
  float a0 = 0, a1 = 0, a2 = 0, a3 = 0;
  int p0 = ofsO[n], pc = cntO[n];
  for (int k = 0; k < pc; k++) {
    int2 oe = lstO[p0 + k];
    float W2 = Wsq[oe.y];
    ushort4 v = ((const ushort4*)(fTh + (size_t)oe.x * CF))[lane];
    a0 += W2 * (o0 - bf2f(v.x)); a1 += W2 * (o1 - bf2f(v.y));
    a2 += W2 * (o2 - bf2f(v.z)); a3 += W2 * (o3 - bf2f(v.w));
  }
  int q0 = ofsI[n], qc = cntI[n];
  for (int k = 0; k < qc; k++) {
    int2 oe = lstI[q0 + k];
    float W2 = Wsq[oe.y];
    ushort4 v = ((const ushort4*)(fTh + (size_t)oe.x * CF))[lane];
    a0 += W2 * (o0 - bf2f(v.x)); a1 += W2 * (o1 - bf2f(v.y));
    a2 += W2 * (o2 - bf2f(v.z)); a3 += W2 * (o3 - bf2f(v.w));
  }
  ushort4 rv;
  rv.x = f2bf(a0); rv.y = f2bf(a1); rv.z = f2bf(a2); rv.w = f2bf(a3);
  ((ushort4*)(lapTh + (size_t)n * CF))[lane] = rv;
}

// ---------------- row log-softmax ----------------
__global__ __launch_bounds__(256)
void logSoftmaxK(const float* __restrict__ logits, float* __restrict__ out)
{
  int n = blockIdx.x;
  const float* row = logits + (size_t)n * NOUT;
  float mx = -1e30f;
  for (int o = threadIdx.x; o < NOUT; o += 256) mx = fmaxf(mx, row[o]);
  mx = blockMaxF(mx);
  float se = 0;
  for (int o = threadIdx.x; o < NOUT; o += 256) se += expf(row[o] - mx);
  se = blockSumF(se);
  float lse = mx + logf(se);
  for (int o = threadIdx.x; o < NOUT; o += 256) out[(size_t)n * NOUT + o] = row[o] - lse;
}

extern "C" void kernel_launch(void* const* d_in, const int* in_sizes, int n_in,
                              void* d_out, int out_size, void* d_ws, size_t ws_size,
                              hipStream_t stream)
{
  (void)in_sizes; (void)n_in; (void)out_size; (void)ws_size;
  const float* x0      = (const float*)d_in[0];
  const float* K1      = (const float*)d_in[1];
  const float* K2      = (const float*)d_in[2];
  const float* KNclose = (const float*)d_in[3];
  const float* KN1     = (const float*)d_in[4];
  const float* KN2     = (const float*)d_in[5];
  const float* lin1w   = (const float*)d_in[6];
  const float* lin1b   = (const float*)d_in[7];
  const float* lin2w   = (const float*)d_in[8];
  const float* lin2b   = (const float*)d_in[9];
  const int*   ei      = (const int*)d_in[10];
  const int*   ej      = (const int*)d_in[11];
  float* out = (float*)d_out;

  // ---------------- workspace layout ----------------
  float* base   = (float*)d_ws;
  float* fT     = base;                     // [N][CF] f32 residual features
  float* logits = fT + (size_t)CN;          // [N][NOUT]
  float* Gp     = logits + 4 * (size_t)CN;  // [16][256*256] Gram split-K partials
  float* sq     = Gp + (size_t)CN;          // [N]
  float* deg    = sq + N_NODES;             // [N]
  float* sP     = deg + N_NODES;            // [64][256]
  float* hP     = sP + 64 * 256;            // [64][256]
  float* wE     = hP + 64 * 256;            // [E0]
  float* Wsq    = wE + E0_EDGES;            // [E0]
  double* pS    = (double*)(Wsq + E0_EDGES + 2);  // [256]
  double* pS2   = pS + 256;                 // [256]
  double* parts = pS2 + 256;                // [5*64]

  ushort* u0 = (ushort*)(((uintptr_t)(parts + 5 * STD_BLOCKS) + 15) & ~(uintptr_t)15);
  ushort* fTh   = u0;                       // [N][CF] bf16 features
  ushort* fh    = fTh + (size_t)CN;         // [CF][N] transposed bf16 (xt at open)
  ushort* lapTh = fh + (size_t)CN;          // lap bf16; x1 at close
  ushort* uTh   = lapTh + (size_t)CN;       // intermediate bf16; y at close
  ushort* wH    = uTh + (size_t)CN;         // all weights bf16
  int* ib = (int*)(((uintptr_t)(wH + NW_TOT) + 15) & ~(uintptr_t)15);
  int*  cntO = ib;
  int*  cntI = cntO + N_NODES;
  int*  ofsO = cntI + N_NODES;
  int*  ofsI = ofsO + N_NODES;
  int*  curO = ofsI + N_NODES;
  int*  curI = curO + N_NODES;
  int2* lstO = (int2*)(curI + N_NODES);
  int2* lstI = lstO + E0_EDGES;

  // ---- one-time: weight bf16 + CSR ----
  prepWK<<<dim3(64, 7), 256, 0, stream>>>(K1, K2, KNclose, KN1, KN2, lin1w, lin2w, wH);
  hipMemsetAsync(cntO, 0, 6 * N_NODES * sizeof(int), stream);
  csrCountK<<<E0_EDGES/256, 256, 0, stream>>>(ei, ej, cntO, cntI);
  csrScanK<<<1, 256, 0, stream>>>(cntO, cntI, ofsO, ofsI);
  csrFillK<<<E0_EDGES/256, 256, 0, stream>>>(ei, ej, ofsO, ofsI, curO, curI, lstO, lstI);

  // ---- opening: fT = tanh(LN(x0T·K1^T))·K2^T ----
  transposeBF<<<dim3(N_NODES/32, CIN/32), dim3(32, 8), 0, stream>>>(x0, fh, CIN, N_NODES);
  gemmB1<64,0,0,1,0,1,false><<<dim3(4,64,1), 256, 0, stream>>>(
      fh, fh, CIN, 1 << 30, wH + OFF_K1, CIN,
      nullptr, uTh, nullptr, CF, 0, CIN, 1.f, 0.f, nullptr, pS, pS2);
  tanhNormBF<<<256, 256, 0, stream>>>(uTh, pS, pS2);
  gemmB1<128,0,1,1,1,0,false><<<dim3(4,64,1), 256, 0, stream>>>(
      uTh, uTh, CF, 1 << 30, wH + OFF_K2, CF,
      fT, fTh, fh, CF, 0, CF, 1.f, 0.f, nullptr, nullptr, nullptr);

  for (int L = 0; L < NLAYER; L++) {
    const ushort* k1h = wH + OFF_KN1 + (size_t)L * CF * 2 * CF;
    const ushort* k2h = wH + OFF_KN2 + (size_t)L * CF * CF;

    sqSHK<<<64, 256, 0, stream>>>(fTh, sq, sP, hP, deg);
    // Gram split-K=16 partials, upper-triangle tiles only (G symmetric)
    gemmB1<128,0,1,0,0,0,true><<<dim3(10,1,16), 256, 0, stream>>>(
        fh, fh, N_NODES, 1 << 30, fh, N_NODES,
        Gp, nullptr, nullptr, CF, 65536, 256, 1.f, 0.f, nullptr, nullptr, nullptr);
    stdPartsK<<<STD_BLOCKS, 256, 0, stream>>>(sP, hP, Gp, sq, parts);
    edgeWK<<<E0_EDGES/16, 256, 0, stream>>>(ei, ej, fTh, sq, parts, wE, deg);
    wsqK<<<E0_EDGES/256, 256, 0, stream>>>(ei, ej, wE, deg, Wsq);
    gatherLapK<<<N_NODES/4, 256, 0, stream>>>(lstO, lstI, ofsO, ofsI, cntO, cntI,
                                              Wsq, fTh, lapTh);
    // uT = [fT, lapT]·KN1^T (fused K=512 dual-A) + LN-stat partials
    gemmB1<128,0,0,1,0,1,false><<<dim3(4,64,1), 256, 0, stream>>>(
        fTh, lapTh, CF, 256, k1h, 2*CF,
        nullptr, uTh, nullptr, CF, 0, 2*CF, 1.f, 0.f, nullptr, pS, pS2);
    tanhNormBF<<<256, 256, 0, stream>>>(uTh, pS, pS2);
    // fT += 0.1 · uT·KN2^T  (writes f32 fT, bf16 fTh, transposed bf16 fh)
    gemmB1<128,0,1,1,1,0,false><<<dim3(4,64,1), 256, 0, stream>>>(
        uTh, uTh, CF, 1 << 30, k2h, CF,
        fT, fTh, fh, CF, 0, CF, 0.1f, 1.f, nullptr, nullptr, nullptr);
  }

  // ---- close: y = fT·KNclose^T ; x1 = elu(y·lin1^T+b1) ; logits ; log_softmax ----
  gemmB1<128,0,0,1,0,0,false><<<dim3(4,64,1), 256, 0, stream>>>(
      fTh, fTh, CF, 1 << 30, wH + OFF_KNC, CF,
      nullptr, uTh, nullptr, CF, 0, CF, 1.f, 0.f, nullptr, nullptr, nullptr);
  gemmB1<128,1,0,1,0,0,false><<<dim3(4,64,1), 256, 0, stream>>>(
      uTh, uTh, CF, 1 << 30, wH + OFF_L1, CF,
      nullptr, lapTh, nullptr, CF, 0, CF, 1.f, 0.f, lin1b, nullptr, nullptr);
  gemmB1<128,0,1,0,0,0,false><<<dim3(16,64,1), 256, 0, stream>>>(
      lapTh, lapTh, CF, 1 << 30, wH + OFF_L2, CF,
      logits, nullptr, nullptr, NOUT, 0, CF, 1.f, 0.f, lin2b, nullptr, nullptr);
  logSoftmaxK<<<N_NODES, 256, 0, stream>>>(logits, out);
}